// Round 1
// baseline (1080.280 us; speedup 1.0000x reference)
//
#include <hip/hip_runtime.h>
#include <hip/hip_bf16.h>
#include <stdint.h>

// Problem constants
#define B_  2
#define S_  2048
#define SC_ 512
#define H_  2048
#define NH_ 16
#define G_  8
#define D_  128

typedef __attribute__((ext_vector_type(8))) short bf16x8;
typedef __attribute__((ext_vector_type(4))) float f32x4;

__device__ __forceinline__ uint16_t bf16_rne_bits(float x) {
  uint32_t u = __float_as_uint(x);
  u += 0x7fffu + ((u >> 16) & 1u);
  return (uint16_t)(u >> 16);
}
__device__ __forceinline__ float bf16_rne_f(float x) {
  uint32_t u = __float_as_uint(x);
  u += 0x7fffu + ((u >> 16) & 1u);
  return __uint_as_float(u & 0xffff0000u);
}
// fp8 e4m3fn round-trip (RNE, input already clipped to [-448,448])
__device__ __forceinline__ float fp8_rt(float x) {
  float a = fabsf(x);
  float step;
  if (a >= 0.015625f) {  // normal range: step = 2^(E-3)
    uint32_t u = __float_as_uint(a);
    int E = (int)((u >> 23) & 0xffu) - 127;
    step = __uint_as_float((uint32_t)(E - 3 + 127) << 23);
  } else {
    step = 0.001953125f;  // 2^-9 subnormal step
  }
  float q = rintf(a / step) * step;
  return x < 0.f ? -q : q;
}

// ---------------- prep: weight casts / splits / scalar scales ----------------
__global__ __launch_bounds__(256) void k_prep(
    const float* __restrict__ wq, const float* __restrict__ wqx,
    const float* __restrict__ wk, const float* __restrict__ wv,
    const float* __restrict__ wkvx, const float* __restrict__ wproj,
    const float* __restrict__ cond,
    const float* __restrict__ q_is, const float* __restrict__ wq_s,
    const float* __restrict__ qx_is, const float* __restrict__ wqx_s,
    const float* __restrict__ k_is, const float* __restrict__ wk_s,
    const float* __restrict__ v_is, const float* __restrict__ wv_s,
    const float* __restrict__ p_is, const float* __restrict__ p_ws,
    uint16_t* __restrict__ Wcat, uint16_t* __restrict__ Wpb,
    uint16_t* __restrict__ Wkvxh, uint16_t* __restrict__ Wkvxl,
    uint16_t* __restrict__ condh, uint16_t* __restrict__ condl,
    float* __restrict__ scales)
{
  size_t idx = (size_t)blockIdx.x * 256 + threadIdx.x;
  size_t stride = (size_t)gridDim.x * 256;
  const size_t NC = (size_t)6144 * 2048;
  for (size_t i = idx; i < NC; i += stride) {
    size_t row = i >> 11; int col = (int)(i & 2047);
    float v;
    if (row < 2048)      v = wq[i];
    else if (row < 4096) v = wqx[(row - 2048) * 2048 + col];
    else if (row < 5120) v = wk[(row - 4096) * 2048 + col];
    else                 v = wv[(row - 5120) * 2048 + col];
    Wcat[i] = (uint16_t)(__float_as_uint(v) >> 16);  // fp8 values: exact in bf16
  }
  const size_t NP = (size_t)2048 * 4096;
  for (size_t i = idx; i < NP; i += stride)
    Wpb[i] = (uint16_t)(__float_as_uint(wproj[i]) >> 16);
  const size_t NX = (size_t)2048 * 2048;
  for (size_t i = idx; i < NX; i += stride) {
    float x = wkvx[i];
    uint16_t h = bf16_rne_bits(x);
    Wkvxh[i] = h;
    Wkvxl[i] = bf16_rne_bits(x - __uint_as_float((uint32_t)h << 16));
  }
  const size_t ND = (size_t)1024 * 2048;
  for (size_t i = idx; i < ND; i += stride) {
    float x = cond[i];
    uint16_t h = bf16_rne_bits(x);
    condh[i] = h;
    condl[i] = bf16_rne_bits(x - __uint_as_float((uint32_t)h << 16));
  }
  if (idx == 0) {
    scales[0] = q_is[0] * wq_s[0];
    scales[1] = qx_is[0] * wqx_s[0];
    scales[2] = k_is[0] * wk_s[0];
    scales[3] = v_is[0] * wv_s[0];
    scales[4] = p_is[0] * p_ws[0];
  }
}

// ---------------- hidden LayerNorm + fp8 quantize -> Aq (bf16 storage) -------
__global__ __launch_bounds__(256) void k_ln_quant(
    const float* __restrict__ x, const float* __restrict__ w,
    const float* __restrict__ b, const float* __restrict__ qis,
    uint16_t* __restrict__ Aq)
{
  int row = blockIdx.x;
  int tid = threadIdx.x;
  const float* xr = x + (size_t)row * H_;
  float v[8];
  float s = 0.f, sq = 0.f;
#pragma unroll
  for (int i = 0; i < 8; i++) {
    float t = xr[tid + i * 256];
    v[i] = t; s += t; sq += t * t;
  }
#pragma unroll
  for (int m = 1; m < 64; m <<= 1) { s += __shfl_xor(s, m); sq += __shfl_xor(sq, m); }
  __shared__ float red[8];
  int wv = tid >> 6;
  if ((tid & 63) == 0) { red[wv] = s; red[4 + wv] = sq; }
  __syncthreads();
  s = red[0] + red[1] + red[2] + red[3];
  sq = red[4] + red[5] + red[6] + red[7];
  float mu = s * (1.f / H_);
  float var = sq * (1.f / H_) - mu * mu;
  float rs = 1.0f / sqrtf(var + 1e-5f);
#pragma unroll
  for (int i = 0; i < 8; i++) {
    int c = tid + i * 256;
    float y = (v[i] - mu) * rs * w[c] + b[c];
    float t = y / qis[c];
    t = fminf(fmaxf(t, -448.f), 448.f);
    t = fp8_rt(bf16_rne_f(t));
    Aq[(size_t)row * H_ + c] = bf16_rne_bits(t);  // exact
  }
}

// ---------------- GEMM (B^T layout) with fused epilogues ---------------------
// MODE 0: QKV proj  (single A=Aq, single B=Wcat)  -> per-head LN -> hi/lo planes
// MODE 1: kvx       (split A=cond, split B=wkvx, 3-MFMA)         -> hi/lo planes
// MODE 2: out proj  (single A=catq, single B=Wproj) -> *scale -> f32 out
template <int MODE>
__global__ __launch_bounds__(256) void k_gemm(
    const uint16_t* __restrict__ Ah, const uint16_t* __restrict__ Al,
    const uint16_t* __restrict__ Bh, const uint16_t* __restrict__ Bl,
    int M, int N, int K,
    const float* __restrict__ scales,
    const float* __restrict__ qln_w, const float* __restrict__ qln_b,
    const float* __restrict__ kln_w, const float* __restrict__ kln_b,
    const float* __restrict__ qxln_w, const float* __restrict__ qxln_b,
    const float* __restrict__ kxln_w, const float* __restrict__ kxln_b,
    uint16_t* __restrict__ Qh, uint16_t* __restrict__ Ql,
    uint16_t* __restrict__ Qxh, uint16_t* __restrict__ Qxl,
    uint16_t* __restrict__ Kh, uint16_t* __restrict__ Kl,
    uint16_t* __restrict__ Vth, uint16_t* __restrict__ Vtl,
    uint16_t* __restrict__ Kxh, uint16_t* __restrict__ Kxl,
    uint16_t* __restrict__ Vxth, uint16_t* __restrict__ Vxtl,
    float* __restrict__ Cout)
{
  __shared__ __align__(16) uint16_t lA[128 * 40];
  __shared__ __align__(16) uint16_t lB[128 * 40];
  __shared__ __align__(16) uint16_t lA2[(MODE == 1) ? 128 * 40 : 8];
  __shared__ __align__(16) uint16_t lB2[(MODE == 1) ? 128 * 40 : 8];
  __shared__ float sred[512];

  const int tid = threadIdx.x;
  const int lane = tid & 63;
  const int wv = tid >> 6;
  const int wr = wv >> 1, wc = wv & 1;
  const int l15 = lane & 15, l4 = lane >> 4;
  const int m0 = blockIdx.y * 128, n0 = blockIdx.x * 128;

  f32x4 acc[4][4] = {};

  for (int kt = 0; kt < K; kt += 32) {
    __syncthreads();
#pragma unroll
    for (int i = 0; i < 2; i++) {
      int c = tid + i * 256;           // 0..511
      int row = c >> 2, kc = (c & 3) * 8;
      *(bf16x8*)&lA[row * 40 + kc] = *(const bf16x8*)&Ah[(size_t)(m0 + row) * K + kt + kc];
      *(bf16x8*)&lB[row * 40 + kc] = *(const bf16x8*)&Bh[(size_t)(n0 + row) * K + kt + kc];
      if (MODE == 1) {
        *(bf16x8*)&lA2[row * 40 + kc] = *(const bf16x8*)&Al[(size_t)(m0 + row) * K + kt + kc];
        *(bf16x8*)&lB2[row * 40 + kc] = *(const bf16x8*)&Bl[(size_t)(n0 + row) * K + kt + kc];
      }
    }
    __syncthreads();
    bf16x8 af[4], af2[4];
#pragma unroll
    for (int mt = 0; mt < 4; mt++) {
      af[mt] = *(bf16x8*)&lA[(wr * 64 + mt * 16 + l15) * 40 + l4 * 8];
      if (MODE == 1) af2[mt] = *(bf16x8*)&lA2[(wr * 64 + mt * 16 + l15) * 40 + l4 * 8];
    }
#pragma unroll
    for (int nt = 0; nt < 4; nt++) {
      bf16x8 bh = *(bf16x8*)&lB[(wc * 64 + nt * 16 + l15) * 40 + l4 * 8];
      if (MODE == 1) {
        bf16x8 bl = *(bf16x8*)&lB2[(wc * 64 + nt * 16 + l15) * 40 + l4 * 8];
#pragma unroll
        for (int mt = 0; mt < 4; mt++) {
          acc[mt][nt] = __builtin_amdgcn_mfma_f32_16x16x32_bf16(af[mt], bh, acc[mt][nt], 0, 0, 0);
          acc[mt][nt] = __builtin_amdgcn_mfma_f32_16x16x32_bf16(af[mt], bl, acc[mt][nt], 0, 0, 0);
          acc[mt][nt] = __builtin_amdgcn_mfma_f32_16x16x32_bf16(af2[mt], bh, acc[mt][nt], 0, 0, 0);
        }
      } else {
#pragma unroll
        for (int mt = 0; mt < 4; mt++)
          acc[mt][nt] = __builtin_amdgcn_mfma_f32_16x16x32_bf16(af[mt], bh, acc[mt][nt], 0, 0, 0);
      }
    }
  }

  const int cb = n0 >> 7;
  float sscale = 1.f;
  const float *lw = nullptr, *lb = nullptr;
  if (MODE == 0) {
    int sect = (cb < 16) ? 0 : (cb < 32) ? 1 : (cb < 40) ? 2 : 3;
    sscale = scales[sect];
    if (sect == 0) { lw = qln_w; lb = qln_b; }
    else if (sect == 1) { lw = qxln_w; lb = qxln_b; }
    else if (sect == 2) { lw = kln_w; lb = kln_b; }
  } else if (MODE == 1) {
    if (cb < 8) { lw = kxln_w; lb = kxln_b; }
  } else {
    sscale = scales[4];
  }
#pragma unroll
  for (int mt = 0; mt < 4; mt++)
#pragma unroll
    for (int nt = 0; nt < 4; nt++)
#pragma unroll
      for (int j = 0; j < 4; j++) acc[mt][nt][j] *= sscale;

  if (MODE == 2) {
#pragma unroll
    for (int mt = 0; mt < 4; mt++)
#pragma unroll
      for (int j = 0; j < 4; j++) {
        int r = m0 + wr * 64 + mt * 16 + l4 * 4 + j;
#pragma unroll
        for (int nt = 0; nt < 4; nt++) {
          int c = n0 + wc * 64 + nt * 16 + l15;
          Cout[(size_t)r * N + c] = acc[mt][nt][j];
        }
      }
    return;
  }

  float mu_[4][4], rs_[4][4];
#pragma unroll
  for (int mt = 0; mt < 4; mt++)
#pragma unroll
    for (int j = 0; j < 4; j++) { mu_[mt][j] = 0.f; rs_[mt][j] = 1.f; }

  if (lw) {  // per-head LayerNorm over the 128-col tile (d dim)
#pragma unroll
    for (int mt = 0; mt < 4; mt++)
#pragma unroll
      for (int j = 0; j < 4; j++) {
        float s = 0.f, sq = 0.f;
#pragma unroll
        for (int nt = 0; nt < 4; nt++) { float t = acc[mt][nt][j]; s += t; sq += t * t; }
#pragma unroll
        for (int mm = 1; mm < 16; mm <<= 1) { s += __shfl_xor(s, mm); sq += __shfl_xor(sq, mm); }
        if (l15 == 0) {
          int ar = wr * 64 + mt * 16 + l4 * 4 + j;
          sred[wc * 128 + ar] = s;
          sred[256 + wc * 128 + ar] = sq;
        }
      }
    __syncthreads();
#pragma unroll
    for (int mt = 0; mt < 4; mt++)
#pragma unroll
      for (int j = 0; j < 4; j++) {
        int ar = wr * 64 + mt * 16 + l4 * 4 + j;
        float Sm = sred[ar] + sred[128 + ar];
        float Sq = sred[256 + ar] + sred[384 + ar];
        float mu = Sm * (1.f / 128.f);
        float var = Sq * (1.f / 128.f) - mu * mu;
        mu_[mt][j] = mu;
        rs_[mt][j] = 1.f / sqrtf(var + 1e-5f);
      }
  }

#pragma unroll
  for (int mt = 0; mt < 4; mt++)
#pragma unroll
    for (int j = 0; j < 4; j++) {
      int r = m0 + wr * 64 + mt * 16 + l4 * 4 + j;
#pragma unroll
      for (int nt = 0; nt < 4; nt++) {
        int d = wc * 64 + nt * 16 + l15;
        float y = acc[mt][nt][j];
        if (lw) y = (y - mu_[mt][j]) * rs_[mt][j] * lw[d] + lb[d];
        uint16_t hb = bf16_rne_bits(y);
        uint16_t lob = bf16_rne_bits(y - __uint_as_float((uint32_t)hb << 16));
        uint16_t *Dh, *Dl; size_t o;
        if (MODE == 0) {
          if (cb < 16)      { Dh = Qh;  Dl = Ql;  o = ((size_t)r * NH_ + cb) * D_ + d; }
          else if (cb < 32) { Dh = Qxh; Dl = Qxl; o = ((size_t)r * NH_ + (cb - 16)) * D_ + d; }
          else if (cb < 40) { Dh = Kh;  Dl = Kl;  o = ((size_t)r * G_ + (cb - 32)) * D_ + d; }
          else { Dh = Vth; Dl = Vtl; int gg = cb - 40;
                 o = (((size_t)(r >> 11) * G_ + gg) * D_ + d) * (size_t)S_ + (r & 2047); }
        } else {
          if (cb < 8) { Dh = Kxh; Dl = Kxl; o = ((size_t)r * G_ + cb) * D_ + d; }
          else { Dh = Vxth; Dl = Vxtl; int gg = cb - 8;
                 o = (((size_t)(r >> 9) * G_ + gg) * D_ + d) * (size_t)SC_ + (r & 511); }
        }
        Dh[o] = hb; Dl[o] = lob;
      }
    }
}

// ---------------- flash GQA attention (hi/lo split, TBLK=32) -----------------
// grid: (S/64, NH, B); 4 waves x 16 q-rows. Writes quantized catq directly.
__global__ __launch_bounds__(256) void k_attn(
    const uint16_t* __restrict__ Qh, const uint16_t* __restrict__ Ql,
    const uint16_t* __restrict__ Kh, const uint16_t* __restrict__ Kl,
    const uint16_t* __restrict__ Vth, const uint16_t* __restrict__ Vtl,
    const float* __restrict__ smooth, uint16_t* __restrict__ catq,
    int T, int colOff)
{
  __shared__ __align__(16) uint16_t lKh[32 * 136];
  __shared__ __align__(16) uint16_t lKl[32 * 136];
  __shared__ __align__(16) uint16_t lVh[128 * 40];
  __shared__ __align__(16) uint16_t lVl[128 * 40];
  __shared__ __align__(16) uint16_t lPh[64 * 40];
  __shared__ __align__(16) uint16_t lPl[64 * 40];

  const int tid = threadIdx.x, lane = tid & 63, wv = tid >> 6;
  const int l15 = lane & 15, l4 = lane >> 4;
  const int q0 = blockIdx.x * 64, h = blockIdx.y, b = blockIdx.z;
  const int g = h >> 1;

  bf16x8 qfh[4], qfl[4];
  {
    int srow = q0 + wv * 16 + l15;
    size_t base = (((size_t)b * S_ + srow) * NH_ + h) * (size_t)D_ + l4 * 8;
#pragma unroll
    for (int ks = 0; ks < 4; ks++) {
      qfh[ks] = *(const bf16x8*)&Qh[base + ks * 32];
      qfl[ks] = *(const bf16x8*)&Ql[base + ks * 32];
    }
  }

  float mrun[4] = {-1e30f, -1e30f, -1e30f, -1e30f};
  float lsum[4] = {0.f, 0.f, 0.f, 0.f};
  f32x4 oacc[8] = {};

  const int nT = T >> 5;
  for (int tt = 0; tt < nT; tt++) {
    const int t0 = tt << 5;
    __syncthreads();
#pragma unroll
    for (int i = 0; i < 2; i++) {       // K tile: 32 t x 128 d
      int c = tid + i * 256;            // 0..511
      int t = c >> 4, dc = (c & 15) * 8;
      size_t ga = (((size_t)b * T + (t0 + t)) * G_ + g) * (size_t)D_ + dc;
      *(bf16x8*)&lKh[t * 136 + dc] = *(const bf16x8*)&Kh[ga];
      *(bf16x8*)&lKl[t * 136 + dc] = *(const bf16x8*)&Kl[ga];
    }
#pragma unroll
    for (int i = 0; i < 2; i++) {       // V tile (pre-transposed [d][t])
      int c = tid + i * 256;
      int d = c & 127, tg = c >> 7;     // tg 0..3
      size_t ga = (((size_t)b * G_ + g) * (size_t)D_ + d) * (size_t)T + t0 + tg * 8;
      *(bf16x8*)&lVh[d * 40 + tg * 8] = *(const bf16x8*)&Vth[ga];
      *(bf16x8*)&lVl[d * 40 + tg * 8] = *(const bf16x8*)&Vtl[ga];
    }
    __syncthreads();

    f32x4 sf[2];
#pragma unroll
    for (int nt = 0; nt < 2; nt++) {
      f32x4 a = {0.f, 0.f, 0.f, 0.f};
#pragma unroll
      for (int ks = 0; ks < 4; ks++) {
        int off = (nt * 16 + l15) * 136 + ks * 32 + l4 * 8;
        bf16x8 kh = *(bf16x8*)&lKh[off];
        bf16x8 kl = *(bf16x8*)&lKl[off];
        a = __builtin_amdgcn_mfma_f32_16x16x32_bf16(qfh[ks], kh, a, 0, 0, 0);
        a = __builtin_amdgcn_mfma_f32_16x16x32_bf16(qfh[ks], kl, a, 0, 0, 0);
        a = __builtin_amdgcn_mfma_f32_16x16x32_bf16(qfl[ks], kh, a, 0, 0, 0);
      }
      sf[nt] = a;
    }

    const float SCL = 0.08838834764831845f;  // 1/sqrt(128)
#pragma unroll
    for (int j = 0; j < 4; j++) {
      float s0 = sf[0][j] * SCL, s1 = sf[1][j] * SCL;
      float tm = fmaxf(s0, s1);
#pragma unroll
      for (int mm = 1; mm < 16; mm <<= 1) tm = fmaxf(tm, __shfl_xor(tm, mm));
      float mn = fmaxf(mrun[j], tm);
      float al = expf(mrun[j] - mn);
      float p0 = expf(s0 - mn), p1 = expf(s1 - mn);
      float rsum = p0 + p1;
#pragma unroll
      for (int mm = 1; mm < 16; mm <<= 1) rsum += __shfl_xor(rsum, mm);
      lsum[j] = lsum[j] * al + rsum;
      mrun[j] = mn;
#pragma unroll
      for (int dt = 0; dt < 8; dt++) oacc[dt][j] *= al;
      int prow = wv * 16 + l4 * 4 + j;
      uint16_t p0h = bf16_rne_bits(p0);
      uint16_t p1h = bf16_rne_bits(p1);
      lPh[prow * 40 + l15]      = p0h;
      lPh[prow * 40 + 16 + l15] = p1h;
      lPl[prow * 40 + l15]      = bf16_rne_bits(p0 - __uint_as_float((uint32_t)p0h << 16));
      lPl[prow * 40 + 16 + l15] = bf16_rne_bits(p1 - __uint_as_float((uint32_t)p1h << 16));
    }

    bf16x8 pah = *(bf16x8*)&lPh[(wv * 16 + l15) * 40 + l4 * 8];
    bf16x8 pal = *(bf16x8*)&lPl[(wv * 16 + l15) * 40 + l4 * 8];
#pragma unroll
    for (int dt = 0; dt < 8; dt++) {
      int off = (dt * 16 + l15) * 40 + l4 * 8;
      bf16x8 vh = *(bf16x8*)&lVh[off];
      bf16x8 vl = *(bf16x8*)&lVl[off];
      oacc[dt] = __builtin_amdgcn_mfma_f32_16x16x32_bf16(pah, vh, oacc[dt], 0, 0, 0);
      oacc[dt] = __builtin_amdgcn_mfma_f32_16x16x32_bf16(pah, vl, oacc[dt], 0, 0, 0);
      oacc[dt] = __builtin_amdgcn_mfma_f32_16x16x32_bf16(pal, vh, oacc[dt], 0, 0, 0);
    }
  }

#pragma unroll
  for (int j = 0; j < 4; j++) {
    float inv = 1.f / lsum[j];
    int srow = q0 + wv * 16 + l4 * 4 + j;
    size_t rbase = ((size_t)b * S_ + srow) * 4096;
#pragma unroll
    for (int dt = 0; dt < 8; dt++) {
      int c = colOff + h * D_ + dt * 16 + l15;
      float t = (oacc[dt][j] * inv) / smooth[c];
      t = fminf(fmaxf(t, -448.f), 448.f);
      t = fp8_rt(bf16_rne_f(t));
      catq[rbase + c] = bf16_rne_bits(t);
    }
  }
}

// ---------------------------------------------------------------------------
extern "C" void kernel_launch(void* const* d_in, const int* in_sizes, int n_in,
                              void* d_out, int out_size, void* d_ws, size_t ws_size,
                              hipStream_t stream)
{
  (void)in_sizes; (void)n_in; (void)out_size;
  const float* hidden = (const float*)d_in[0];
  const float* cond   = (const float*)d_in[1];
  const float* ln_w   = (const float*)d_in[2];
  const float* ln_b   = (const float*)d_in[3];
  const float* wq     = (const float*)d_in[4];
  const float* wq_s   = (const float*)d_in[5];
  const float* q_is   = (const float*)d_in[6];
  const float* wqx    = (const float*)d_in[7];
  const float* wqx_s  = (const float*)d_in[8];
  const float* qx_is  = (const float*)d_in[9];
  const float* wk     = (const float*)d_in[10];
  const float* wk_s   = (const float*)d_in[11];
  const float* k_is   = (const float*)d_in[12];
  const float* wv     = (const float*)d_in[13];
  const float* wv_s   = (const float*)d_in[14];
  const float* v_is   = (const float*)d_in[15];
  const float* wkvx   = (const float*)d_in[16];
  const float* qln_w  = (const float*)d_in[17];
  const float* qln_b  = (const float*)d_in[18];
  const float* kln_w  = (const float*)d_in[19];
  const float* kln_b  = (const float*)d_in[20];
  const float* qxln_w = (const float*)d_in[21];
  const float* qxln_b = (const float*)d_in[22];
  const float* kxln_w = (const float*)d_in[23];
  const float* kxln_b = (const float*)d_in[24];
  const float* wproj  = (const float*)d_in[25];
  const float* p_ws   = (const float*)d_in[26];  // proj_w_scale
  const float* p_is   = (const float*)d_in[27];  // proj_in_scale
  const float* smooth = (const float*)d_in[28];  // proj_smooth

  char* ws = (char*)d_ws;
  size_t off = 0;
  auto alloc = [&](size_t bytes) {
    char* p = ws + off;
    off += (bytes + 255) & ~(size_t)255;
    return p;
  };
  uint16_t* Aq    = (uint16_t*)alloc((size_t)4096 * 2048 * 2);
  uint16_t* Wcat  = (uint16_t*)alloc((size_t)6144 * 2048 * 2);
  uint16_t* Wpb   = (uint16_t*)alloc((size_t)2048 * 4096 * 2);
  uint16_t* Wkvxh = (uint16_t*)alloc((size_t)2048 * 2048 * 2);
  uint16_t* Wkvxl = (uint16_t*)alloc((size_t)2048 * 2048 * 2);
  uint16_t* condh = (uint16_t*)alloc((size_t)1024 * 2048 * 2);
  uint16_t* condl = (uint16_t*)alloc((size_t)1024 * 2048 * 2);
  uint16_t* Qh    = (uint16_t*)alloc((size_t)4096 * 16 * 128 * 2);
  uint16_t* Ql    = (uint16_t*)alloc((size_t)4096 * 16 * 128 * 2);
  uint16_t* Qxh   = (uint16_t*)alloc((size_t)4096 * 16 * 128 * 2);
  uint16_t* Qxl   = (uint16_t*)alloc((size_t)4096 * 16 * 128 * 2);
  uint16_t* Kh    = (uint16_t*)alloc((size_t)4096 * 8 * 128 * 2);
  uint16_t* Kl    = (uint16_t*)alloc((size_t)4096 * 8 * 128 * 2);
  uint16_t* Vth   = (uint16_t*)alloc((size_t)4096 * 8 * 128 * 2);
  uint16_t* Vtl   = (uint16_t*)alloc((size_t)4096 * 8 * 128 * 2);
  uint16_t* Kxh   = (uint16_t*)alloc((size_t)1024 * 8 * 128 * 2);
  uint16_t* Kxl   = (uint16_t*)alloc((size_t)1024 * 8 * 128 * 2);
  uint16_t* Vxth  = (uint16_t*)alloc((size_t)1024 * 8 * 128 * 2);
  uint16_t* Vxtl  = (uint16_t*)alloc((size_t)1024 * 8 * 128 * 2);
  uint16_t* catq  = (uint16_t*)alloc((size_t)4096 * 4096 * 2);
  float* scales   = (float*)alloc(256);
  if (ws_size < off) return;  // workspace too small; fail loudly via wrong output

  k_prep<<<2048, 256, 0, stream>>>(wq, wqx, wk, wv, wkvx, wproj, cond,
      q_is, wq_s, qx_is, wqx_s, k_is, wk_s, v_is, wv_s, p_is, p_ws,
      Wcat, Wpb, Wkvxh, Wkvxl, condh, condl, scales);

  k_ln_quant<<<4096, 256, 0, stream>>>(hidden, ln_w, ln_b, q_is, Aq);

  k_gemm<0><<<dim3(48, 32), 256, 0, stream>>>(Aq, nullptr, Wcat, nullptr,
      4096, 6144, 2048, scales,
      qln_w, qln_b, kln_w, kln_b, qxln_w, qxln_b, kxln_w, kxln_b,
      Qh, Ql, Qxh, Qxl, Kh, Kl, Vth, Vtl,
      nullptr, nullptr, nullptr, nullptr, nullptr);

  k_gemm<1><<<dim3(16, 8), 256, 0, stream>>>(condh, condl, Wkvxh, Wkvxl,
      1024, 2048, 2048, scales,
      qln_w, qln_b, kln_w, kln_b, qxln_w, qxln_b, kxln_w, kxln_b,
      nullptr, nullptr, nullptr, nullptr, nullptr, nullptr, nullptr, nullptr,
      Kxh, Kxl, Vxth, Vxtl, nullptr);

  k_attn<<<dim3(32, 16, 2), 256, 0, stream>>>(Qh, Ql, Kh, Kl, Vth, Vtl,
      smooth, catq, 2048, 0);
  k_attn<<<dim3(32, 16, 2), 256, 0, stream>>>(Qxh, Qxl, Kxh, Kxl, Vxth, Vxtl,
      smooth, catq, 512, 2048);

  k_gemm<2><<<dim3(16, 32), 256, 0, stream>>>(catq, nullptr, Wpb, nullptr,
      4096, 2048, 4096, scales,
      qln_w, qln_b, kln_w, kln_b, qxln_w, qxln_b, kxln_w, kxln_b,
      nullptr, nullptr, nullptr, nullptr, nullptr, nullptr, nullptr, nullptr,
      nullptr, nullptr, nullptr, nullptr, (float*)d_out);
}

// Round 2
// 897.612 us; speedup vs baseline: 1.2035x; 1.2035x over previous
//
#include <hip/hip_runtime.h>
#include <hip/hip_bf16.h>
#include <stdint.h>

#define B_  2
#define S_  2048
#define SC_ 512
#define H_  2048
#define NH_ 16
#define G_  8
#define D_  128

typedef __attribute__((ext_vector_type(8))) short bf16x8;
typedef __attribute__((ext_vector_type(4))) float f32x4;

#define GLOAD_LDS16(g, l) __builtin_amdgcn_global_load_lds( \
    (const __attribute__((address_space(1))) uint32_t*)(g), \
    (__attribute__((address_space(3))) uint32_t*)(l), 16, 0, 0)

__device__ __forceinline__ uint16_t bf16_rne_bits(float x) {
  uint32_t u = __float_as_uint(x);
  u += 0x7fffu + ((u >> 16) & 1u);
  return (uint16_t)(u >> 16);
}
__device__ __forceinline__ float bf16_rne_f(float x) {
  uint32_t u = __float_as_uint(x);
  u += 0x7fffu + ((u >> 16) & 1u);
  return __uint_as_float(u & 0xffff0000u);
}
// fp8 e4m3fn round-trip (RNE, input already clipped to [-448,448])
__device__ __forceinline__ float fp8_rt(float x) {
  float a = fabsf(x);
  float step;
  if (a >= 0.015625f) {
    uint32_t u = __float_as_uint(a);
    int E = (int)((u >> 23) & 0xffu) - 127;
    step = __uint_as_float((uint32_t)(E - 3 + 127) << 23);
  } else {
    step = 0.001953125f;
  }
  float q = rintf(a / step) * step;
  return x < 0.f ? -q : q;
}

// ---------------- prep: weight casts / splits / scalar scales ----------------
__global__ __launch_bounds__(256) void k_prep(
    const float* __restrict__ wq, const float* __restrict__ wqx,
    const float* __restrict__ wk, const float* __restrict__ wv,
    const float* __restrict__ wkvx, const float* __restrict__ wproj,
    const float* __restrict__ cond,
    const float* __restrict__ q_is, const float* __restrict__ wq_s,
    const float* __restrict__ qx_is, const float* __restrict__ wqx_s,
    const float* __restrict__ k_is, const float* __restrict__ wk_s,
    const float* __restrict__ v_is, const float* __restrict__ wv_s,
    const float* __restrict__ p_is, const float* __restrict__ p_ws,
    uint16_t* __restrict__ Wcat, uint16_t* __restrict__ Wpb,
    uint16_t* __restrict__ Wkvxh, uint16_t* __restrict__ Wkvxl,
    uint16_t* __restrict__ condh, uint16_t* __restrict__ condl,
    float* __restrict__ scales)
{
  size_t idx = (size_t)blockIdx.x * 256 + threadIdx.x;
  size_t stride = (size_t)gridDim.x * 256;
  const size_t NC = (size_t)6144 * 2048;
  for (size_t i = idx; i < NC; i += stride) {
    size_t row = i >> 11; int col = (int)(i & 2047);
    float v;
    if (row < 2048)      v = wq[i];
    else if (row < 4096) v = wqx[(row - 2048) * 2048 + col];
    else if (row < 5120) v = wk[(row - 4096) * 2048 + col];
    else                 v = wv[(row - 5120) * 2048 + col];
    Wcat[i] = (uint16_t)(__float_as_uint(v) >> 16);  // fp8 values: exact in bf16
  }
  const size_t NP = (size_t)2048 * 4096;
  for (size_t i = idx; i < NP; i += stride)
    Wpb[i] = (uint16_t)(__float_as_uint(wproj[i]) >> 16);
  const size_t NX = (size_t)2048 * 2048;
  for (size_t i = idx; i < NX; i += stride) {
    float x = wkvx[i];
    uint16_t h = bf16_rne_bits(x);
    Wkvxh[i] = h;
    Wkvxl[i] = bf16_rne_bits(x - __uint_as_float((uint32_t)h << 16));
  }
  const size_t ND = (size_t)1024 * 2048;
  for (size_t i = idx; i < ND; i += stride) {
    float x = cond[i];
    uint16_t h = bf16_rne_bits(x);
    condh[i] = h;
    condl[i] = bf16_rne_bits(x - __uint_as_float((uint32_t)h << 16));
  }
  if (idx == 0) {
    scales[0] = q_is[0] * wq_s[0];
    scales[1] = qx_is[0] * wqx_s[0];
    scales[2] = k_is[0] * wk_s[0];
    scales[3] = v_is[0] * wv_s[0];
    scales[4] = p_is[0] * p_ws[0];
  }
}

// ---------------- hidden LayerNorm + fp8 quantize -> Aq ----------------------
__global__ __launch_bounds__(256) void k_ln_quant(
    const float* __restrict__ x, const float* __restrict__ w,
    const float* __restrict__ b, const float* __restrict__ qis,
    uint16_t* __restrict__ Aq)
{
  int row = blockIdx.x;
  int tid = threadIdx.x;
  const float* xr = x + (size_t)row * H_;
  float v[8];
  float s = 0.f, sq = 0.f;
#pragma unroll
  for (int i = 0; i < 8; i++) {
    float t = xr[tid + i * 256];
    v[i] = t; s += t; sq += t * t;
  }
#pragma unroll
  for (int m = 1; m < 64; m <<= 1) { s += __shfl_xor(s, m); sq += __shfl_xor(sq, m); }
  __shared__ float red[8];
  int wv = tid >> 6;
  if ((tid & 63) == 0) { red[wv] = s; red[4 + wv] = sq; }
  __syncthreads();
  s = red[0] + red[1] + red[2] + red[3];
  sq = red[4] + red[5] + red[6] + red[7];
  float mu = s * (1.f / H_);
  float var = sq * (1.f / H_) - mu * mu;
  float rs = 1.0f / sqrtf(var + 1e-5f);
#pragma unroll
  for (int i = 0; i < 8; i++) {
    int c = tid + i * 256;
    float y = (v[i] - mu) * rs * w[c] + b[c];
    float t = y / qis[c];
    t = fminf(fmaxf(t, -448.f), 448.f);
    t = fp8_rt(bf16_rne_f(t));
    Aq[(size_t)row * H_ + c] = bf16_rne_bits(t);
  }
}

// ---------------- m97-structure GEMM (B^T), global_load_lds + XOR swizzle ----
// MODE 0: QKV proj -> per-head LN -> hi/lo planes (V: hi only, transposed)
// MODE 2: out proj -> *scale -> f32 out
template <int MODE>
__global__ __launch_bounds__(256) void k_gemm2(
    const uint16_t* __restrict__ A, const uint16_t* __restrict__ Bm,
    int M, int N, int K,
    const float* __restrict__ scales,
    const float* __restrict__ qln_w, const float* __restrict__ qln_b,
    const float* __restrict__ kln_w, const float* __restrict__ kln_b,
    const float* __restrict__ qxln_w, const float* __restrict__ qxln_b,
    uint16_t* __restrict__ Qh, uint16_t* __restrict__ Ql,
    uint16_t* __restrict__ Qxh, uint16_t* __restrict__ Qxl,
    uint16_t* __restrict__ Kh, uint16_t* __restrict__ Kl,
    uint16_t* __restrict__ Vth,
    float* __restrict__ Cout)
{
  __shared__ __align__(16) uint16_t lA[128 * 32];
  __shared__ __align__(16) uint16_t lB[128 * 32];
  __shared__ float sred[512];

  const int tid = threadIdx.x;
  const int lane = tid & 63;
  const int wv = tid >> 6;
  const int wr = wv >> 1, wc = wv & 1;
  const int l15 = lane & 15, l4 = lane >> 4;
  const int m0 = blockIdx.y * 128, n0 = blockIdx.x * 128;

  // staging chunk geometry: chunk i (0..511) -> row=i>>2, swz col-group = (i&3)^(row&3)
  int arow[2], acg[2];
#pragma unroll
  for (int c = 0; c < 2; c++) {
    int i = c * 256 + tid;
    arow[c] = i >> 2;
    acg[c] = (i & 3) ^ (arow[c] & 3);
  }
  // frag read chunk-xor (row&3 == l15&3 for all mt)
  const int axo = ((l4 ^ (l15 & 3)) * 8);

  f32x4 acc[4][4] = {};

  for (int kt = 0; kt < K; kt += 32) {
    __syncthreads();
#pragma unroll
    for (int c = 0; c < 2; c++) {
      GLOAD_LDS16(&A[(size_t)(m0 + arow[c]) * K + kt + acg[c] * 8],
                  &lA[(c * 256 + wv * 64) * 8]);
      GLOAD_LDS16(&Bm[(size_t)(n0 + arow[c]) * K + kt + acg[c] * 8],
                  &lB[(c * 256 + wv * 64) * 8]);
    }
    __syncthreads();  // vmcnt(0) drain before barrier -> tiles ready
    bf16x8 af[4];
#pragma unroll
    for (int mt = 0; mt < 4; mt++)
      af[mt] = *(bf16x8*)&lA[(wr * 64 + mt * 16 + l15) * 32 + axo];
#pragma unroll
    for (int nt = 0; nt < 4; nt++) {
      bf16x8 bh = *(bf16x8*)&lB[(wc * 64 + nt * 16 + l15) * 32 + axo];
#pragma unroll
      for (int mt = 0; mt < 4; mt++)
        acc[mt][nt] = __builtin_amdgcn_mfma_f32_16x16x32_bf16(af[mt], bh, acc[mt][nt], 0, 0, 0);
    }
  }

  const int cb = n0 >> 7;
  float sscale;
  const float *lw = nullptr, *lb = nullptr;
  if (MODE == 0) {
    int sect = (cb < 16) ? 0 : (cb < 32) ? 1 : (cb < 40) ? 2 : 3;
    sscale = scales[sect];
    if (sect == 0) { lw = qln_w; lb = qln_b; }
    else if (sect == 1) { lw = qxln_w; lb = qxln_b; }
    else if (sect == 2) { lw = kln_w; lb = kln_b; }
  } else {
    sscale = scales[4];
  }
#pragma unroll
  for (int mt = 0; mt < 4; mt++)
#pragma unroll
    for (int nt = 0; nt < 4; nt++)
#pragma unroll
      for (int j = 0; j < 4; j++) acc[mt][nt][j] *= sscale;

  if (MODE == 2) {
#pragma unroll
    for (int mt = 0; mt < 4; mt++)
#pragma unroll
      for (int j = 0; j < 4; j++) {
        int r = m0 + wr * 64 + mt * 16 + l4 * 4 + j;
#pragma unroll
        for (int nt = 0; nt < 4; nt++) {
          int c = n0 + wc * 64 + nt * 16 + l15;
          Cout[(size_t)r * N + c] = acc[mt][nt][j];
        }
      }
    return;
  }

  float mu_[4][4], rs_[4][4];
#pragma unroll
  for (int mt = 0; mt < 4; mt++)
#pragma unroll
    for (int j = 0; j < 4; j++) { mu_[mt][j] = 0.f; rs_[mt][j] = 1.f; }

  if (lw) {  // per-head LN over the 128-col tile
#pragma unroll
    for (int mt = 0; mt < 4; mt++)
#pragma unroll
      for (int j = 0; j < 4; j++) {
        float s = 0.f, sq = 0.f;
#pragma unroll
        for (int nt = 0; nt < 4; nt++) { float t = acc[mt][nt][j]; s += t; sq += t * t; }
#pragma unroll
        for (int mm = 1; mm < 16; mm <<= 1) { s += __shfl_xor(s, mm); sq += __shfl_xor(sq, mm); }
        if (l15 == 0) {
          int ar = wr * 64 + mt * 16 + l4 * 4 + j;
          sred[wc * 128 + ar] = s;
          sred[256 + wc * 128 + ar] = sq;
        }
      }
    __syncthreads();
#pragma unroll
    for (int mt = 0; mt < 4; mt++)
#pragma unroll
      for (int j = 0; j < 4; j++) {
        int ar = wr * 64 + mt * 16 + l4 * 4 + j;
        float Sm = sred[ar] + sred[128 + ar];
        float Sq = sred[256 + ar] + sred[384 + ar];
        float mu = Sm * (1.f / 128.f);
        float var = Sq * (1.f / 128.f) - mu * mu;
        mu_[mt][j] = mu;
        rs_[mt][j] = 1.f / sqrtf(var + 1e-5f);
      }
  }

#pragma unroll
  for (int mt = 0; mt < 4; mt++)
#pragma unroll
    for (int j = 0; j < 4; j++) {
      int r = m0 + wr * 64 + mt * 16 + l4 * 4 + j;
#pragma unroll
      for (int nt = 0; nt < 4; nt++) {
        int d = wc * 64 + nt * 16 + l15;
        float y = acc[mt][nt][j];
        if (lw) y = (y - mu_[mt][j]) * rs_[mt][j] * lw[d] + lb[d];
        uint16_t hb = bf16_rne_bits(y);
        uint16_t *Dh, *Dl = nullptr; size_t o;
        if (cb < 16)      { Dh = Qh;  Dl = Ql;  o = ((size_t)r * NH_ + cb) * D_ + d; }
        else if (cb < 32) { Dh = Qxh; Dl = Qxl; o = ((size_t)r * NH_ + (cb - 16)) * D_ + d; }
        else if (cb < 40) { Dh = Kh;  Dl = Kl;  o = ((size_t)r * G_ + (cb - 32)) * D_ + d; }
        else { Dh = Vth; int gg = cb - 40;      // V: hi plane only, transposed [b][g][d][t]
               o = (((size_t)(r >> 11) * G_ + gg) * D_ + d) * (size_t)S_ + (r & 2047); }
        Dh[o] = hb;
        if (Dl) Dl[o] = bf16_rne_bits(y - __uint_as_float((uint32_t)hb << 16));
      }
    }
}

// ---------------- old-style GEMM for MODE 1 (kvx: split A, split B) ----------
__global__ __launch_bounds__(256) void k_gemm_kvx(
    const uint16_t* __restrict__ Ah, const uint16_t* __restrict__ Al,
    const uint16_t* __restrict__ Bh, const uint16_t* __restrict__ Bl,
    int M, int N, int K,
    const float* __restrict__ kxln_w, const float* __restrict__ kxln_b,
    uint16_t* __restrict__ Kxh, uint16_t* __restrict__ Kxl,
    uint16_t* __restrict__ Vxth)
{
  __shared__ __align__(16) uint16_t lA[128 * 40];
  __shared__ __align__(16) uint16_t lB[128 * 40];
  __shared__ __align__(16) uint16_t lA2[128 * 40];
  __shared__ __align__(16) uint16_t lB2[128 * 40];
  __shared__ float sred[512];

  const int tid = threadIdx.x;
  const int lane = tid & 63;
  const int wv = tid >> 6;
  const int wr = wv >> 1, wc = wv & 1;
  const int l15 = lane & 15, l4 = lane >> 4;
  const int m0 = blockIdx.y * 128, n0 = blockIdx.x * 128;

  f32x4 acc[4][4] = {};

  for (int kt = 0; kt < K; kt += 32) {
    __syncthreads();
#pragma unroll
    for (int i = 0; i < 2; i++) {
      int c = tid + i * 256;
      int row = c >> 2, kc = (c & 3) * 8;
      *(bf16x8*)&lA[row * 40 + kc] = *(const bf16x8*)&Ah[(size_t)(m0 + row) * K + kt + kc];
      *(bf16x8*)&lB[row * 40 + kc] = *(const bf16x8*)&Bh[(size_t)(n0 + row) * K + kt + kc];
      *(bf16x8*)&lA2[row * 40 + kc] = *(const bf16x8*)&Al[(size_t)(m0 + row) * K + kt + kc];
      *(bf16x8*)&lB2[row * 40 + kc] = *(const bf16x8*)&Bl[(size_t)(n0 + row) * K + kt + kc];
    }
    __syncthreads();
    bf16x8 af[4], af2[4];
#pragma unroll
    for (int mt = 0; mt < 4; mt++) {
      af[mt] = *(bf16x8*)&lA[(wr * 64 + mt * 16 + l15) * 40 + l4 * 8];
      af2[mt] = *(bf16x8*)&lA2[(wr * 64 + mt * 16 + l15) * 40 + l4 * 8];
    }
#pragma unroll
    for (int nt = 0; nt < 4; nt++) {
      bf16x8 bh = *(bf16x8*)&lB[(wc * 64 + nt * 16 + l15) * 40 + l4 * 8];
      bf16x8 bl = *(bf16x8*)&lB2[(wc * 64 + nt * 16 + l15) * 40 + l4 * 8];
#pragma unroll
      for (int mt = 0; mt < 4; mt++) {
        acc[mt][nt] = __builtin_amdgcn_mfma_f32_16x16x32_bf16(af[mt], bh, acc[mt][nt], 0, 0, 0);
        acc[mt][nt] = __builtin_amdgcn_mfma_f32_16x16x32_bf16(af[mt], bl, acc[mt][nt], 0, 0, 0);
        acc[mt][nt] = __builtin_amdgcn_mfma_f32_16x16x32_bf16(af2[mt], bh, acc[mt][nt], 0, 0, 0);
      }
    }
  }

  const int cb = n0 >> 7;
  const float *lw = nullptr, *lb = nullptr;
  if (cb < 8) { lw = kxln_w; lb = kxln_b; }

  float mu_[4][4], rs_[4][4];
#pragma unroll
  for (int mt = 0; mt < 4; mt++)
#pragma unroll
    for (int j = 0; j < 4; j++) { mu_[mt][j] = 0.f; rs_[mt][j] = 1.f; }

  if (lw) {
#pragma unroll
    for (int mt = 0; mt < 4; mt++)
#pragma unroll
      for (int j = 0; j < 4; j++) {
        float s = 0.f, sq = 0.f;
#pragma unroll
        for (int nt = 0; nt < 4; nt++) { float t = acc[mt][nt][j]; s += t; sq += t * t; }
#pragma unroll
        for (int mm = 1; mm < 16; mm <<= 1) { s += __shfl_xor(s, mm); sq += __shfl_xor(sq, mm); }
        if (l15 == 0) {
          int ar = wr * 64 + mt * 16 + l4 * 4 + j;
          sred[wc * 128 + ar] = s;
          sred[256 + wc * 128 + ar] = sq;
        }
      }
    __syncthreads();
#pragma unroll
    for (int mt = 0; mt < 4; mt++)
#pragma unroll
      for (int j = 0; j < 4; j++) {
        int ar = wr * 64 + mt * 16 + l4 * 4 + j;
        float Sm = sred[ar] + sred[128 + ar];
        float Sq = sred[256 + ar] + sred[384 + ar];
        float mu = Sm * (1.f / 128.f);
        float var = Sq * (1.f / 128.f) - mu * mu;
        mu_[mt][j] = mu;
        rs_[mt][j] = 1.f / sqrtf(var + 1e-5f);
      }
  }

#pragma unroll
  for (int mt = 0; mt < 4; mt++)
#pragma unroll
    for (int j = 0; j < 4; j++) {
      int r = m0 + wr * 64 + mt * 16 + l4 * 4 + j;
#pragma unroll
      for (int nt = 0; nt < 4; nt++) {
        int d = wc * 64 + nt * 16 + l15;
        float y = acc[mt][nt][j];
        if (lw) y = (y - mu_[mt][j]) * rs_[mt][j] * lw[d] + lb[d];
        uint16_t hb = bf16_rne_bits(y);
        if (cb < 8) {
          size_t o = ((size_t)r * G_ + cb) * D_ + d;
          Kxh[o] = hb;
          Kxl[o] = bf16_rne_bits(y - __uint_as_float((uint32_t)hb << 16));
        } else {
          int gg = cb - 8;  // V: hi only, transposed
          size_t o = (((size_t)(r >> 9) * G_ + gg) * D_ + d) * (size_t)SC_ + (r & 511);
          Vxth[o] = hb;
        }
      }
    }
}

// ---------------- flash GQA attention v2 ------------------------------------
// QK^T: 3-MFMA hi/lo split. PV: single MFMA (ph*vh). global_load_lds staging
// with XOR-swizzled LDS; defer-max (THR=8); setprio around MFMA clusters.
__global__ __launch_bounds__(256) void k_attn(
    const uint16_t* __restrict__ Qh, const uint16_t* __restrict__ Ql,
    const uint16_t* __restrict__ Kh, const uint16_t* __restrict__ Kl,
    const uint16_t* __restrict__ Vth,
    const float* __restrict__ smooth, uint16_t* __restrict__ catq,
    int T, int colOff)
{
  __shared__ __align__(16) uint16_t lKh[32 * 128];
  __shared__ __align__(16) uint16_t lKl[32 * 128];
  __shared__ __align__(16) uint16_t lV[128 * 32];
  __shared__ __align__(16) uint16_t lPh[64 * 40];

  const int tid = threadIdx.x, lane = tid & 63, wv = tid >> 6;
  const int l15 = lane & 15, l4 = lane >> 4;
  const int q0 = blockIdx.x * 64, h = blockIdx.y, b = blockIdx.z;
  const int g = h >> 1;

  bf16x8 qfh[4], qfl[4];
  {
    int srow = q0 + wv * 16 + l15;
    size_t base = (((size_t)b * S_ + srow) * NH_ + h) * (size_t)D_ + l4 * 8;
#pragma unroll
    for (int ks = 0; ks < 4; ks++) {
      qfh[ks] = *(const bf16x8*)&Qh[base + ks * 32];
      qfl[ks] = *(const bf16x8*)&Ql[base + ks * 32];
    }
  }

  // staging chunk geometry
  int krow[2], kcg[2], vrow[2], vcg[2];
#pragma unroll
  for (int c = 0; c < 2; c++) {
    int i = c * 256 + tid;
    krow[c] = i >> 4;                      // K tile row t (0..31), 16 chunks/row
    kcg[c] = (i & 15) ^ (krow[c] & 7);     // swizzled col-group
    vrow[c] = i >> 2;                      // V tile row d (0..127), 4 chunks/row
    vcg[c] = (i & 3) ^ (vrow[c] & 3);
  }
  // frag read offsets (halves)
  int koff[2][4];
#pragma unroll
  for (int nt = 0; nt < 2; nt++)
#pragma unroll
    for (int ks = 0; ks < 4; ks++)
      koff[nt][ks] = (nt * 16 + l15) * 128 + (((ks * 4 + l4) ^ (l15 & 7)) * 8);
  const int vxo = (l4 ^ (l15 & 3)) * 8;

  float mrun[4] = {-1e30f, -1e30f, -1e30f, -1e30f};
  float lsum[4] = {0.f, 0.f, 0.f, 0.f};
  f32x4 oacc[8] = {};

  const int nT = T >> 5;
  for (int tt = 0; tt < nT; tt++) {
    const int t0 = tt << 5;
    __syncthreads();
#pragma unroll
    for (int c = 0; c < 2; c++) {
      size_t ga = (((size_t)b * T + (t0 + krow[c])) * G_ + g) * (size_t)D_ + kcg[c] * 8;
      GLOAD_LDS16(&Kh[ga], &lKh[(c * 256 + wv * 64) * 8]);
      GLOAD_LDS16(&Kl[ga], &lKl[(c * 256 + wv * 64) * 8]);
      size_t gv = (((size_t)b * G_ + g) * (size_t)D_ + vrow[c]) * (size_t)T + t0 + vcg[c] * 8;
      GLOAD_LDS16(&Vth[gv], &lV[(c * 256 + wv * 64) * 8]);
    }
    __syncthreads();  // vmcnt drain -> tiles ready

    f32x4 sf[2];
    __builtin_amdgcn_s_setprio(1);
#pragma unroll
    for (int nt = 0; nt < 2; nt++) {
      f32x4 a = {0.f, 0.f, 0.f, 0.f};
#pragma unroll
      for (int ks = 0; ks < 4; ks++) {
        bf16x8 kh = *(bf16x8*)&lKh[koff[nt][ks]];
        bf16x8 kl = *(bf16x8*)&lKl[koff[nt][ks]];
        a = __builtin_amdgcn_mfma_f32_16x16x32_bf16(qfh[ks], kh, a, 0, 0, 0);
        a = __builtin_amdgcn_mfma_f32_16x16x32_bf16(qfh[ks], kl, a, 0, 0, 0);
        a = __builtin_amdgcn_mfma_f32_16x16x32_bf16(qfl[ks], kh, a, 0, 0, 0);
      }
      sf[nt] = a;
    }
    __builtin_amdgcn_s_setprio(0);

    const float SCL = 0.08838834764831845f;  // 1/sqrt(128)
#pragma unroll
    for (int j = 0; j < 4; j++) {
      float s0 = sf[0][j] * SCL, s1 = sf[1][j] * SCL;
      float tm = fmaxf(s0, s1);
#pragma unroll
      for (int mm = 1; mm < 16; mm <<= 1) tm = fmaxf(tm, __shfl_xor(tm, mm));
      bool resc = (tm > mrun[j] + 8.f);   // defer-max: only rescale on big jump
      if (resc) {
        float al = __expf(mrun[j] - tm);
        mrun[j] = tm;
        lsum[j] *= al;
#pragma unroll
        for (int dt = 0; dt < 8; dt++) oacc[dt][j] *= al;
      }
      float p0 = __expf(s0 - mrun[j]), p1 = __expf(s1 - mrun[j]);
      float rsum = p0 + p1;
#pragma unroll
      for (int mm = 1; mm < 16; mm <<= 1) rsum += __shfl_xor(rsum, mm);
      lsum[j] += rsum;
      int prow = wv * 16 + l4 * 4 + j;
      lPh[prow * 40 + l15] = bf16_rne_bits(p0);
      lPh[prow * 40 + 16 + l15] = bf16_rne_bits(p1);
    }

    bf16x8 pah = *(bf16x8*)&lPh[(wv * 16 + l15) * 40 + l4 * 8];
    __builtin_amdgcn_s_setprio(1);
#pragma unroll
    for (int dt = 0; dt < 8; dt++) {
      bf16x8 vh = *(bf16x8*)&lV[(dt * 16 + l15) * 32 + vxo];
      oacc[dt] = __builtin_amdgcn_mfma_f32_16x16x32_bf16(pah, vh, oacc[dt], 0, 0, 0);
    }
    __builtin_amdgcn_s_setprio(0);
  }

#pragma unroll
  for (int j = 0; j < 4; j++) {
    float inv = 1.f / lsum[j];
    int srow = q0 + wv * 16 + l4 * 4 + j;
    size_t rbase = ((size_t)b * S_ + srow) * 4096;
#pragma unroll
    for (int dt = 0; dt < 8; dt++) {
      int c = colOff + h * D_ + dt * 16 + l15;
      float t = (oacc[dt][j] * inv) / smooth[c];
      t = fminf(fmaxf(t, -448.f), 448.f);
      t = fp8_rt(bf16_rne_f(t));
      catq[rbase + c] = bf16_rne_bits(t);
    }
  }
}

// ---------------------------------------------------------------------------
extern "C" void kernel_launch(void* const* d_in, const int* in_sizes, int n_in,
                              void* d_out, int out_size, void* d_ws, size_t ws_size,
                              hipStream_t stream)
{
  (void)in_sizes; (void)n_in; (void)out_size;
  const float* hidden = (const float*)d_in[0];
  const float* cond   = (const float*)d_in[1];
  const float* ln_w   = (const float*)d_in[2];
  const float* ln_b   = (const float*)d_in[3];
  const float* wq     = (const float*)d_in[4];
  const float* wq_s   = (const float*)d_in[5];
  const float* q_is   = (const float*)d_in[6];
  const float* wqx    = (const float*)d_in[7];
  const float* wqx_s  = (const float*)d_in[8];
  const float* qx_is  = (const float*)d_in[9];
  const float* wk     = (const float*)d_in[10];
  const float* wk_s   = (const float*)d_in[11];
  const float* k_is   = (const float*)d_in[12];
  const float* wv     = (const float*)d_in[13];
  const float* wv_s   = (const float*)d_in[14];
  const float* v_is   = (const float*)d_in[15];
  const float* wkvx   = (const float*)d_in[16];
  const float* qln_w  = (const float*)d_in[17];
  const float* qln_b  = (const float*)d_in[18];
  const float* kln_w  = (const float*)d_in[19];
  const float* kln_b  = (const float*)d_in[20];
  const float* qxln_w = (const float*)d_in[21];
  const float* qxln_b = (const float*)d_in[22];
  const float* kxln_w = (const float*)d_in[23];
  const float* kxln_b = (const float*)d_in[24];
  const float* wproj  = (const float*)d_in[25];
  const float* p_ws   = (const float*)d_in[26];
  const float* p_is   = (const float*)d_in[27];
  const float* smooth = (const float*)d_in[28];

  char* ws = (char*)d_ws;
  size_t off = 0;
  auto alloc = [&](size_t bytes) {
    char* p = ws + off;
    off += (bytes + 255) & ~(size_t)255;
    return p;
  };
  uint16_t* Aq    = (uint16_t*)alloc((size_t)4096 * 2048 * 2);
  uint16_t* Wcat  = (uint16_t*)alloc((size_t)6144 * 2048 * 2);
  uint16_t* Wpb   = (uint16_t*)alloc((size_t)2048 * 4096 * 2);
  uint16_t* Wkvxh = (uint16_t*)alloc((size_t)2048 * 2048 * 2);
  uint16_t* Wkvxl = (uint16_t*)alloc((size_t)2048 * 2048 * 2);
  uint16_t* condh = (uint16_t*)alloc((size_t)1024 * 2048 * 2);
  uint16_t* condl = (uint16_t*)alloc((size_t)1024 * 2048 * 2);
  uint16_t* Qh    = (uint16_t*)alloc((size_t)4096 * 16 * 128 * 2);
  uint16_t* Ql    = (uint16_t*)alloc((size_t)4096 * 16 * 128 * 2);
  uint16_t* Qxh   = (uint16_t*)alloc((size_t)4096 * 16 * 128 * 2);
  uint16_t* Qxl   = (uint16_t*)alloc((size_t)4096 * 16 * 128 * 2);
  uint16_t* Kh    = (uint16_t*)alloc((size_t)4096 * 8 * 128 * 2);
  uint16_t* Kl    = (uint16_t*)alloc((size_t)4096 * 8 * 128 * 2);
  uint16_t* Vth   = (uint16_t*)alloc((size_t)4096 * 8 * 128 * 2);
  uint16_t* Kxh   = (uint16_t*)alloc((size_t)1024 * 8 * 128 * 2);
  uint16_t* Kxl   = (uint16_t*)alloc((size_t)1024 * 8 * 128 * 2);
  uint16_t* Vxth  = (uint16_t*)alloc((size_t)1024 * 8 * 128 * 2);
  uint16_t* catq  = (uint16_t*)alloc((size_t)4096 * 4096 * 2);
  float* scales   = (float*)alloc(256);
  if (ws_size < off) return;

  k_prep<<<2048, 256, 0, stream>>>(wq, wqx, wk, wv, wkvx, wproj, cond,
      q_is, wq_s, qx_is, wqx_s, k_is, wk_s, v_is, wv_s, p_is, p_ws,
      Wcat, Wpb, Wkvxh, Wkvxl, condh, condl, scales);

  k_ln_quant<<<4096, 256, 0, stream>>>(hidden, ln_w, ln_b, q_is, Aq);

  k_gemm2<0><<<dim3(48, 32), 256, 0, stream>>>(Aq, Wcat,
      4096, 6144, 2048, scales, qln_w, qln_b, kln_w, kln_b, qxln_w, qxln_b,
      Qh, Ql, Qxh, Qxl, Kh, Kl, Vth, nullptr);

  k_gemm_kvx<<<dim3(16, 8), 256, 0, stream>>>(condh, condl, Wkvxh, Wkvxl,
      1024, 2048, 2048, kxln_w, kxln_b, Kxh, Kxl, Vxth);

  k_attn<<<dim3(32, 16, 2), 256, 0, stream>>>(Qh, Ql, Kh, Kl, Vth,
      smooth, catq, 2048, 0);
  k_attn<<<dim3(32, 16, 2), 256, 0, stream>>>(Qxh, Qxl, Kxh, Kxl, Vxth,
      smooth, catq, 512, 2048);

  k_gemm2<2><<<dim3(16, 32), 256, 0, stream>>>(catq, Wpb,
      4096, 2048, 4096, scales, nullptr, nullptr, nullptr, nullptr, nullptr, nullptr,
      nullptr, nullptr, nullptr, nullptr, nullptr, nullptr, nullptr,
      (float*)d_out);
}

// Round 3
// 709.129 us; speedup vs baseline: 1.5234x; 1.2658x over previous
//
#include <hip/hip_runtime.h>
#include <hip/hip_bf16.h>
#include <stdint.h>

#define B_  2
#define S_  2048
#define SC_ 512
#define H_  2048
#define NH_ 16
#define G_  8
#define D_  128

typedef __attribute__((ext_vector_type(8))) short bf16x8;
typedef __attribute__((ext_vector_type(8))) _Float16 f16x8;
typedef __attribute__((ext_vector_type(4))) float f32x4;

#define GLOAD_LDS16(g, l) __builtin_amdgcn_global_load_lds( \
    (const __attribute__((address_space(1))) uint32_t*)(g), \
    (__attribute__((address_space(3))) uint32_t*)(l), 16, 0, 0)

__device__ __forceinline__ uint16_t bf16_rne_bits(float x) {
  uint32_t u = __float_as_uint(x);
  u += 0x7fffu + ((u >> 16) & 1u);
  return (uint16_t)(u >> 16);
}
__device__ __forceinline__ float bf16_rne_f(float x) {
  uint32_t u = __float_as_uint(x);
  u += 0x7fffu + ((u >> 16) & 1u);
  return __uint_as_float(u & 0xffff0000u);
}
__device__ __forceinline__ uint16_t f16_bits(float x) {
  _Float16 h = (_Float16)x;
  return __builtin_bit_cast(uint16_t, h);
}
__device__ __forceinline__ float f16_val(uint16_t b) {
  return (float)__builtin_bit_cast(_Float16, b);
}
// fp8 e4m3fn round-trip (RNE, input already clipped to [-448,448])
__device__ __forceinline__ float fp8_rt(float x) {
  float a = fabsf(x);
  float step;
  if (a >= 0.015625f) {
    uint32_t u = __float_as_uint(a);
    int E = (int)((u >> 23) & 0xffu) - 127;
    step = __uint_as_float((uint32_t)(E - 3 + 127) << 23);
  } else {
    step = 0.001953125f;
  }
  float q = rintf(a / step) * step;
  return x < 0.f ? -q : q;
}

// ---------------- prep: weight casts / splits / scalar scales ----------------
__global__ __launch_bounds__(256) void k_prep(
    const float* __restrict__ wq, const float* __restrict__ wqx,
    const float* __restrict__ wk, const float* __restrict__ wv,
    const float* __restrict__ wkvx, const float* __restrict__ wproj,
    const float* __restrict__ cond,
    const float* __restrict__ q_is, const float* __restrict__ wq_s,
    const float* __restrict__ qx_is, const float* __restrict__ wqx_s,
    const float* __restrict__ k_is, const float* __restrict__ wk_s,
    const float* __restrict__ v_is, const float* __restrict__ wv_s,
    const float* __restrict__ p_is, const float* __restrict__ p_ws,
    uint16_t* __restrict__ Wcat, uint16_t* __restrict__ Wpb,
    uint16_t* __restrict__ Wkvxh, uint16_t* __restrict__ Wkvxl,
    uint16_t* __restrict__ condh, uint16_t* __restrict__ condl,
    float* __restrict__ scales)
{
  size_t idx = (size_t)blockIdx.x * 256 + threadIdx.x;
  size_t stride = (size_t)gridDim.x * 256;
  const size_t NC = (size_t)6144 * 2048;
  for (size_t i = idx; i < NC; i += stride) {
    size_t row = i >> 11; int col = (int)(i & 2047);
    float v;
    if (row < 2048)      v = wq[i];
    else if (row < 4096) v = wqx[(row - 2048) * 2048 + col];
    else if (row < 5120) v = wk[(row - 4096) * 2048 + col];
    else                 v = wv[(row - 5120) * 2048 + col];
    Wcat[i] = (uint16_t)(__float_as_uint(v) >> 16);  // fp8 values: exact in bf16
  }
  const size_t NP = (size_t)2048 * 4096;
  for (size_t i = idx; i < NP; i += stride)
    Wpb[i] = (uint16_t)(__float_as_uint(wproj[i]) >> 16);
  const size_t NX = (size_t)2048 * 2048;
  for (size_t i = idx; i < NX; i += stride) {
    float x = wkvx[i];
    uint16_t h = bf16_rne_bits(x);
    Wkvxh[i] = h;
    Wkvxl[i] = bf16_rne_bits(x - __uint_as_float((uint32_t)h << 16));
  }
  const size_t ND = (size_t)1024 * 2048;
  for (size_t i = idx; i < ND; i += stride) {
    float x = cond[i];
    uint16_t h = bf16_rne_bits(x);
    condh[i] = h;
    condl[i] = bf16_rne_bits(x - __uint_as_float((uint32_t)h << 16));
  }
  if (idx == 0) {
    scales[0] = q_is[0] * wq_s[0];
    scales[1] = qx_is[0] * wqx_s[0];
    scales[2] = k_is[0] * wk_s[0];
    scales[3] = v_is[0] * wv_s[0];
    scales[4] = p_is[0] * p_ws[0];
  }
}

// ---------------- hidden LayerNorm + fp8 quantize -> Aq ----------------------
__global__ __launch_bounds__(256) void k_ln_quant(
    const float* __restrict__ x, const float* __restrict__ w,
    const float* __restrict__ b, const float* __restrict__ qis,
    uint16_t* __restrict__ Aq)
{
  int row = blockIdx.x;
  int tid = threadIdx.x;
  const float* xr = x + (size_t)row * H_;
  float v[8];
  float s = 0.f, sq = 0.f;
#pragma unroll
  for (int i = 0; i < 8; i++) {
    float t = xr[tid + i * 256];
    v[i] = t; s += t; sq += t * t;
  }
#pragma unroll
  for (int m = 1; m < 64; m <<= 1) { s += __shfl_xor(s, m); sq += __shfl_xor(sq, m); }
  __shared__ float red[8];
  int wv = tid >> 6;
  if ((tid & 63) == 0) { red[wv] = s; red[4 + wv] = sq; }
  __syncthreads();
  s = red[0] + red[1] + red[2] + red[3];
  sq = red[4] + red[5] + red[6] + red[7];
  float mu = s * (1.f / H_);
  float var = sq * (1.f / H_) - mu * mu;
  float rs = 1.0f / sqrtf(var + 1e-5f);
#pragma unroll
  for (int i = 0; i < 8; i++) {
    int c = tid + i * 256;
    float y = (v[i] - mu) * rs * w[c] + b[c];
    float t = y / qis[c];
    t = fminf(fmaxf(t, -448.f), 448.f);
    t = fp8_rt(bf16_rne_f(t));
    Aq[(size_t)row * H_ + c] = bf16_rne_bits(t);
  }
}

// ---------------- m97-structure GEMM (B^T), global_load_lds + XOR swizzle ----
// MODE 0: QKV proj -> per-head LN -> Q dual f16 / K,V single f16
// MODE 2: out proj -> *scale -> f32 out
template <int MODE>
__global__ __launch_bounds__(256) void k_gemm2(
    const uint16_t* __restrict__ A, const uint16_t* __restrict__ Bm,
    int M, int N, int K,
    const float* __restrict__ scales,
    const float* __restrict__ qln_w, const float* __restrict__ qln_b,
    const float* __restrict__ kln_w, const float* __restrict__ kln_b,
    const float* __restrict__ qxln_w, const float* __restrict__ qxln_b,
    uint16_t* __restrict__ Qh, uint16_t* __restrict__ Ql,
    uint16_t* __restrict__ Qxh, uint16_t* __restrict__ Qxl,
    uint16_t* __restrict__ Kf, uint16_t* __restrict__ Vtf,
    float* __restrict__ Cout)
{
  __shared__ __align__(16) uint16_t lA[128 * 32];
  __shared__ __align__(16) uint16_t lB[128 * 32];
  __shared__ float sred[512];

  const int tid = threadIdx.x;
  const int lane = tid & 63;
  const int wv = tid >> 6;
  const int wr = wv >> 1, wc = wv & 1;
  const int l15 = lane & 15, l4 = lane >> 4;
  const int m0 = blockIdx.y * 128, n0 = blockIdx.x * 128;

  int arow[2], acg[2];
#pragma unroll
  for (int c = 0; c < 2; c++) {
    int i = c * 256 + tid;
    arow[c] = i >> 2;
    acg[c] = (i & 3) ^ (arow[c] & 3);
  }
  const int axo = ((l4 ^ (l15 & 3)) * 8);

  f32x4 acc[4][4] = {};

  for (int kt = 0; kt < K; kt += 32) {
    __syncthreads();
#pragma unroll
    for (int c = 0; c < 2; c++) {
      GLOAD_LDS16(&A[(size_t)(m0 + arow[c]) * K + kt + acg[c] * 8],
                  &lA[(c * 256 + wv * 64) * 8]);
      GLOAD_LDS16(&Bm[(size_t)(n0 + arow[c]) * K + kt + acg[c] * 8],
                  &lB[(c * 256 + wv * 64) * 8]);
    }
    __syncthreads();
    bf16x8 af[4];
#pragma unroll
    for (int mt = 0; mt < 4; mt++)
      af[mt] = *(bf16x8*)&lA[(wr * 64 + mt * 16 + l15) * 32 + axo];
#pragma unroll
    for (int nt = 0; nt < 4; nt++) {
      bf16x8 bh = *(bf16x8*)&lB[(wc * 64 + nt * 16 + l15) * 32 + axo];
#pragma unroll
      for (int mt = 0; mt < 4; mt++)
        acc[mt][nt] = __builtin_amdgcn_mfma_f32_16x16x32_bf16(af[mt], bh, acc[mt][nt], 0, 0, 0);
    }
  }

  const int cb = n0 >> 7;
  float sscale;
  const float *lw = nullptr, *lb = nullptr;
  if (MODE == 0) {
    int sect = (cb < 16) ? 0 : (cb < 32) ? 1 : (cb < 40) ? 2 : 3;
    sscale = scales[sect];
    if (sect == 0) { lw = qln_w; lb = qln_b; }
    else if (sect == 1) { lw = qxln_w; lb = qxln_b; }
    else if (sect == 2) { lw = kln_w; lb = kln_b; }
  } else {
    sscale = scales[4];
  }
#pragma unroll
  for (int mt = 0; mt < 4; mt++)
#pragma unroll
    for (int nt = 0; nt < 4; nt++)
#pragma unroll
      for (int j = 0; j < 4; j++) acc[mt][nt][j] *= sscale;

  if (MODE == 2) {
#pragma unroll
    for (int mt = 0; mt < 4; mt++)
#pragma unroll
      for (int j = 0; j < 4; j++) {
        int r = m0 + wr * 64 + mt * 16 + l4 * 4 + j;
#pragma unroll
        for (int nt = 0; nt < 4; nt++) {
          int c = n0 + wc * 64 + nt * 16 + l15;
          Cout[(size_t)r * N + c] = acc[mt][nt][j];
        }
      }
    return;
  }

  float mu_[4][4], rs_[4][4];
#pragma unroll
  for (int mt = 0; mt < 4; mt++)
#pragma unroll
    for (int j = 0; j < 4; j++) { mu_[mt][j] = 0.f; rs_[mt][j] = 1.f; }

  if (lw) {  // per-head LN over the 128-col tile
#pragma unroll
    for (int mt = 0; mt < 4; mt++)
#pragma unroll
      for (int j = 0; j < 4; j++) {
        float s = 0.f, sq = 0.f;
#pragma unroll
        for (int nt = 0; nt < 4; nt++) { float t = acc[mt][nt][j]; s += t; sq += t * t; }
#pragma unroll
        for (int mm = 1; mm < 16; mm <<= 1) { s += __shfl_xor(s, mm); sq += __shfl_xor(sq, mm); }
        if (l15 == 0) {
          int ar = wr * 64 + mt * 16 + l4 * 4 + j;
          sred[wc * 128 + ar] = s;
          sred[256 + wc * 128 + ar] = sq;
        }
      }
    __syncthreads();
#pragma unroll
    for (int mt = 0; mt < 4; mt++)
#pragma unroll
      for (int j = 0; j < 4; j++) {
        int ar = wr * 64 + mt * 16 + l4 * 4 + j;
        float Sm = sred[ar] + sred[128 + ar];
        float Sq = sred[256 + ar] + sred[384 + ar];
        float mu = Sm * (1.f / 128.f);
        float var = Sq * (1.f / 128.f) - mu * mu;
        mu_[mt][j] = mu;
        rs_[mt][j] = 1.f / sqrtf(var + 1e-5f);
      }
  }

#pragma unroll
  for (int mt = 0; mt < 4; mt++)
#pragma unroll
    for (int j = 0; j < 4; j++) {
      int r = m0 + wr * 64 + mt * 16 + l4 * 4 + j;
#pragma unroll
      for (int nt = 0; nt < 4; nt++) {
        int d = wc * 64 + nt * 16 + l15;
        float y = acc[mt][nt][j];
        if (lw) y = (y - mu_[mt][j]) * rs_[mt][j] * lw[d] + lb[d];
        uint16_t hb = f16_bits(y);
        if (cb < 16) {
          size_t o = ((size_t)r * NH_ + cb) * D_ + d;
          Qh[o] = hb; Ql[o] = f16_bits(y - f16_val(hb));
        } else if (cb < 32) {
          size_t o = ((size_t)r * NH_ + (cb - 16)) * D_ + d;
          Qxh[o] = hb; Qxl[o] = f16_bits(y - f16_val(hb));
        } else if (cb < 40) {
          size_t o = ((size_t)r * G_ + (cb - 32)) * D_ + d;
          Kf[o] = hb;
        } else {
          int gg = cb - 40;  // V: single f16, transposed [b][g][d][t]
          size_t o = (((size_t)(r >> 11) * G_ + gg) * D_ + d) * (size_t)S_ + (r & 2047);
          Vtf[o] = hb;
        }
      }
    }
}

// ---------------- kvx GEMM: m97 structure, split A/B 3-MFMA, BM=64 -----------
__global__ __launch_bounds__(256) void k_kvx(
    const uint16_t* __restrict__ Ah, const uint16_t* __restrict__ Al,
    const uint16_t* __restrict__ Bh, const uint16_t* __restrict__ Bl,
    const float* __restrict__ kxln_w, const float* __restrict__ kxln_b,
    uint16_t* __restrict__ Kxf, uint16_t* __restrict__ Vxtf)
{
  const int K = 2048;
  __shared__ __align__(16) uint16_t lA[64 * 32];
  __shared__ __align__(16) uint16_t lA2[64 * 32];
  __shared__ __align__(16) uint16_t lB[128 * 32];
  __shared__ __align__(16) uint16_t lB2[128 * 32];
  __shared__ float sred[512];

  const int tid = threadIdx.x;
  const int lane = tid & 63;
  const int wv = tid >> 6;
  const int wc = wv;                       // wave cols: 4 x 32
  const int l15 = lane & 15, l4 = lane >> 4;
  const int m0 = blockIdx.y * 64, n0 = blockIdx.x * 128;

  const int ar0 = tid >> 2, ag0 = (tid & 3) ^ (ar0 & 3);
  int brow[2], bcg[2];
#pragma unroll
  for (int c = 0; c < 2; c++) {
    int i = c * 256 + tid;
    brow[c] = i >> 2;
    bcg[c] = (i & 3) ^ (brow[c] & 3);
  }
  const int axo = ((l4 ^ (l15 & 3)) * 8);

  f32x4 acc[4][2] = {};

  for (int kt = 0; kt < K; kt += 32) {
    __syncthreads();
    GLOAD_LDS16(&Ah[(size_t)(m0 + ar0) * K + kt + ag0 * 8], &lA[(wv * 64) * 8]);
    GLOAD_LDS16(&Al[(size_t)(m0 + ar0) * K + kt + ag0 * 8], &lA2[(wv * 64) * 8]);
#pragma unroll
    for (int c = 0; c < 2; c++) {
      GLOAD_LDS16(&Bh[(size_t)(n0 + brow[c]) * K + kt + bcg[c] * 8],
                  &lB[(c * 256 + wv * 64) * 8]);
      GLOAD_LDS16(&Bl[(size_t)(n0 + brow[c]) * K + kt + bcg[c] * 8],
                  &lB2[(c * 256 + wv * 64) * 8]);
    }
    __syncthreads();
    bf16x8 af[4], af2[4];
#pragma unroll
    for (int mt = 0; mt < 4; mt++) {
      af[mt]  = *(bf16x8*)&lA[(mt * 16 + l15) * 32 + axo];
      af2[mt] = *(bf16x8*)&lA2[(mt * 16 + l15) * 32 + axo];
    }
#pragma unroll
    for (int nt = 0; nt < 2; nt++) {
      bf16x8 bh = *(bf16x8*)&lB[(wc * 32 + nt * 16 + l15) * 32 + axo];
      bf16x8 bl = *(bf16x8*)&lB2[(wc * 32 + nt * 16 + l15) * 32 + axo];
#pragma unroll
      for (int mt = 0; mt < 4; mt++) {
        acc[mt][nt] = __builtin_amdgcn_mfma_f32_16x16x32_bf16(af[mt], bh, acc[mt][nt], 0, 0, 0);
        acc[mt][nt] = __builtin_amdgcn_mfma_f32_16x16x32_bf16(af[mt], bl, acc[mt][nt], 0, 0, 0);
        acc[mt][nt] = __builtin_amdgcn_mfma_f32_16x16x32_bf16(af2[mt], bh, acc[mt][nt], 0, 0, 0);
      }
    }
  }

  const int cb = n0 >> 7;   // 0..15: <8 -> Kx (LN), else Vxt
  float mu_[4][4], rs_[4][4];
  if (cb < 8) {
#pragma unroll
    for (int mt = 0; mt < 4; mt++)
#pragma unroll
      for (int j = 0; j < 4; j++) {
        float s = 0.f, sq = 0.f;
#pragma unroll
        for (int nt = 0; nt < 2; nt++) { float t = acc[mt][nt][j]; s += t; sq += t * t; }
#pragma unroll
        for (int mm = 1; mm < 16; mm <<= 1) { s += __shfl_xor(s, mm); sq += __shfl_xor(sq, mm); }
        if (l15 == 0) {
          int ar = mt * 16 + l4 * 4 + j;
          sred[wc * 64 + ar] = s;
          sred[256 + wc * 64 + ar] = sq;
        }
      }
    __syncthreads();
#pragma unroll
    for (int mt = 0; mt < 4; mt++)
#pragma unroll
      for (int j = 0; j < 4; j++) {
        int ar = mt * 16 + l4 * 4 + j;
        float Sm = sred[ar] + sred[64 + ar] + sred[128 + ar] + sred[192 + ar];
        float Sq = sred[256 + ar] + sred[320 + ar] + sred[384 + ar] + sred[448 + ar];
        float mu = Sm * (1.f / 128.f);
        float var = Sq * (1.f / 128.f) - mu * mu;
        mu_[mt][j] = mu;
        rs_[mt][j] = 1.f / sqrtf(var + 1e-5f);
      }
  }

#pragma unroll
  for (int mt = 0; mt < 4; mt++)
#pragma unroll
    for (int j = 0; j < 4; j++) {
      int r = m0 + mt * 16 + l4 * 4 + j;
#pragma unroll
      for (int nt = 0; nt < 2; nt++) {
        int d = wc * 32 + nt * 16 + l15;
        float y = acc[mt][nt][j];
        if (cb < 8) {
          y = (y - mu_[mt][j]) * rs_[mt][j] * kxln_w[d] + kxln_b[d];
          size_t o = ((size_t)r * G_ + cb) * D_ + d;
          Kxf[o] = f16_bits(y);
        } else {
          int gg = cb - 8;
          size_t o = (((size_t)(r >> 9) * G_ + gg) * D_ + d) * (size_t)SC_ + (r & 511);
          Vxtf[o] = f16_bits(y);
        }
      }
    }
}

// ---------------- flash GQA attention v3 (f16) -------------------------------
// QK^T: 2 MFMA (Q dual f16 x K single f16). PV: 1 MFMA (P f16 x V f16).
// Ballot-gated defer-max; per-lane partial lsum (reduced once at end).
__global__ __launch_bounds__(256) void k_attn(
    const uint16_t* __restrict__ Qh, const uint16_t* __restrict__ Ql,
    const uint16_t* __restrict__ Kf, const uint16_t* __restrict__ Vtf,
    const float* __restrict__ smooth, uint16_t* __restrict__ catq,
    int T, int colOff)
{
  __shared__ __align__(16) uint16_t lK[32 * 128];
  __shared__ __align__(16) uint16_t lV[128 * 32];
  __shared__ __align__(16) uint16_t lP[64 * 40];

  const int tid = threadIdx.x, lane = tid & 63, wv = tid >> 6;
  const int l15 = lane & 15, l4 = lane >> 4;
  const int q0 = blockIdx.x * 64, h = blockIdx.y, b = blockIdx.z;
  const int g = h >> 1;

  f16x8 qfh[4], qfl[4];
  {
    int srow = q0 + wv * 16 + l15;
    size_t base = (((size_t)b * S_ + srow) * NH_ + h) * (size_t)D_ + l4 * 8;
#pragma unroll
    for (int ks = 0; ks < 4; ks++) {
      qfh[ks] = *(const f16x8*)&Qh[base + ks * 32];
      qfl[ks] = *(const f16x8*)&Ql[base + ks * 32];
    }
  }

  int krow[2], kcg[2], vrow[2], vcg[2];
#pragma unroll
  for (int c = 0; c < 2; c++) {
    int i = c * 256 + tid;
    krow[c] = i >> 4;
    kcg[c] = (i & 15) ^ (krow[c] & 7);
    vrow[c] = i >> 2;
    vcg[c] = (i & 3) ^ (vrow[c] & 3);
  }
  int koff[2][4];
#pragma unroll
  for (int nt = 0; nt < 2; nt++)
#pragma unroll
    for (int ks = 0; ks < 4; ks++)
      koff[nt][ks] = (nt * 16 + l15) * 128 + (((ks * 4 + l4) ^ (l15 & 7)) * 8);
  const int vxo = (l4 ^ (l15 & 3)) * 8;

  float mrun[4] = {-1e30f, -1e30f, -1e30f, -1e30f};
  float lsump[4] = {0.f, 0.f, 0.f, 0.f};   // per-lane partial denominators
  f32x4 oacc[8] = {};

  const int nT = T >> 5;
  for (int tt = 0; tt < nT; tt++) {
    const int t0 = tt << 5;
    __syncthreads();
#pragma unroll
    for (int c = 0; c < 2; c++) {
      size_t ga = (((size_t)b * T + (t0 + krow[c])) * G_ + g) * (size_t)D_ + kcg[c] * 8;
      GLOAD_LDS16(&Kf[ga], &lK[(c * 256 + wv * 64) * 8]);
      size_t gv = (((size_t)b * G_ + g) * (size_t)D_ + vrow[c]) * (size_t)T + t0 + vcg[c] * 8;
      GLOAD_LDS16(&Vtf[gv], &lV[(c * 256 + wv * 64) * 8]);
    }
    __syncthreads();

    f32x4 sf[2];
    __builtin_amdgcn_s_setprio(1);
#pragma unroll
    for (int nt = 0; nt < 2; nt++) {
      f32x4 a = {0.f, 0.f, 0.f, 0.f};
#pragma unroll
      for (int ks = 0; ks < 4; ks++) {
        f16x8 kf = *(f16x8*)&lK[koff[nt][ks]];
        a = __builtin_amdgcn_mfma_f32_16x16x32_f16(qfh[ks], kf, a, 0, 0, 0);
        a = __builtin_amdgcn_mfma_f32_16x16x32_f16(qfl[ks], kf, a, 0, 0, 0);
      }
      sf[nt] = a;
    }
    __builtin_amdgcn_s_setprio(0);

    const float SCL = 0.08838834764831845f;  // 1/sqrt(128)
    float tl[4];
    bool need = false;
#pragma unroll
    for (int j = 0; j < 4; j++) {
      tl[j] = fmaxf(sf[0][j], sf[1][j]) * SCL;
      need = need || (tl[j] > mrun[j] + 8.f);
    }
    if (__any(need ? 1 : 0)) {   // rare: full row-max reduce + rescale
#pragma unroll
      for (int j = 0; j < 4; j++) {
        float tm = tl[j];
#pragma unroll
        for (int mm = 1; mm < 16; mm <<= 1) tm = fmaxf(tm, __shfl_xor(tm, mm));
        float mn = fmaxf(tm, mrun[j]);
        float al = __expf(mrun[j] - mn);
        mrun[j] = mn;
        lsump[j] *= al;
#pragma unroll
        for (int dt = 0; dt < 8; dt++) oacc[dt][j] *= al;
      }
    }
#pragma unroll
    for (int j = 0; j < 4; j++) {
      float p0 = __expf(sf[0][j] * SCL - mrun[j]);
      float p1 = __expf(sf[1][j] * SCL - mrun[j]);
      lsump[j] += p0 + p1;
      int prow = wv * 16 + l4 * 4 + j;
      lP[prow * 40 + l15] = f16_bits(p0);
      lP[prow * 40 + 16 + l15] = f16_bits(p1);
    }

    f16x8 pa = *(f16x8*)&lP[(wv * 16 + l15) * 40 + l4 * 8];
    __builtin_amdgcn_s_setprio(1);
#pragma unroll
    for (int dt = 0; dt < 8; dt++) {
      f16x8 vh = *(f16x8*)&lV[(dt * 16 + l15) * 32 + vxo];
      oacc[dt] = __builtin_amdgcn_mfma_f32_16x16x32_f16(pa, vh, oacc[dt], 0, 0, 0);
    }
    __builtin_amdgcn_s_setprio(0);
  }

#pragma unroll
  for (int j = 0; j < 4; j++) {
    float rsum = lsump[j];
#pragma unroll
    for (int mm = 1; mm < 16; mm <<= 1) rsum += __shfl_xor(rsum, mm);
    float inv = 1.f / rsum;
    int srow = q0 + wv * 16 + l4 * 4 + j;
    size_t rbase = ((size_t)b * S_ + srow) * 4096;
#pragma unroll
    for (int dt = 0; dt < 8; dt++) {
      int c = colOff + h * D_ + dt * 16 + l15;
      float t = (oacc[dt][j] * inv) / smooth[c];
      t = fminf(fmaxf(t, -448.f), 448.f);
      t = fp8_rt(bf16_rne_f(t));
      catq[rbase + c] = bf16_rne_bits(t);
    }
  }
}

// ---------------------------------------------------------------------------
extern "C" void kernel_launch(void* const* d_in, const int* in_sizes, int n_in,
                              void* d_out, int out_size, void* d_ws, size_t ws_size,
                              hipStream_t stream)
{
  (void)in_sizes; (void)n_in; (void)out_size;
  const float* hidden = (const float*)d_in[0];
  const float* cond   = (const float*)d_in[1];
  const float* ln_w   = (const float*)d_in[2];
  const float* ln_b   = (const float*)d_in[3];
  const float* wq     = (const float*)d_in[4];
  const float* wq_s   = (const float*)d_in[5];
  const float* q_is   = (const float*)d_in[6];
  const float* wqx    = (const float*)d_in[7];
  const float* wqx_s  = (const float*)d_in[8];
  const float* qx_is  = (const float*)d_in[9];
  const float* wk     = (const float*)d_in[10];
  const float* wk_s   = (const float*)d_in[11];
  const float* k_is   = (const float*)d_in[12];
  const float* wv     = (const float*)d_in[13];
  const float* wv_s   = (const float*)d_in[14];
  const float* v_is   = (const float*)d_in[15];
  const float* wkvx   = (const float*)d_in[16];
  const float* qln_w  = (const float*)d_in[17];
  const float* qln_b  = (const float*)d_in[18];
  const float* kln_w  = (const float*)d_in[19];
  const float* kln_b  = (const float*)d_in[20];
  const float* qxln_w = (const float*)d_in[21];
  const float* qxln_b = (const float*)d_in[22];
  const float* kxln_w = (const float*)d_in[23];
  const float* kxln_b = (const float*)d_in[24];
  const float* wproj  = (const float*)d_in[25];
  const float* p_ws   = (const float*)d_in[26];
  const float* p_is   = (const float*)d_in[27];
  const float* smooth = (const float*)d_in[28];

  char* ws = (char*)d_ws;
  size_t off = 0;
  auto alloc = [&](size_t bytes) {
    char* p = ws + off;
    off += (bytes + 255) & ~(size_t)255;
    return p;
  };
  uint16_t* Aq    = (uint16_t*)alloc((size_t)4096 * 2048 * 2);
  uint16_t* Wcat  = (uint16_t*)alloc((size_t)6144 * 2048 * 2);
  uint16_t* Wpb   = (uint16_t*)alloc((size_t)2048 * 4096 * 2);
  uint16_t* Wkvxh = (uint16_t*)alloc((size_t)2048 * 2048 * 2);
  uint16_t* Wkvxl = (uint16_t*)alloc((size_t)2048 * 2048 * 2);
  uint16_t* condh = (uint16_t*)alloc((size_t)1024 * 2048 * 2);
  uint16_t* condl = (uint16_t*)alloc((size_t)1024 * 2048 * 2);
  uint16_t* Qh    = (uint16_t*)alloc((size_t)4096 * 16 * 128 * 2);
  uint16_t* Ql    = (uint16_t*)alloc((size_t)4096 * 16 * 128 * 2);
  uint16_t* Qxh   = (uint16_t*)alloc((size_t)4096 * 16 * 128 * 2);
  uint16_t* Qxl   = (uint16_t*)alloc((size_t)4096 * 16 * 128 * 2);
  uint16_t* Kf    = (uint16_t*)alloc((size_t)4096 * 8 * 128 * 2);
  uint16_t* Vtf   = (uint16_t*)alloc((size_t)4096 * 8 * 128 * 2);
  uint16_t* Kxf   = (uint16_t*)alloc((size_t)1024 * 8 * 128 * 2);
  uint16_t* Vxtf  = (uint16_t*)alloc((size_t)1024 * 8 * 128 * 2);
  uint16_t* catq  = (uint16_t*)alloc((size_t)4096 * 4096 * 2);
  float* scales   = (float*)alloc(256);
  if (ws_size < off) return;

  k_prep<<<2048, 256, 0, stream>>>(wq, wqx, wk, wv, wkvx, wproj, cond,
      q_is, wq_s, qx_is, wqx_s, k_is, wk_s, v_is, wv_s, p_is, p_ws,
      Wcat, Wpb, Wkvxh, Wkvxl, condh, condl, scales);

  k_ln_quant<<<4096, 256, 0, stream>>>(hidden, ln_w, ln_b, q_is, Aq);

  k_gemm2<0><<<dim3(48, 32), 256, 0, stream>>>(Aq, Wcat,
      4096, 6144, 2048, scales, qln_w, qln_b, kln_w, kln_b, qxln_w, qxln_b,
      Qh, Ql, Qxh, Qxl, Kf, Vtf, nullptr);

  k_kvx<<<dim3(16, 16), 256, 0, stream>>>(condh, condl, Wkvxh, Wkvxl,
      kxln_w, kxln_b, Kxf, Vxtf);

  k_attn<<<dim3(32, 16, 2), 256, 0, stream>>>(Qh, Ql, Kf, Vtf,
      smooth, catq, 2048, 0);
  k_attn<<<dim3(32, 16, 2), 256, 0, stream>>>(Qxh, Qxl, Kxf, Vxtf,
      smooth, catq, 512, 2048);

  k_gemm2<2><<<dim3(16, 32), 256, 0, stream>>>(catq, Wpb,
      4096, 2048, 4096, scales, nullptr, nullptr, nullptr, nullptr, nullptr, nullptr,
      nullptr, nullptr, nullptr, nullptr, nullptr, nullptr,
      (float*)d_out);
}

// Round 4
// 603.965 us; speedup vs baseline: 1.7886x; 1.1741x over previous
//
#include <hip/hip_runtime.h>
#include <hip/hip_bf16.h>
#include <stdint.h>

#define B_  2
#define S_  2048
#define SC_ 512
#define H_  2048
#define NH_ 16
#define G_  8
#define D_  128

typedef __attribute__((ext_vector_type(8))) short bf16x8;
typedef __attribute__((ext_vector_type(8))) _Float16 f16x8;
typedef __attribute__((ext_vector_type(4))) float f32x4;
typedef __attribute__((ext_vector_type(8))) int i32x8;

#define GLOAD_LDS16(g, l) __builtin_amdgcn_global_load_lds( \
    (const __attribute__((address_space(1))) uint32_t*)(g), \
    (__attribute__((address_space(3))) uint32_t*)(l), 16, 0, 0)

__device__ __forceinline__ uint16_t bf16_rne_bits(float x) {
  uint32_t u = __float_as_uint(x);
  u += 0x7fffu + ((u >> 16) & 1u);
  return (uint16_t)(u >> 16);
}
__device__ __forceinline__ float bf16_rne_f(float x) {
  uint32_t u = __float_as_uint(x);
  u += 0x7fffu + ((u >> 16) & 1u);
  return __uint_as_float(u & 0xffff0000u);
}
__device__ __forceinline__ uint16_t f16_bits(float x) {
  _Float16 h = (_Float16)x;
  return __builtin_bit_cast(uint16_t, h);
}
__device__ __forceinline__ float f16_val(uint16_t b) {
  return (float)__builtin_bit_cast(_Float16, b);
}
// fp8 e4m3fn round-trip (RNE, input already clipped to [-448,448])
__device__ __forceinline__ float fp8_rt(float x) {
  float a = fabsf(x);
  float step;
  if (a >= 0.015625f) {
    uint32_t u = __float_as_uint(a);
    int E = (int)((u >> 23) & 0xffu) - 127;
    step = __uint_as_float((uint32_t)(E - 3 + 127) << 23);
  } else {
    step = 0.001953125f;
  }
  float q = rintf(a / step) * step;
  return x < 0.f ? -q : q;
}
// exact e4m3fn encode of a value that is already an exact fp8 value
__device__ __forceinline__ uint8_t fp8_enc(float v) {
  uint32_t u = __float_as_uint(v);
  uint8_t s = (uint8_t)((u >> 24) & 0x80u);
  float a = fabsf(v);
  if (a == 0.f) return s;
  int E = (int)((u >> 23) & 0xffu) - 127;
  if (E < -6) return s | (uint8_t)(a * 512.f);        // subnormal: k * 2^-9
  uint32_t mant = (u >> 20) & 7u;
  return s | ((uint8_t)(E + 7) << 3) | (uint8_t)mant;
}

// ---------------- prep: weight encodes / splits / scalar scales --------------
__global__ __launch_bounds__(256) void k_prep(
    const float* __restrict__ wq, const float* __restrict__ wqx,
    const float* __restrict__ wk, const float* __restrict__ wv,
    const float* __restrict__ wkvx, const float* __restrict__ wproj,
    const float* __restrict__ cond,
    const float* __restrict__ q_is, const float* __restrict__ wq_s,
    const float* __restrict__ qx_is, const float* __restrict__ wqx_s,
    const float* __restrict__ k_is, const float* __restrict__ wk_s,
    const float* __restrict__ v_is, const float* __restrict__ wv_s,
    const float* __restrict__ p_is, const float* __restrict__ p_ws,
    uint8_t* __restrict__ Wcat, uint8_t* __restrict__ Wpb,
    uint16_t* __restrict__ Wkvxh, uint16_t* __restrict__ Wkvxl,
    uint16_t* __restrict__ condh, uint16_t* __restrict__ condl,
    float* __restrict__ scales)
{
  size_t idx = (size_t)blockIdx.x * 256 + threadIdx.x;
  size_t stride = (size_t)gridDim.x * 256;
  const size_t NC = (size_t)6144 * 2048;
  for (size_t i = idx; i < NC; i += stride) {
    size_t row = i >> 11; int col = (int)(i & 2047);
    float v;
    if (row < 2048)      v = wq[i];
    else if (row < 4096) v = wqx[(row - 2048) * 2048 + col];
    else if (row < 5120) v = wk[(row - 4096) * 2048 + col];
    else                 v = wv[(row - 5120) * 2048 + col];
    Wcat[i] = fp8_enc(v);   // weights are exact fp8 values
  }
  const size_t NP = (size_t)2048 * 4096;
  for (size_t i = idx; i < NP; i += stride)
    Wpb[i] = fp8_enc(wproj[i]);
  const size_t NX = (size_t)2048 * 2048;
  for (size_t i = idx; i < NX; i += stride) {
    float x = wkvx[i];
    uint16_t h = bf16_rne_bits(x);
    Wkvxh[i] = h;
    Wkvxl[i] = bf16_rne_bits(x - __uint_as_float((uint32_t)h << 16));
  }
  const size_t ND = (size_t)1024 * 2048;
  for (size_t i = idx; i < ND; i += stride) {
    float x = cond[i];
    uint16_t h = bf16_rne_bits(x);
    condh[i] = h;
    condl[i] = bf16_rne_bits(x - __uint_as_float((uint32_t)h << 16));
  }
  if (idx == 0) {
    scales[0] = q_is[0] * wq_s[0];
    scales[1] = qx_is[0] * wqx_s[0];
    scales[2] = k_is[0] * wk_s[0];
    scales[3] = v_is[0] * wv_s[0];
    scales[4] = p_is[0] * p_ws[0];
  }
}

// ---------------- hidden LayerNorm + fp8 quantize -> Aq (fp8 bytes) ----------
__global__ __launch_bounds__(256) void k_ln_quant(
    const float* __restrict__ x, const float* __restrict__ w,
    const float* __restrict__ b, const float* __restrict__ qis,
    uint8_t* __restrict__ Aq)
{
  int row = blockIdx.x;
  int tid = threadIdx.x;
  const float* xr = x + (size_t)row * H_;
  float v[8];
  float s = 0.f, sq = 0.f;
#pragma unroll
  for (int i = 0; i < 8; i++) {
    float t = xr[tid + i * 256];
    v[i] = t; s += t; sq += t * t;
  }
#pragma unroll
  for (int m = 1; m < 64; m <<= 1) { s += __shfl_xor(s, m); sq += __shfl_xor(sq, m); }
  __shared__ float red[8];
  int wv = tid >> 6;
  if ((tid & 63) == 0) { red[wv] = s; red[4 + wv] = sq; }
  __syncthreads();
  s = red[0] + red[1] + red[2] + red[3];
  sq = red[4] + red[5] + red[6] + red[7];
  float mu = s * (1.f / H_);
  float var = sq * (1.f / H_) - mu * mu;
  float rs = 1.0f / sqrtf(var + 1e-5f);
#pragma unroll
  for (int i = 0; i < 8; i++) {
    int c = tid + i * 256;
    float y = (v[i] - mu) * rs * w[c] + b[c];
    float t = y / qis[c];
    t = fminf(fmaxf(t, -448.f), 448.f);
    t = fp8_rt(bf16_rne_f(t));
    Aq[(size_t)row * H_ + c] = fp8_enc(t);
  }
}

// ---------------- MX-fp8 GEMM (B^T layout), K-step = 128 fp8 bytes -----------
// MODE 0: QKV proj -> per-head LN -> Q dual f16 / K,V single f16
// MODE 2: out proj -> *scale -> f32 out
// LDS: linear dest for global_load_lds; source pre-swizzled in 32B units
// (chunk32 ^= row&3); frag reads apply the same XOR -> bank-balanced.
template <int MODE>
__global__ __launch_bounds__(256) void k_gemm8(
    const uint8_t* __restrict__ A, const uint8_t* __restrict__ Bm,
    int M, int N, int K,
    const float* __restrict__ scales,
    const float* __restrict__ qln_w, const float* __restrict__ qln_b,
    const float* __restrict__ kln_w, const float* __restrict__ kln_b,
    const float* __restrict__ qxln_w, const float* __restrict__ qxln_b,
    uint16_t* __restrict__ Qh, uint16_t* __restrict__ Ql,
    uint16_t* __restrict__ Qxh, uint16_t* __restrict__ Qxl,
    uint16_t* __restrict__ Kf, uint16_t* __restrict__ Vtf,
    float* __restrict__ Cout)
{
  __shared__ __align__(64) uint8_t lA[128 * 128];
  __shared__ __align__(64) uint8_t lB[128 * 128];
  __shared__ float sred[512];

  const int tid = threadIdx.x;
  const int lane = tid & 63;
  const int wv = tid >> 6;
  const int wr = wv >> 1, wc = wv & 1;
  const int l15 = lane & 15, l4 = lane >> 4;
  const int m0 = blockIdx.y * 128, n0 = blockIdx.x * 128;

  // staging: 1024 16B-chunks per tile, 4 per thread; inverse swizzle on source
  int srow[4]; int soff[4];
#pragma unroll
  for (int c = 0; c < 4; c++) {
    int i = c * 256 + tid;
    int row = i >> 3, s = i & 7;
    srow[c] = row;
    soff[c] = (((s >> 1) ^ (row & 3)) << 5) + ((s & 1) << 4);
  }
  const int axo = ((l4 ^ (l15 & 3)) << 5);   // 32B frag-read XOR

  f32x4 acc[4][4] = {};

  for (int kt = 0; kt < K; kt += 128) {
    __syncthreads();
#pragma unroll
    for (int c = 0; c < 4; c++) {
      GLOAD_LDS16(&A[(size_t)(m0 + srow[c]) * K + kt + soff[c]],
                  &lA[(c * 256 + wv * 64) * 16]);
      GLOAD_LDS16(&Bm[(size_t)(n0 + srow[c]) * K + kt + soff[c]],
                  &lB[(c * 256 + wv * 64) * 16]);
    }
    __syncthreads();
    i32x8 af[4];
#pragma unroll
    for (int mt = 0; mt < 4; mt++)
      af[mt] = *(i32x8*)&lA[(wr * 64 + mt * 16 + l15) * 128 + axo];
#pragma unroll
    for (int nt = 0; nt < 4; nt++) {
      i32x8 bf = *(i32x8*)&lB[(wc * 64 + nt * 16 + l15) * 128 + axo];
#pragma unroll
      for (int mt = 0; mt < 4; mt++)
        acc[mt][nt] = __builtin_amdgcn_mfma_scale_f32_16x16x128_f8f6f4(
            af[mt], bf, acc[mt][nt], 0, 0, 0, 0x7F7F7F7F, 0, 0x7F7F7F7F);
    }
  }

  const int cb = n0 >> 7;
  float sscale;
  const float *lw = nullptr, *lb = nullptr;
  if (MODE == 0) {
    int sect = (cb < 16) ? 0 : (cb < 32) ? 1 : (cb < 40) ? 2 : 3;
    sscale = scales[sect];
    if (sect == 0) { lw = qln_w; lb = qln_b; }
    else if (sect == 1) { lw = qxln_w; lb = qxln_b; }
    else if (sect == 2) { lw = kln_w; lb = kln_b; }
  } else {
    sscale = scales[4];
  }
#pragma unroll
  for (int mt = 0; mt < 4; mt++)
#pragma unroll
    for (int nt = 0; nt < 4; nt++)
#pragma unroll
      for (int j = 0; j < 4; j++) acc[mt][nt][j] *= sscale;

  if (MODE == 2) {
#pragma unroll
    for (int mt = 0; mt < 4; mt++)
#pragma unroll
      for (int j = 0; j < 4; j++) {
        int r = m0 + wr * 64 + mt * 16 + l4 * 4 + j;
#pragma unroll
        for (int nt = 0; nt < 4; nt++) {
          int c = n0 + wc * 64 + nt * 16 + l15;
          Cout[(size_t)r * N + c] = acc[mt][nt][j];
        }
      }
    return;
  }

  float mu_[4][4], rs_[4][4];
#pragma unroll
  for (int mt = 0; mt < 4; mt++)
#pragma unroll
    for (int j = 0; j < 4; j++) { mu_[mt][j] = 0.f; rs_[mt][j] = 1.f; }

  if (lw) {  // per-head LN over the 128-col tile
#pragma unroll
    for (int mt = 0; mt < 4; mt++)
#pragma unroll
      for (int j = 0; j < 4; j++) {
        float s = 0.f, sq = 0.f;
#pragma unroll
        for (int nt = 0; nt < 4; nt++) { float t = acc[mt][nt][j]; s += t; sq += t * t; }
#pragma unroll
        for (int mm = 1; mm < 16; mm <<= 1) { s += __shfl_xor(s, mm); sq += __shfl_xor(sq, mm); }
        if (l15 == 0) {
          int ar = wr * 64 + mt * 16 + l4 * 4 + j;
          sred[wc * 128 + ar] = s;
          sred[256 + wc * 128 + ar] = sq;
        }
      }
    __syncthreads();
#pragma unroll
    for (int mt = 0; mt < 4; mt++)
#pragma unroll
      for (int j = 0; j < 4; j++) {
        int ar = wr * 64 + mt * 16 + l4 * 4 + j;
        float Sm = sred[ar] + sred[128 + ar];
        float Sq = sred[256 + ar] + sred[384 + ar];
        float mu = Sm * (1.f / 128.f);
        float var = Sq * (1.f / 128.f) - mu * mu;
        mu_[mt][j] = mu;
        rs_[mt][j] = 1.f / sqrtf(var + 1e-5f);
      }
  }

#pragma unroll
  for (int mt = 0; mt < 4; mt++)
#pragma unroll
    for (int j = 0; j < 4; j++) {
      int r = m0 + wr * 64 + mt * 16 + l4 * 4 + j;
#pragma unroll
      for (int nt = 0; nt < 4; nt++) {
        int d = wc * 64 + nt * 16 + l15;
        float y = acc[mt][nt][j];
        if (lw) y = (y - mu_[mt][j]) * rs_[mt][j] * lw[d] + lb[d];
        uint16_t hb = f16_bits(y);
        if (cb < 16) {
          size_t o = ((size_t)r * NH_ + cb) * D_ + d;
          Qh[o] = hb; Ql[o] = f16_bits(y - f16_val(hb));
        } else if (cb < 32) {
          size_t o = ((size_t)r * NH_ + (cb - 16)) * D_ + d;
          Qxh[o] = hb; Qxl[o] = f16_bits(y - f16_val(hb));
        } else if (cb < 40) {
          size_t o = ((size_t)r * G_ + (cb - 32)) * D_ + d;
          Kf[o] = hb;
        } else {
          int gg = cb - 40;  // V: single f16, transposed [b][g][d][t]
          size_t o = (((size_t)(r >> 11) * G_ + gg) * D_ + d) * (size_t)S_ + (r & 2047);
          Vtf[o] = hb;
        }
      }
    }
}

// ---------------- kvx GEMM: m97 structure, split A/B 3-MFMA, BM=64 -----------
__global__ __launch_bounds__(256) void k_kvx(
    const uint16_t* __restrict__ Ah, const uint16_t* __restrict__ Al,
    const uint16_t* __restrict__ Bh, const uint16_t* __restrict__ Bl,
    const float* __restrict__ kxln_w, const float* __restrict__ kxln_b,
    uint16_t* __restrict__ Kxf, uint16_t* __restrict__ Vxtf)
{
  const int K = 2048;
  __shared__ __align__(16) uint16_t lA[64 * 32];
  __shared__ __align__(16) uint16_t lA2[64 * 32];
  __shared__ __align__(16) uint16_t lB[128 * 32];
  __shared__ __align__(16) uint16_t lB2[128 * 32];
  __shared__ float sred[512];

  const int tid = threadIdx.x;
  const int lane = tid & 63;
  const int wv = tid >> 6;
  const int wc = wv;
  const int l15 = lane & 15, l4 = lane >> 4;
  const int m0 = blockIdx.y * 64, n0 = blockIdx.x * 128;

  const int ar0 = tid >> 2, ag0 = (tid & 3) ^ (ar0 & 3);
  int brow[2], bcg[2];
#pragma unroll
  for (int c = 0; c < 2; c++) {
    int i = c * 256 + tid;
    brow[c] = i >> 2;
    bcg[c] = (i & 3) ^ (brow[c] & 3);
  }
  const int axo = ((l4 ^ (l15 & 3)) * 8);

  f32x4 acc[4][2] = {};

  for (int kt = 0; kt < K; kt += 32) {
    __syncthreads();
    GLOAD_LDS16(&Ah[(size_t)(m0 + ar0) * K + kt + ag0 * 8], &lA[(wv * 64) * 8]);
    GLOAD_LDS16(&Al[(size_t)(m0 + ar0) * K + kt + ag0 * 8], &lA2[(wv * 64) * 8]);
#pragma unroll
    for (int c = 0; c < 2; c++) {
      GLOAD_LDS16(&Bh[(size_t)(n0 + brow[c]) * K + kt + bcg[c] * 8],
                  &lB[(c * 256 + wv * 64) * 8]);
      GLOAD_LDS16(&Bl[(size_t)(n0 + brow[c]) * K + kt + bcg[c] * 8],
                  &lB2[(c * 256 + wv * 64) * 8]);
    }
    __syncthreads();
    bf16x8 af[4], af2[4];
#pragma unroll
    for (int mt = 0; mt < 4; mt++) {
      af[mt]  = *(bf16x8*)&lA[(mt * 16 + l15) * 32 + axo];
      af2[mt] = *(bf16x8*)&lA2[(mt * 16 + l15) * 32 + axo];
    }
#pragma unroll
    for (int nt = 0; nt < 2; nt++) {
      bf16x8 bh = *(bf16x8*)&lB[(wc * 32 + nt * 16 + l15) * 32 + axo];
      bf16x8 bl = *(bf16x8*)&lB2[(wc * 32 + nt * 16 + l15) * 32 + axo];
#pragma unroll
      for (int mt = 0; mt < 4; mt++) {
        acc[mt][nt] = __builtin_amdgcn_mfma_f32_16x16x32_bf16(af[mt], bh, acc[mt][nt], 0, 0, 0);
        acc[mt][nt] = __builtin_amdgcn_mfma_f32_16x16x32_bf16(af[mt], bl, acc[mt][nt], 0, 0, 0);
        acc[mt][nt] = __builtin_amdgcn_mfma_f32_16x16x32_bf16(af2[mt], bh, acc[mt][nt], 0, 0, 0);
      }
    }
  }

  const int cb = n0 >> 7;
  float mu_[4][4], rs_[4][4];
  if (cb < 8) {
#pragma unroll
    for (int mt = 0; mt < 4; mt++)
#pragma unroll
      for (int j = 0; j < 4; j++) {
        float s = 0.f, sq = 0.f;
#pragma unroll
        for (int nt = 0; nt < 2; nt++) { float t = acc[mt][nt][j]; s += t; sq += t * t; }
#pragma unroll
        for (int mm = 1; mm < 16; mm <<= 1) { s += __shfl_xor(s, mm); sq += __shfl_xor(sq, mm); }
        if (l15 == 0) {
          int ar = mt * 16 + l4 * 4 + j;
          sred[wc * 64 + ar] = s;
          sred[256 + wc * 64 + ar] = sq;
        }
      }
    __syncthreads();
#pragma unroll
    for (int mt = 0; mt < 4; mt++)
#pragma unroll
      for (int j = 0; j < 4; j++) {
        int ar = mt * 16 + l4 * 4 + j;
        float Sm = sred[ar] + sred[64 + ar] + sred[128 + ar] + sred[192 + ar];
        float Sq = sred[256 + ar] + sred[320 + ar] + sred[384 + ar] + sred[448 + ar];
        float mu = Sm * (1.f / 128.f);
        float var = Sq * (1.f / 128.f) - mu * mu;
        mu_[mt][j] = mu;
        rs_[mt][j] = 1.f / sqrtf(var + 1e-5f);
      }
  }

#pragma unroll
  for (int mt = 0; mt < 4; mt++)
#pragma unroll
    for (int j = 0; j < 4; j++) {
      int r = m0 + mt * 16 + l4 * 4 + j;
#pragma unroll
      for (int nt = 0; nt < 2; nt++) {
        int d = wc * 32 + nt * 16 + l15;
        float y = acc[mt][nt][j];
        if (cb < 8) {
          y = (y - mu_[mt][j]) * rs_[mt][j] * kxln_w[d] + kxln_b[d];
          size_t o = ((size_t)r * G_ + cb) * D_ + d;
          Kxf[o] = f16_bits(y);
        } else {
          int gg = cb - 8;
          size_t o = (((size_t)(r >> 9) * G_ + gg) * D_ + d) * (size_t)SC_ + (r & 511);
          Vxtf[o] = f16_bits(y);
        }
      }
    }
}

// ---------------- flash GQA attention (f16) ----------------------------------
__global__ __launch_bounds__(256) void k_attn(
    const uint16_t* __restrict__ Qh, const uint16_t* __restrict__ Ql,
    const uint16_t* __restrict__ Kf, const uint16_t* __restrict__ Vtf,
    const float* __restrict__ smooth, uint8_t* __restrict__ catq,
    int T, int colOff)
{
  __shared__ __align__(16) uint16_t lK[32 * 128];
  __shared__ __align__(16) uint16_t lV[128 * 32];
  __shared__ __align__(16) uint16_t lP[64 * 40];

  const int tid = threadIdx.x, lane = tid & 63, wv = tid >> 6;
  const int l15 = lane & 15, l4 = lane >> 4;
  const int q0 = blockIdx.x * 64, h = blockIdx.y, b = blockIdx.z;
  const int g = h >> 1;

  f16x8 qfh[4], qfl[4];
  {
    int srow = q0 + wv * 16 + l15;
    size_t base = (((size_t)b * S_ + srow) * NH_ + h) * (size_t)D_ + l4 * 8;
#pragma unroll
    for (int ks = 0; ks < 4; ks++) {
      qfh[ks] = *(const f16x8*)&Qh[base + ks * 32];
      qfl[ks] = *(const f16x8*)&Ql[base + ks * 32];
    }
  }

  int krow[2], kcg[2], vrow[2], vcg[2];
#pragma unroll
  for (int c = 0; c < 2; c++) {
    int i = c * 256 + tid;
    krow[c] = i >> 4;
    kcg[c] = (i & 15) ^ (krow[c] & 7);
    vrow[c] = i >> 2;
    vcg[c] = (i & 3) ^ (vrow[c] & 3);
  }
  int koff[2][4];
#pragma unroll
  for (int nt = 0; nt < 2; nt++)
#pragma unroll
    for (int ks = 0; ks < 4; ks++)
      koff[nt][ks] = (nt * 16 + l15) * 128 + (((ks * 4 + l4) ^ (l15 & 7)) * 8);
  const int vxo = (l4 ^ (l15 & 3)) * 8;

  float mrun[4] = {-1e30f, -1e30f, -1e30f, -1e30f};
  float lsump[4] = {0.f, 0.f, 0.f, 0.f};
  f32x4 oacc[8] = {};

  const int nT = T >> 5;
  for (int tt = 0; tt < nT; tt++) {
    const int t0 = tt << 5;
    __syncthreads();
#pragma unroll
    for (int c = 0; c < 2; c++) {
      size_t ga = (((size_t)b * T + (t0 + krow[c])) * G_ + g) * (size_t)D_ + kcg[c] * 8;
      GLOAD_LDS16(&Kf[ga], &lK[(c * 256 + wv * 64) * 8]);
      size_t gv = (((size_t)b * G_ + g) * (size_t)D_ + vrow[c]) * (size_t)T + t0 + vcg[c] * 8;
      GLOAD_LDS16(&Vtf[gv], &lV[(c * 256 + wv * 64) * 8]);
    }
    __syncthreads();

    f32x4 sf[2];
    __builtin_amdgcn_s_setprio(1);
#pragma unroll
    for (int nt = 0; nt < 2; nt++) {
      f32x4 a = {0.f, 0.f, 0.f, 0.f};
#pragma unroll
      for (int ks = 0; ks < 4; ks++) {
        f16x8 kf = *(f16x8*)&lK[koff[nt][ks]];
        a = __builtin_amdgcn_mfma_f32_16x16x32_f16(qfh[ks], kf, a, 0, 0, 0);
        a = __builtin_amdgcn_mfma_f32_16x16x32_f16(qfl[ks], kf, a, 0, 0, 0);
      }
      sf[nt] = a;
    }
    __builtin_amdgcn_s_setprio(0);

    const float SCL = 0.08838834764831845f;  // 1/sqrt(128)
    float tl[4];
    bool need = false;
#pragma unroll
    for (int j = 0; j < 4; j++) {
      tl[j] = fmaxf(sf[0][j], sf[1][j]) * SCL;
      need = need || (tl[j] > mrun[j] + 8.f);
    }
    if (__any(need ? 1 : 0)) {
#pragma unroll
      for (int j = 0; j < 4; j++) {
        float tm = tl[j];
#pragma unroll
        for (int mm = 1; mm < 16; mm <<= 1) tm = fmaxf(tm, __shfl_xor(tm, mm));
        float mn = fmaxf(tm, mrun[j]);
        float al = __expf(mrun[j] - mn);
        mrun[j] = mn;
        lsump[j] *= al;
#pragma unroll
        for (int dt = 0; dt < 8; dt++) oacc[dt][j] *= al;
      }
    }
#pragma unroll
    for (int j = 0; j < 4; j++) {
      float p0 = __expf(sf[0][j] * SCL - mrun[j]);
      float p1 = __expf(sf[1][j] * SCL - mrun[j]);
      lsump[j] += p0 + p1;
      int prow = wv * 16 + l4 * 4 + j;
      lP[prow * 40 + l15] = f16_bits(p0);
      lP[prow * 40 + 16 + l15] = f16_bits(p1);
    }

    f16x8 pa = *(f16x8*)&lP[(wv * 16 + l15) * 40 + l4 * 8];
    __builtin_amdgcn_s_setprio(1);
#pragma unroll
    for (int dt = 0; dt < 8; dt++) {
      f16x8 vh = *(f16x8*)&lV[(dt * 16 + l15) * 32 + vxo];
      oacc[dt] = __builtin_amdgcn_mfma_f32_16x16x32_f16(pa, vh, oacc[dt], 0, 0, 0);
    }
    __builtin_amdgcn_s_setprio(0);
  }

#pragma unroll
  for (int j = 0; j < 4; j++) {
    float rsum = lsump[j];
#pragma unroll
    for (int mm = 1; mm < 16; mm <<= 1) rsum += __shfl_xor(rsum, mm);
    float inv = 1.f / rsum;
    int srow = q0 + wv * 16 + l4 * 4 + j;
    size_t rbase = ((size_t)b * S_ + srow) * 4096;
#pragma unroll
    for (int dt = 0; dt < 8; dt++) {
      int c = colOff + h * D_ + dt * 16 + l15;
      float t = (oacc[dt][j] * inv) / smooth[c];
      t = fminf(fmaxf(t, -448.f), 448.f);
      t = fp8_rt(bf16_rne_f(t));
      catq[rbase + c] = fp8_enc(t);
    }
  }
}

// ---------------------------------------------------------------------------
extern "C" void kernel_launch(void* const* d_in, const int* in_sizes, int n_in,
                              void* d_out, int out_size, void* d_ws, size_t ws_size,
                              hipStream_t stream)
{
  (void)in_sizes; (void)n_in; (void)out_size;
  const float* hidden = (const float*)d_in[0];
  const float* cond   = (const float*)d_in[1];
  const float* ln_w   = (const float*)d_in[2];
  const float* ln_b   = (const float*)d_in[3];
  const float* wq     = (const float*)d_in[4];
  const float* wq_s   = (const float*)d_in[5];
  const float* q_is   = (const float*)d_in[6];
  const float* wqx    = (const float*)d_in[7];
  const float* wqx_s  = (const float*)d_in[8];
  const float* qx_is  = (const float*)d_in[9];
  const float* wk     = (const float*)d_in[10];
  const float* wk_s   = (const float*)d_in[11];
  const float* k_is   = (const float*)d_in[12];
  const float* wv     = (const float*)d_in[13];
  const float* wv_s   = (const float*)d_in[14];
  const float* v_is   = (const float*)d_in[15];
  const float* wkvx   = (const float*)d_in[16];
  const float* qln_w  = (const float*)d_in[17];
  const float* qln_b  = (const float*)d_in[18];
  const float* kln_w  = (const float*)d_in[19];
  const float* kln_b  = (const float*)d_in[20];
  const float* qxln_w = (const float*)d_in[21];
  const float* qxln_b = (const float*)d_in[22];
  const float* kxln_w = (const float*)d_in[23];
  const float* kxln_b = (const float*)d_in[24];
  const float* wproj  = (const float*)d_in[25];
  const float* p_ws   = (const float*)d_in[26];
  const float* p_is   = (const float*)d_in[27];
  const float* smooth = (const float*)d_in[28];

  char* ws = (char*)d_ws;
  size_t off = 0;
  auto alloc = [&](size_t bytes) {
    char* p = ws + off;
    off += (bytes + 255) & ~(size_t)255;
    return p;
  };
  uint8_t*  Aq    = (uint8_t*)alloc((size_t)4096 * 2048);
  uint8_t*  Wcat  = (uint8_t*)alloc((size_t)6144 * 2048);
  uint8_t*  Wpb   = (uint8_t*)alloc((size_t)2048 * 4096);
  uint16_t* Wkvxh = (uint16_t*)alloc((size_t)2048 * 2048 * 2);
  uint16_t* Wkvxl = (uint16_t*)alloc((size_t)2048 * 2048 * 2);
  uint16_t* condh = (uint16_t*)alloc((size_t)1024 * 2048 * 2);
  uint16_t* condl = (uint16_t*)alloc((size_t)1024 * 2048 * 2);
  uint16_t* Qh    = (uint16_t*)alloc((size_t)4096 * 16 * 128 * 2);
  uint16_t* Ql    = (uint16_t*)alloc((size_t)4096 * 16 * 128 * 2);
  uint16_t* Qxh   = (uint16_t*)alloc((size_t)4096 * 16 * 128 * 2);
  uint16_t* Qxl   = (uint16_t*)alloc((size_t)4096 * 16 * 128 * 2);
  uint16_t* Kf    = (uint16_t*)alloc((size_t)4096 * 8 * 128 * 2);
  uint16_t* Vtf   = (uint16_t*)alloc((size_t)4096 * 8 * 128 * 2);
  uint16_t* Kxf   = (uint16_t*)alloc((size_t)1024 * 8 * 128 * 2);
  uint16_t* Vxtf  = (uint16_t*)alloc((size_t)1024 * 8 * 128 * 2);
  uint8_t*  catq  = (uint8_t*)alloc((size_t)4096 * 4096);
  float* scales   = (float*)alloc(256);
  if (ws_size < off) return;

  k_prep<<<2048, 256, 0, stream>>>(wq, wqx, wk, wv, wkvx, wproj, cond,
      q_is, wq_s, qx_is, wqx_s, k_is, wk_s, v_is, wv_s, p_is, p_ws,
      Wcat, Wpb, Wkvxh, Wkvxl, condh, condl, scales);

  k_ln_quant<<<4096, 256, 0, stream>>>(hidden, ln_w, ln_b, q_is, Aq);

  k_gemm8<0><<<dim3(48, 32), 256, 0, stream>>>(Aq, Wcat,
      4096, 6144, 2048, scales, qln_w, qln_b, kln_w, kln_b, qxln_w, qxln_b,
      Qh, Ql, Qxh, Qxl, Kf, Vtf, nullptr);

  k_kvx<<<dim3(16, 16), 256, 0, stream>>>(condh, condl, Wkvxh, Wkvxl,
      kxln_w, kxln_b, Kxf, Vxtf);

  k_attn<<<dim3(32, 16, 2), 256, 0, stream>>>(Qh, Ql, Kf, Vtf,
      smooth, catq, 2048, 0);
  k_attn<<<dim3(32, 16, 2), 256, 0, stream>>>(Qxh, Qxl, Kxf, Vxtf,
      smooth, catq, 512, 2048);

  k_gemm8<2><<<dim3(16, 32), 256, 0, stream>>>(catq, Wpb,
      4096, 2048, 4096, scales, nullptr, nullptr, nullptr, nullptr, nullptr, nullptr,
      nullptr, nullptr, nullptr, nullptr, nullptr, nullptr,
      (float*)d_out);
}

// Round 5
// 502.315 us; speedup vs baseline: 2.1506x; 1.2024x over previous
//
#include <hip/hip_runtime.h>
#include <hip/hip_bf16.h>
#include <stdint.h>

#define B_  2
#define S_  2048
#define SC_ 512
#define H_  2048
#define NH_ 16
#define G_  8
#define D_  128

typedef __attribute__((ext_vector_type(8))) short bf16x8;
typedef __attribute__((ext_vector_type(8))) _Float16 f16x8;
typedef __attribute__((ext_vector_type(4))) float f32x4;
typedef __attribute__((ext_vector_type(8))) int i32x8;

#define GLOAD_LDS16(g, l) __builtin_amdgcn_global_load_lds( \
    (const __attribute__((address_space(1))) uint32_t*)(g), \
    (__attribute__((address_space(3))) uint32_t*)(l), 16, 0, 0)

__device__ __forceinline__ uint16_t bf16_rne_bits(float x) {
  uint32_t u = __float_as_uint(x);
  u += 0x7fffu + ((u >> 16) & 1u);
  return (uint16_t)(u >> 16);
}
__device__ __forceinline__ float bf16_rne_f(float x) {
  uint32_t u = __float_as_uint(x);
  u += 0x7fffu + ((u >> 16) & 1u);
  return __uint_as_float(u & 0xffff0000u);
}
__device__ __forceinline__ uint16_t f16_bits(float x) {
  _Float16 h = (_Float16)x;
  return __builtin_bit_cast(uint16_t, h);
}
__device__ __forceinline__ float f16_val(uint16_t b) {
  return (float)__builtin_bit_cast(_Float16, b);
}
// fp8 e4m3fn round-trip (RNE, input already clipped to [-448,448])
__device__ __forceinline__ float fp8_rt(float x) {
  float a = fabsf(x);
  float step;
  if (a >= 0.015625f) {
    uint32_t u = __float_as_uint(a);
    int E = (int)((u >> 23) & 0xffu) - 127;
    step = __uint_as_float((uint32_t)(E - 3 + 127) << 23);
  } else {
    step = 0.001953125f;
  }
  float q = rintf(a / step) * step;
  return x < 0.f ? -q : q;
}
// exact e4m3fn encode of a value that is already an exact fp8 value
__device__ __forceinline__ uint8_t fp8_enc(float v) {
  uint32_t u = __float_as_uint(v);
  uint8_t s = (uint8_t)((u >> 24) & 0x80u);
  float a = fabsf(v);
  if (a == 0.f) return s;
  int E = (int)((u >> 23) & 0xffu) - 127;
  if (E < -6) return s | (uint8_t)(a * 512.f);        // subnormal: k * 2^-9
  uint32_t mant = (u >> 20) & 7u;
  return s | ((uint8_t)(E + 7) << 3) | (uint8_t)mant;
}

// ---------------- prep: weight encodes / splits / scalar scales --------------
__global__ __launch_bounds__(256) void k_prep(
    const float* __restrict__ wq, const float* __restrict__ wqx,
    const float* __restrict__ wk, const float* __restrict__ wv,
    const float* __restrict__ wkvx, const float* __restrict__ wproj,
    const float* __restrict__ cond,
    const float* __restrict__ q_is, const float* __restrict__ wq_s,
    const float* __restrict__ qx_is, const float* __restrict__ wqx_s,
    const float* __restrict__ k_is, const float* __restrict__ wk_s,
    const float* __restrict__ v_is, const float* __restrict__ wv_s,
    const float* __restrict__ p_is, const float* __restrict__ p_ws,
    uint8_t* __restrict__ Wcat, uint8_t* __restrict__ Wpb,
    uint16_t* __restrict__ Wkvxh, uint16_t* __restrict__ Wkvxl,
    uint16_t* __restrict__ condh, uint16_t* __restrict__ condl,
    float* __restrict__ scales)
{
  size_t idx = (size_t)blockIdx.x * 256 + threadIdx.x;
  size_t stride = (size_t)gridDim.x * 256;
  const size_t NC = (size_t)6144 * 2048;
  for (size_t i = idx; i < NC; i += stride) {
    size_t row = i >> 11; int col = (int)(i & 2047);
    float v;
    if (row < 2048)      v = wq[i];
    else if (row < 4096) v = wqx[(row - 2048) * 2048 + col];
    else if (row < 5120) v = wk[(row - 4096) * 2048 + col];
    else                 v = wv[(row - 5120) * 2048 + col];
    Wcat[i] = fp8_enc(v);
  }
  const size_t NP = (size_t)2048 * 4096;
  for (size_t i = idx; i < NP; i += stride)
    Wpb[i] = fp8_enc(wproj[i]);
  const size_t NX = (size_t)2048 * 2048;
  for (size_t i = idx; i < NX; i += stride) {
    float x = wkvx[i];
    uint16_t h = bf16_rne_bits(x);
    Wkvxh[i] = h;
    Wkvxl[i] = bf16_rne_bits(x - __uint_as_float((uint32_t)h << 16));
  }
  const size_t ND = (size_t)1024 * 2048;
  for (size_t i = idx; i < ND; i += stride) {
    float x = cond[i];
    uint16_t h = bf16_rne_bits(x);
    condh[i] = h;
    condl[i] = bf16_rne_bits(x - __uint_as_float((uint32_t)h << 16));
  }
  if (idx == 0) {
    scales[0] = q_is[0] * wq_s[0];
    scales[1] = qx_is[0] * wqx_s[0];
    scales[2] = k_is[0] * wk_s[0];
    scales[3] = v_is[0] * wv_s[0];
    scales[4] = p_is[0] * p_ws[0];
  }
}

// ---------------- hidden LayerNorm + fp8 quantize -> Aq (fp8 bytes) ----------
__global__ __launch_bounds__(256) void k_ln_quant(
    const float* __restrict__ x, const float* __restrict__ w,
    const float* __restrict__ b, const float* __restrict__ qis,
    uint8_t* __restrict__ Aq)
{
  int row = blockIdx.x;
  int tid = threadIdx.x;
  const float* xr = x + (size_t)row * H_;
  float v[8];
  float s = 0.f, sq = 0.f;
#pragma unroll
  for (int i = 0; i < 8; i++) {
    float t = xr[tid + i * 256];
    v[i] = t; s += t; sq += t * t;
  }
#pragma unroll
  for (int m = 1; m < 64; m <<= 1) { s += __shfl_xor(s, m); sq += __shfl_xor(sq, m); }
  __shared__ float red[8];
  int wv = tid >> 6;
  if ((tid & 63) == 0) { red[wv] = s; red[4 + wv] = sq; }
  __syncthreads();
  s = red[0] + red[1] + red[2] + red[3];
  sq = red[4] + red[5] + red[6] + red[7];
  float mu = s * (1.f / H_);
  float var = sq * (1.f / H_) - mu * mu;
  float rs = 1.0f / sqrtf(var + 1e-5f);
#pragma unroll
  for (int i = 0; i < 8; i++) {
    int c = tid + i * 256;
    float y = (v[i] - mu) * rs * w[c] + b[c];
    float t = y / qis[c];
    t = fminf(fmaxf(t, -448.f), 448.f);
    t = fp8_rt(bf16_rne_f(t));
    Aq[(size_t)row * H_ + c] = fp8_enc(t);
  }
}

// ---------------- MX-fp8 GEMM (B^T layout), K-step = 128 fp8 bytes -----------
// MODE 0: QKV proj -> per-head LN -> Q/K/V single f16 (V transposed)
// MODE 2: out proj -> *scale -> f32 out
template <int MODE>
__global__ __launch_bounds__(256) void k_gemm8(
    const uint8_t* __restrict__ A, const uint8_t* __restrict__ Bm,
    int M, int N, int K,
    const float* __restrict__ scales,
    const float* __restrict__ qln_w, const float* __restrict__ qln_b,
    const float* __restrict__ kln_w, const float* __restrict__ kln_b,
    const float* __restrict__ qxln_w, const float* __restrict__ qxln_b,
    uint16_t* __restrict__ Qh,
    uint16_t* __restrict__ Qxh,
    uint16_t* __restrict__ Kf, uint16_t* __restrict__ Vtf,
    float* __restrict__ Cout)
{
  __shared__ __align__(64) uint8_t lA[128 * 128];
  __shared__ __align__(64) uint8_t lB[128 * 128];
  __shared__ float sred[512];

  const int tid = threadIdx.x;
  const int lane = tid & 63;
  const int wv = tid >> 6;
  const int wr = wv >> 1, wc = wv & 1;
  const int l15 = lane & 15, l4 = lane >> 4;
  const int m0 = blockIdx.y * 128, n0 = blockIdx.x * 128;

  int srow[4]; int soff[4];
#pragma unroll
  for (int c = 0; c < 4; c++) {
    int i = c * 256 + tid;
    int row = i >> 3, s = i & 7;
    srow[c] = row;
    soff[c] = (((s >> 1) ^ (row & 3)) << 5) + ((s & 1) << 4);
  }
  const int axo = ((l4 ^ (l15 & 3)) << 5);

  f32x4 acc[4][4] = {};

  for (int kt = 0; kt < K; kt += 128) {
    __syncthreads();
#pragma unroll
    for (int c = 0; c < 4; c++) {
      GLOAD_LDS16(&A[(size_t)(m0 + srow[c]) * K + kt + soff[c]],
                  &lA[(c * 256 + wv * 64) * 16]);
      GLOAD_LDS16(&Bm[(size_t)(n0 + srow[c]) * K + kt + soff[c]],
                  &lB[(c * 256 + wv * 64) * 16]);
    }
    __syncthreads();
    i32x8 af[4];
#pragma unroll
    for (int mt = 0; mt < 4; mt++)
      af[mt] = *(i32x8*)&lA[(wr * 64 + mt * 16 + l15) * 128 + axo];
#pragma unroll
    for (int nt = 0; nt < 4; nt++) {
      i32x8 bf = *(i32x8*)&lB[(wc * 64 + nt * 16 + l15) * 128 + axo];
#pragma unroll
      for (int mt = 0; mt < 4; mt++)
        acc[mt][nt] = __builtin_amdgcn_mfma_scale_f32_16x16x128_f8f6f4(
            af[mt], bf, acc[mt][nt], 0, 0, 0, 0x7F7F7F7F, 0, 0x7F7F7F7F);
    }
  }

  const int cb = n0 >> 7;
  float sscale;
  const float *lw = nullptr, *lb = nullptr;
  if (MODE == 0) {
    int sect = (cb < 16) ? 0 : (cb < 32) ? 1 : (cb < 40) ? 2 : 3;
    sscale = scales[sect];
    if (sect == 0) { lw = qln_w; lb = qln_b; }
    else if (sect == 1) { lw = qxln_w; lb = qxln_b; }
    else if (sect == 2) { lw = kln_w; lb = kln_b; }
  } else {
    sscale = scales[4];
  }
#pragma unroll
  for (int mt = 0; mt < 4; mt++)
#pragma unroll
    for (int nt = 0; nt < 4; nt++)
#pragma unroll
      for (int j = 0; j < 4; j++) acc[mt][nt][j] *= sscale;

  if (MODE == 2) {
#pragma unroll
    for (int mt = 0; mt < 4; mt++)
#pragma unroll
      for (int j = 0; j < 4; j++) {
        int r = m0 + wr * 64 + mt * 16 + l4 * 4 + j;
#pragma unroll
        for (int nt = 0; nt < 4; nt++) {
          int c = n0 + wc * 64 + nt * 16 + l15;
          Cout[(size_t)r * N + c] = acc[mt][nt][j];
        }
      }
    return;
  }

  float mu_[4][4], rs_[4][4];
#pragma unroll
  for (int mt = 0; mt < 4; mt++)
#pragma unroll
    for (int j = 0; j < 4; j++) { mu_[mt][j] = 0.f; rs_[mt][j] = 1.f; }

  if (lw) {  // per-head LN over the 128-col tile
#pragma unroll
    for (int mt = 0; mt < 4; mt++)
#pragma unroll
      for (int j = 0; j < 4; j++) {
        float s = 0.f, sq = 0.f;
#pragma unroll
        for (int nt = 0; nt < 4; nt++) { float t = acc[mt][nt][j]; s += t; sq += t * t; }
#pragma unroll
        for (int mm = 1; mm < 16; mm <<= 1) { s += __shfl_xor(s, mm); sq += __shfl_xor(sq, mm); }
        if (l15 == 0) {
          int ar = wr * 64 + mt * 16 + l4 * 4 + j;
          sred[wc * 128 + ar] = s;
          sred[256 + wc * 128 + ar] = sq;
        }
      }
    __syncthreads();
#pragma unroll
    for (int mt = 0; mt < 4; mt++)
#pragma unroll
      for (int j = 0; j < 4; j++) {
        int ar = wr * 64 + mt * 16 + l4 * 4 + j;
        float Sm = sred[ar] + sred[128 + ar];
        float Sq = sred[256 + ar] + sred[384 + ar];
        float mu = Sm * (1.f / 128.f);
        float var = Sq * (1.f / 128.f) - mu * mu;
        mu_[mt][j] = mu;
        rs_[mt][j] = 1.f / sqrtf(var + 1e-5f);
      }
  }

#pragma unroll
  for (int mt = 0; mt < 4; mt++)
#pragma unroll
    for (int j = 0; j < 4; j++) {
      int r = m0 + wr * 64 + mt * 16 + l4 * 4 + j;
#pragma unroll
      for (int nt = 0; nt < 4; nt++) {
        int d = wc * 64 + nt * 16 + l15;
        float y = acc[mt][nt][j];
        if (lw) y = (y - mu_[mt][j]) * rs_[mt][j] * lw[d] + lb[d];
        uint16_t hb = f16_bits(y);
        if (cb < 16) {
          Qh[((size_t)r * NH_ + cb) * D_ + d] = hb;
        } else if (cb < 32) {
          Qxh[((size_t)r * NH_ + (cb - 16)) * D_ + d] = hb;
        } else if (cb < 40) {
          Kf[((size_t)r * G_ + (cb - 32)) * D_ + d] = hb;
        } else {
          int gg = cb - 40;  // V: single f16, transposed [b][g][d][t]
          Vtf[(((size_t)(r >> 11) * G_ + gg) * D_ + d) * (size_t)S_ + (r & 2047)] = hb;
        }
      }
    }
}

// ---------------- kvx GEMM: m97 structure, split A/B 3-MFMA, BM=64 -----------
__global__ __launch_bounds__(256) void k_kvx(
    const uint16_t* __restrict__ Ah, const uint16_t* __restrict__ Al,
    const uint16_t* __restrict__ Bh, const uint16_t* __restrict__ Bl,
    const float* __restrict__ kxln_w, const float* __restrict__ kxln_b,
    uint16_t* __restrict__ Kxf, uint16_t* __restrict__ Vxtf)
{
  const int K = 2048;
  __shared__ __align__(16) uint16_t lA[64 * 32];
  __shared__ __align__(16) uint16_t lA2[64 * 32];
  __shared__ __align__(16) uint16_t lB[128 * 32];
  __shared__ __align__(16) uint16_t lB2[128 * 32];
  __shared__ float sred[512];

  const int tid = threadIdx.x;
  const int lane = tid & 63;
  const int wv = tid >> 6;
  const int wc = wv;
  const int l15 = lane & 15, l4 = lane >> 4;
  const int m0 = blockIdx.y * 64, n0 = blockIdx.x * 128;

  const int ar0 = tid >> 2, ag0 = (tid & 3) ^ (ar0 & 3);
  int brow[2], bcg[2];
#pragma unroll
  for (int c = 0; c < 2; c++) {
    int i = c * 256 + tid;
    brow[c] = i >> 2;
    bcg[c] = (i & 3) ^ (brow[c] & 3);
  }
  const int axo = ((l4 ^ (l15 & 3)) * 8);

  f32x4 acc[4][2] = {};

  for (int kt = 0; kt < K; kt += 32) {
    __syncthreads();
    GLOAD_LDS16(&Ah[(size_t)(m0 + ar0) * K + kt + ag0 * 8], &lA[(wv * 64) * 8]);
    GLOAD_LDS16(&Al[(size_t)(m0 + ar0) * K + kt + ag0 * 8], &lA2[(wv * 64) * 8]);
#pragma unroll
    for (int c = 0; c < 2; c++) {
      GLOAD_LDS16(&Bh[(size_t)(n0 + brow[c]) * K + kt + bcg[c] * 8],
                  &lB[(c * 256 + wv * 64) * 8]);
      GLOAD_LDS16(&Bl[(size_t)(n0 + brow[c]) * K + kt + bcg[c] * 8],
                  &lB2[(c * 256 + wv * 64) * 8]);
    }
    __syncthreads();
    bf16x8 af[4], af2[4];
#pragma unroll
    for (int mt = 0; mt < 4; mt++) {
      af[mt]  = *(bf16x8*)&lA[(mt * 16 + l15) * 32 + axo];
      af2[mt] = *(bf16x8*)&lA2[(mt * 16 + l15) * 32 + axo];
    }
#pragma unroll
    for (int nt = 0; nt < 2; nt++) {
      bf16x8 bh = *(bf16x8*)&lB[(wc * 32 + nt * 16 + l15) * 32 + axo];
      bf16x8 bl = *(bf16x8*)&lB2[(wc * 32 + nt * 16 + l15) * 32 + axo];
#pragma unroll
      for (int mt = 0; mt < 4; mt++) {
        acc[mt][nt] = __builtin_amdgcn_mfma_f32_16x16x32_bf16(af[mt], bh, acc[mt][nt], 0, 0, 0);
        acc[mt][nt] = __builtin_amdgcn_mfma_f32_16x16x32_bf16(af[mt], bl, acc[mt][nt], 0, 0, 0);
        acc[mt][nt] = __builtin_amdgcn_mfma_f32_16x16x32_bf16(af2[mt], bh, acc[mt][nt], 0, 0, 0);
      }
    }
  }

  const int cb = n0 >> 7;
  float mu_[4][4], rs_[4][4];
  if (cb < 8) {
#pragma unroll
    for (int mt = 0; mt < 4; mt++)
#pragma unroll
      for (int j = 0; j < 4; j++) {
        float s = 0.f, sq = 0.f;
#pragma unroll
        for (int nt = 0; nt < 2; nt++) { float t = acc[mt][nt][j]; s += t; sq += t * t; }
#pragma unroll
        for (int mm = 1; mm < 16; mm <<= 1) { s += __shfl_xor(s, mm); sq += __shfl_xor(sq, mm); }
        if (l15 == 0) {
          int ar = mt * 16 + l4 * 4 + j;
          sred[wc * 64 + ar] = s;
          sred[256 + wc * 64 + ar] = sq;
        }
      }
    __syncthreads();
#pragma unroll
    for (int mt = 0; mt < 4; mt++)
#pragma unroll
      for (int j = 0; j < 4; j++) {
        int ar = mt * 16 + l4 * 4 + j;
        float Sm = sred[ar] + sred[64 + ar] + sred[128 + ar] + sred[192 + ar];
        float Sq = sred[256 + ar] + sred[320 + ar] + sred[384 + ar] + sred[448 + ar];
        float mu = Sm * (1.f / 128.f);
        float var = Sq * (1.f / 128.f) - mu * mu;
        mu_[mt][j] = mu;
        rs_[mt][j] = 1.f / sqrtf(var + 1e-5f);
      }
  }

#pragma unroll
  for (int mt = 0; mt < 4; mt++)
#pragma unroll
    for (int j = 0; j < 4; j++) {
      int r = m0 + mt * 16 + l4 * 4 + j;
#pragma unroll
      for (int nt = 0; nt < 2; nt++) {
        int d = wc * 32 + nt * 16 + l15;
        float y = acc[mt][nt][j];
        if (cb < 8) {
          y = (y - mu_[mt][j]) * rs_[mt][j] * kxln_w[d] + kxln_b[d];
          Kxf[((size_t)r * G_ + cb) * D_ + d] = f16_bits(y);
        } else {
          int gg = cb - 8;
          Vxtf[(((size_t)(r >> 9) * G_ + gg) * D_ + d) * (size_t)SC_ + (r & 511)] = f16_bits(y);
        }
      }
    }
}

// ---------------- merged flash GQA attention (f16, dbuf prefetch) ------------
// z: 0,1 = self batches; 2,3 = cross batches. QK: 1 MFMA/ks (single f16 Q).
__global__ __launch_bounds__(256) void k_attn(
    const uint16_t* __restrict__ Qs, const uint16_t* __restrict__ Qx,
    const uint16_t* __restrict__ Ks, const uint16_t* __restrict__ Vs,
    const uint16_t* __restrict__ Kx, const uint16_t* __restrict__ Vx,
    const float* __restrict__ smooth, uint8_t* __restrict__ catq)
{
  __shared__ __align__(16) uint16_t lK[2][32 * 128];
  __shared__ __align__(16) uint16_t lV[2][128 * 32];
  __shared__ __align__(16) uint16_t lP[64 * 40];

  const int tid = threadIdx.x, lane = tid & 63, wv = tid >> 6;
  const int l15 = lane & 15, l4 = lane >> 4;
  const int q0 = blockIdx.x * 64, h = blockIdx.y;
  const int zb = blockIdx.z;
  const int b = zb & 1;
  const bool xr = zb >= 2;
  const uint16_t* __restrict__ Q = xr ? Qx : Qs;
  const uint16_t* __restrict__ Kp = xr ? Kx : Ks;
  const uint16_t* __restrict__ Vp = xr ? Vx : Vs;
  const int T = xr ? SC_ : S_;
  const int colOff = xr ? 2048 : 0;
  const int g = h >> 1;

  f16x8 qf[4];
  {
    int srow = q0 + wv * 16 + l15;
    size_t base = (((size_t)b * S_ + srow) * NH_ + h) * (size_t)D_ + l4 * 8;
#pragma unroll
    for (int ks = 0; ks < 4; ks++)
      qf[ks] = *(const f16x8*)&Q[base + ks * 32];
  }

  int krow[2], kcg[2], vrow[2], vcg[2];
#pragma unroll
  for (int c = 0; c < 2; c++) {
    int i = c * 256 + tid;
    krow[c] = i >> 4;
    kcg[c] = (i & 15) ^ (krow[c] & 7);
    vrow[c] = i >> 2;
    vcg[c] = (i & 3) ^ (vrow[c] & 3);
  }
  int koff[2][4];
#pragma unroll
  for (int nt = 0; nt < 2; nt++)
#pragma unroll
    for (int ks = 0; ks < 4; ks++)
      koff[nt][ks] = (nt * 16 + l15) * 128 + (((ks * 4 + l4) ^ (l15 & 7)) * 8);
  const int vxo = (l4 ^ (l15 & 3)) * 8;

  float mrun[4] = {-1e30f, -1e30f, -1e30f, -1e30f};
  float lsump[4] = {0.f, 0.f, 0.f, 0.f};
  f32x4 oacc[8] = {};

  const size_t kbase = ((size_t)b * T) * G_ * D_ + (size_t)g * D_;
  const size_t vbase = (((size_t)b * G_ + g) * (size_t)D_) * (size_t)T;

  // prologue: stage tile 0 into buf 0
#pragma unroll
  for (int c = 0; c < 2; c++) {
    GLOAD_LDS16(&Kp[kbase + (size_t)krow[c] * (G_ * D_) + kcg[c] * 8],
                &lK[0][(c * 256 + wv * 64) * 8]);
    GLOAD_LDS16(&Vp[vbase + (size_t)vrow[c] * T + vcg[c] * 8],
                &lV[0][(c * 256 + wv * 64) * 8]);
  }

  const int nT = T >> 5;
  for (int tt = 0; tt < nT; tt++) {
    const int cur = tt & 1;
    __syncthreads();   // drains vmcnt: buf[cur] staged; all reads of buf[cur^1] done
    if (tt + 1 < nT) { // prefetch next tile into the other buffer
      const int t1 = (tt + 1) << 5;
#pragma unroll
      for (int c = 0; c < 2; c++) {
        GLOAD_LDS16(&Kp[kbase + (size_t)(t1 + krow[c]) * (G_ * D_) + kcg[c] * 8],
                    &lK[cur ^ 1][(c * 256 + wv * 64) * 8]);
        GLOAD_LDS16(&Vp[vbase + (size_t)vrow[c] * T + t1 + vcg[c] * 8],
                    &lV[cur ^ 1][(c * 256 + wv * 64) * 8]);
      }
    }

    f32x4 sf[2];
    __builtin_amdgcn_s_setprio(1);
#pragma unroll
    for (int nt = 0; nt < 2; nt++) {
      f32x4 a = {0.f, 0.f, 0.f, 0.f};
#pragma unroll
      for (int ks = 0; ks < 4; ks++) {
        f16x8 kf = *(f16x8*)&lK[cur][koff[nt][ks]];
        a = __builtin_amdgcn_mfma_f32_16x16x32_f16(qf[ks], kf, a, 0, 0, 0);
      }
      sf[nt] = a;
    }
    __builtin_amdgcn_s_setprio(0);

    const float SCL = 0.08838834764831845f;  // 1/sqrt(128)
    float tl[4];
    bool need = false;
#pragma unroll
    for (int j = 0; j < 4; j++) {
      tl[j] = fmaxf(sf[0][j], sf[1][j]) * SCL;
      need = need || (tl[j] > mrun[j] + 8.f);
    }
    if (__any(need ? 1 : 0)) {
#pragma unroll
      for (int j = 0; j < 4; j++) {
        float tm = tl[j];
#pragma unroll
        for (int mm = 1; mm < 16; mm <<= 1) tm = fmaxf(tm, __shfl_xor(tm, mm));
        float mn = fmaxf(tm, mrun[j]);
        float al = __expf(mrun[j] - mn);
        mrun[j] = mn;
        lsump[j] *= al;
#pragma unroll
        for (int dt = 0; dt < 8; dt++) oacc[dt][j] *= al;
      }
    }
#pragma unroll
    for (int j = 0; j < 4; j++) {
      float p0 = __expf(sf[0][j] * SCL - mrun[j]);
      float p1 = __expf(sf[1][j] * SCL - mrun[j]);
      lsump[j] += p0 + p1;
      int prow = wv * 16 + l4 * 4 + j;
      lP[prow * 40 + l15] = f16_bits(p0);
      lP[prow * 40 + 16 + l15] = f16_bits(p1);
    }

    f16x8 pa = *(f16x8*)&lP[(wv * 16 + l15) * 40 + l4 * 8];
    __builtin_amdgcn_s_setprio(1);
#pragma unroll
    for (int dt = 0; dt < 8; dt++) {
      f16x8 vh = *(f16x8*)&lV[cur][(dt * 16 + l15) * 32 + vxo];
      oacc[dt] = __builtin_amdgcn_mfma_f32_16x16x32_f16(pa, vh, oacc[dt], 0, 0, 0);
    }
    __builtin_amdgcn_s_setprio(0);
  }

#pragma unroll
  for (int j = 0; j < 4; j++) {
    float rsum = lsump[j];
#pragma unroll
    for (int mm = 1; mm < 16; mm <<= 1) rsum += __shfl_xor(rsum, mm);
    float inv = 1.f / rsum;
    int srow = q0 + wv * 16 + l4 * 4 + j;
    size_t rbase = ((size_t)b * S_ + srow) * 4096;
#pragma unroll
    for (int dt = 0; dt < 8; dt++) {
      int c = colOff + h * D_ + dt * 16 + l15;
      float t = (oacc[dt][j] * inv) / smooth[c];
      t = fminf(fmaxf(t, -448.f), 448.f);
      t = fp8_rt(bf16_rne_f(t));
      catq[rbase + c] = fp8_enc(t);
    }
  }
}

// ---------------------------------------------------------------------------
extern "C" void kernel_launch(void* const* d_in, const int* in_sizes, int n_in,
                              void* d_out, int out_size, void* d_ws, size_t ws_size,
                              hipStream_t stream)
{
  (void)in_sizes; (void)n_in; (void)out_size;
  const float* hidden = (const float*)d_in[0];
  const float* cond   = (const float*)d_in[1];
  const float* ln_w   = (const float*)d_in[2];
  const float* ln_b   = (const float*)d_in[3];
  const float* wq     = (const float*)d_in[4];
  const float* wq_s   = (const float*)d_in[5];
  const float* q_is   = (const float*)d_in[6];
  const float* wqx    = (const float*)d_in[7];
  const float* wqx_s  = (const float*)d_in[8];
  const float* qx_is  = (const float*)d_in[9];
  const float* wk     = (const float*)d_in[10];
  const float* wk_s   = (const float*)d_in[11];
  const float* k_is   = (const float*)d_in[12];
  const float* wv     = (const float*)d_in[13];
  const float* wv_s   = (const float*)d_in[14];
  const float* v_is   = (const float*)d_in[15];
  const float* wkvx   = (const float*)d_in[16];
  const float* qln_w  = (const float*)d_in[17];
  const float* qln_b  = (const float*)d_in[18];
  const float* kln_w  = (const float*)d_in[19];
  const float* kln_b  = (const float*)d_in[20];
  const float* qxln_w = (const float*)d_in[21];
  const float* qxln_b = (const float*)d_in[22];
  const float* kxln_w = (const float*)d_in[23];
  const float* kxln_b = (const float*)d_in[24];
  const float* wproj  = (const float*)d_in[25];
  const float* p_ws   = (const float*)d_in[26];
  const float* p_is   = (const float*)d_in[27];
  const float* smooth = (const float*)d_in[28];

  char* ws = (char*)d_ws;
  size_t off = 0;
  auto alloc = [&](size_t bytes) {
    char* p = ws + off;
    off += (bytes + 255) & ~(size_t)255;
    return p;
  };
  uint8_t*  Aq    = (uint8_t*)alloc((size_t)4096 * 2048);
  uint8_t*  Wcat  = (uint8_t*)alloc((size_t)6144 * 2048);
  uint8_t*  Wpb   = (uint8_t*)alloc((size_t)2048 * 4096);
  uint16_t* Wkvxh = (uint16_t*)alloc((size_t)2048 * 2048 * 2);
  uint16_t* Wkvxl = (uint16_t*)alloc((size_t)2048 * 2048 * 2);
  uint16_t* condh = (uint16_t*)alloc((size_t)1024 * 2048 * 2);
  uint16_t* condl = (uint16_t*)alloc((size_t)1024 * 2048 * 2);
  uint16_t* Qh    = (uint16_t*)alloc((size_t)4096 * 16 * 128 * 2);
  uint16_t* Qxh   = (uint16_t*)alloc((size_t)4096 * 16 * 128 * 2);
  uint16_t* Kf    = (uint16_t*)alloc((size_t)4096 * 8 * 128 * 2);
  uint16_t* Vtf   = (uint16_t*)alloc((size_t)4096 * 8 * 128 * 2);
  uint16_t* Kxf   = (uint16_t*)alloc((size_t)1024 * 8 * 128 * 2);
  uint16_t* Vxtf  = (uint16_t*)alloc((size_t)1024 * 8 * 128 * 2);
  uint8_t*  catq  = (uint8_t*)alloc((size_t)4096 * 4096);
  float* scales   = (float*)alloc(256);
  if (ws_size < off) return;

  k_prep<<<2048, 256, 0, stream>>>(wq, wqx, wk, wv, wkvx, wproj, cond,
      q_is, wq_s, qx_is, wqx_s, k_is, wk_s, v_is, wv_s, p_is, p_ws,
      Wcat, Wpb, Wkvxh, Wkvxl, condh, condl, scales);

  k_ln_quant<<<4096, 256, 0, stream>>>(hidden, ln_w, ln_b, q_is, Aq);

  k_gemm8<0><<<dim3(48, 32), 256, 0, stream>>>(Aq, Wcat,
      4096, 6144, 2048, scales, qln_w, qln_b, kln_w, kln_b, qxln_w, qxln_b,
      Qh, Qxh, Kf, Vtf, nullptr);

  k_kvx<<<dim3(16, 16), 256, 0, stream>>>(condh, condl, Wkvxh, Wkvxl,
      kxln_w, kxln_b, Kxf, Vxtf);

  k_attn<<<dim3(32, 16, 4), 256, 0, stream>>>(Qh, Qxh, Kf, Vtf, Kxf, Vxtf,
      smooth, catq);

  k_gemm8<2><<<dim3(16, 32), 256, 0, stream>>>(catq, Wpb,
      4096, 2048, 4096, scales, nullptr, nullptr, nullptr, nullptr, nullptr, nullptr,
      nullptr, nullptr, nullptr, nullptr,
      (float*)d_out);
}

// Round 7
// 421.428 us; speedup vs baseline: 2.5634x; 1.1919x over previous
//
#include <hip/hip_runtime.h>
#include <hip/hip_bf16.h>
#include <stdint.h>

#define B_  2
#define S_  2048
#define SC_ 512
#define H_  2048
#define NH_ 16
#define G_  8
#define D_  128

typedef __attribute__((ext_vector_type(8))) short bf16x8;
typedef __attribute__((ext_vector_type(8))) _Float16 f16x8;
typedef __attribute__((ext_vector_type(4))) float f32x4;
typedef __attribute__((ext_vector_type(8))) int i32x8;

// SCL * log2(e) = (1/sqrt(128)) * 1.4426950408889634
#define SCLLOG2E 0.12751741f
#define THR_LOG2 11.5415603f   // 8 * log2(e)

#define GLOAD_LDS16(g, l) __builtin_amdgcn_global_load_lds( \
    (const __attribute__((address_space(1))) uint32_t*)(g), \
    (__attribute__((address_space(3))) uint32_t*)(l), 16, 0, 0)

__device__ __forceinline__ uint16_t bf16_rne_bits(float x) {
  uint32_t u = __float_as_uint(x);
  u += 0x7fffu + ((u >> 16) & 1u);
  return (uint16_t)(u >> 16);
}
__device__ __forceinline__ float bf16_rne_f(float x) {
  uint32_t u = __float_as_uint(x);
  u += 0x7fffu + ((u >> 16) & 1u);
  return __uint_as_float(u & 0xffff0000u);
}
__device__ __forceinline__ uint16_t f16_bits(float x) {
  _Float16 h = (_Float16)x;
  return __builtin_bit_cast(uint16_t, h);
}
// fp8 e4m3fn round-trip (RNE, input already clipped to [-448,448])
__device__ __forceinline__ float fp8_rt(float x) {
  float a = fabsf(x);
  float step;
  if (a >= 0.015625f) {
    uint32_t u = __float_as_uint(a);
    int E = (int)((u >> 23) & 0xffu) - 127;
    step = __uint_as_float((uint32_t)(E - 3 + 127) << 23);
  } else {
    step = 0.001953125f;
  }
  float q = rintf(a / step) * step;
  return x < 0.f ? -q : q;
}
// exact e4m3fn encode of a value that is already an exact fp8 value
__device__ __forceinline__ uint8_t fp8_enc(float v) {
  uint32_t u = __float_as_uint(v);
  uint8_t s = (uint8_t)((u >> 24) & 0x80u);
  float a = fabsf(v);
  if (a == 0.f) return s;
  int E = (int)((u >> 23) & 0xffu) - 127;
  if (E < -6) return s | (uint8_t)(a * 512.f);        // subnormal: k * 2^-9
  uint32_t mant = (u >> 20) & 7u;
  return s | ((uint8_t)(E + 7) << 3) | (uint8_t)mant;
}

// ---------------- prep: weight encodes / splits / scalar scales --------------
__global__ __launch_bounds__(256) void k_prep(
    const float* __restrict__ wq, const float* __restrict__ wqx,
    const float* __restrict__ wk, const float* __restrict__ wv,
    const float* __restrict__ wkvx, const float* __restrict__ wproj,
    const float* __restrict__ cond,
    const float* __restrict__ q_is, const float* __restrict__ wq_s,
    const float* __restrict__ qx_is, const float* __restrict__ wqx_s,
    const float* __restrict__ k_is, const float* __restrict__ wk_s,
    const float* __restrict__ v_is, const float* __restrict__ wv_s,
    const float* __restrict__ p_is, const float* __restrict__ p_ws,
    uint8_t* __restrict__ Wcat, uint8_t* __restrict__ Wpb,
    uint16_t* __restrict__ Wkvxh, uint16_t* __restrict__ Wkvxl,
    uint16_t* __restrict__ condh, uint16_t* __restrict__ condl,
    float* __restrict__ scales)
{
  size_t idx = (size_t)blockIdx.x * 256 + threadIdx.x;
  size_t stride = (size_t)gridDim.x * 256;
  const size_t NC = (size_t)6144 * 2048;
  for (size_t i = idx; i < NC; i += stride) {
    size_t row = i >> 11; int col = (int)(i & 2047);
    float v;
    if (row < 2048)      v = wq[i];
    else if (row < 4096) v = wqx[(row - 2048) * 2048 + col];
    else if (row < 5120) v = wk[(row - 4096) * 2048 + col];
    else                 v = wv[(row - 5120) * 2048 + col];
    Wcat[i] = fp8_enc(v);
  }
  const size_t NP = (size_t)2048 * 4096;
  for (size_t i = idx; i < NP; i += stride)
    Wpb[i] = fp8_enc(wproj[i]);
  const size_t NX = (size_t)2048 * 2048;
  for (size_t i = idx; i < NX; i += stride) {
    float x = wkvx[i];
    uint16_t h = bf16_rne_bits(x);
    Wkvxh[i] = h;
    Wkvxl[i] = bf16_rne_bits(x - __uint_as_float((uint32_t)h << 16));
  }
  const size_t ND = (size_t)1024 * 2048;
  for (size_t i = idx; i < ND; i += stride) {
    float x = cond[i];
    uint16_t h = bf16_rne_bits(x);
    condh[i] = h;
    condl[i] = bf16_rne_bits(x - __uint_as_float((uint32_t)h << 16));
  }
  if (idx == 0) {
    scales[0] = q_is[0] * wq_s[0];
    scales[1] = qx_is[0] * wqx_s[0];
    scales[2] = k_is[0] * wk_s[0];
    scales[3] = v_is[0] * wv_s[0];
    scales[4] = p_is[0] * p_ws[0];
  }
}

// ---------------- hidden LayerNorm + fp8 quantize -> Aq (fp8 bytes) ----------
__global__ __launch_bounds__(256) void k_ln_quant(
    const float* __restrict__ x, const float* __restrict__ w,
    const float* __restrict__ b, const float* __restrict__ qis,
    uint8_t* __restrict__ Aq)
{
  int row = blockIdx.x;
  int tid = threadIdx.x;
  const float* xr = x + (size_t)row * H_;
  float v[8];
  float s = 0.f, sq = 0.f;
#pragma unroll
  for (int i = 0; i < 8; i++) {
    float t = xr[tid + i * 256];
    v[i] = t; s += t; sq += t * t;
  }
#pragma unroll
  for (int m = 1; m < 64; m <<= 1) { s += __shfl_xor(s, m); sq += __shfl_xor(sq, m); }
  __shared__ float red[8];
  int wv = tid >> 6;
  if ((tid & 63) == 0) { red[wv] = s; red[4 + wv] = sq; }
  __syncthreads();
  s = red[0] + red[1] + red[2] + red[3];
  sq = red[4] + red[5] + red[6] + red[7];
  float mu = s * (1.f / H_);
  float var = sq * (1.f / H_) - mu * mu;
  float rs = 1.0f / sqrtf(var + 1e-5f);
#pragma unroll
  for (int i = 0; i < 8; i++) {
    int c = tid + i * 256;
    float y = (v[i] - mu) * rs * w[c] + b[c];
    float t = y / qis[c];
    t = fminf(fmaxf(t, -448.f), 448.f);
    t = fp8_rt(bf16_rne_f(t));
    Aq[(size_t)row * H_ + c] = fp8_enc(t);
  }
}

// ---------------- MX-fp8 GEMM (B^T layout), K-step = 128 fp8 bytes -----------
// MODE 0: QKV proj -> per-head LN -> Q/Qx pre-scaled f16, K f16, V^T f16
// MODE 2: out proj -> *scale -> f32 out
template <int MODE>
__global__ __launch_bounds__(256) void k_gemm8(
    const uint8_t* __restrict__ A, const uint8_t* __restrict__ Bm,
    int M, int N, int K,
    const float* __restrict__ scales,
    const float* __restrict__ qln_w, const float* __restrict__ qln_b,
    const float* __restrict__ kln_w, const float* __restrict__ kln_b,
    const float* __restrict__ qxln_w, const float* __restrict__ qxln_b,
    uint16_t* __restrict__ Qh,
    uint16_t* __restrict__ Qxh,
    uint16_t* __restrict__ Kf, uint16_t* __restrict__ Vtf,
    float* __restrict__ Cout)
{
  __shared__ __align__(64) uint8_t smem[128 * 136 * 2];  // >= 32768+2048 staging+sred
  uint8_t* lA = smem;
  uint8_t* lB = smem + 128 * 128;
  float* sred = (float*)(smem + 128 * 128 * 2);
  uint16_t* sT = (uint16_t*)smem;          // V-path overlay: 128*136*2 = 34816 B

  const int tid = threadIdx.x;
  const int lane = tid & 63;
  const int wv = tid >> 6;
  const int wr = wv >> 1, wc = wv & 1;
  const int l15 = lane & 15, l4 = lane >> 4;
  const int m0 = blockIdx.y * 128, n0 = blockIdx.x * 128;

  int srow[4]; int soff[4];
#pragma unroll
  for (int c = 0; c < 4; c++) {
    int i = c * 256 + tid;
    int row = i >> 3, s = i & 7;
    srow[c] = row;
    soff[c] = (((s >> 1) ^ (row & 3)) << 5) + ((s & 1) << 4);
  }
  const int axo = ((l4 ^ (l15 & 3)) << 5);

  f32x4 acc[4][4] = {};

  for (int kt = 0; kt < K; kt += 128) {
    __syncthreads();
#pragma unroll
    for (int c = 0; c < 4; c++) {
      GLOAD_LDS16(&A[(size_t)(m0 + srow[c]) * K + kt + soff[c]],
                  &lA[(c * 256 + wv * 64) * 16]);
      GLOAD_LDS16(&Bm[(size_t)(n0 + srow[c]) * K + kt + soff[c]],
                  &lB[(c * 256 + wv * 64) * 16]);
    }
    __syncthreads();
    i32x8 af[4];
#pragma unroll
    for (int mt = 0; mt < 4; mt++)
      af[mt] = *(i32x8*)&lA[(wr * 64 + mt * 16 + l15) * 128 + axo];
#pragma unroll
    for (int nt = 0; nt < 4; nt++) {
      i32x8 bf = *(i32x8*)&lB[(wc * 64 + nt * 16 + l15) * 128 + axo];
#pragma unroll
      for (int mt = 0; mt < 4; mt++)
        acc[mt][nt] = __builtin_amdgcn_mfma_scale_f32_16x16x128_f8f6f4(
            af[mt], bf, acc[mt][nt], 0, 0, 0, 0x7F7F7F7F, 0, 0x7F7F7F7F);
    }
  }

  const int cb = n0 >> 7;
  float sscale;
  const float *lw = nullptr, *lb = nullptr;
  if (MODE == 0) {
    int sect = (cb < 16) ? 0 : (cb < 32) ? 1 : (cb < 40) ? 2 : 3;
    sscale = scales[sect];
    if (sect == 0) { lw = qln_w; lb = qln_b; }
    else if (sect == 1) { lw = qxln_w; lb = qxln_b; }
    else if (sect == 2) { lw = kln_w; lb = kln_b; }
  } else {
    sscale = scales[4];
  }
#pragma unroll
  for (int mt = 0; mt < 4; mt++)
#pragma unroll
    for (int nt = 0; nt < 4; nt++)
#pragma unroll
      for (int j = 0; j < 4; j++) acc[mt][nt][j] *= sscale;

  if (MODE == 2) {
#pragma unroll
    for (int mt = 0; mt < 4; mt++)
#pragma unroll
      for (int j = 0; j < 4; j++) {
        int r = m0 + wr * 64 + mt * 16 + l4 * 4 + j;
#pragma unroll
        for (int nt = 0; nt < 4; nt++) {
          int c = n0 + wc * 64 + nt * 16 + l15;
          Cout[(size_t)r * N + c] = acc[mt][nt][j];
        }
      }
    return;
  }

  if (MODE == 0 && cb >= 40) {
    // V section: transpose through LDS, coalesced f16 stores.
    // Pad 136 (mult of 8 elems) keeps every row 16B-aligned for b128 reads.
    __syncthreads();   // staging LDS no longer needed; safe to overlay
#pragma unroll
    for (int mt = 0; mt < 4; mt++)
#pragma unroll
      for (int j = 0; j < 4; j++) {
        int rl = wr * 64 + mt * 16 + l4 * 4 + j;
#pragma unroll
        for (int nt = 0; nt < 4; nt++) {
          int d = wc * 64 + nt * 16 + l15;
          sT[d * 136 + rl] = f16_bits(acc[mt][nt][j]);
        }
      }
    __syncthreads();
    int gg = cb - 40;
    int d = tid >> 1, rh = (tid & 1) << 6;
    size_t gbase = (((size_t)(m0 >> 11) * G_ + gg) * D_ + d) * (size_t)S_ +
                   (m0 & 2047) + rh;
    const uint16_t* sp = &sT[d * 136 + rh];
#pragma unroll
    for (int k = 0; k < 8; k++)
      *(bf16x8*)&Vtf[gbase + k * 8] = *(const bf16x8*)&sp[k * 8];
    return;
  }

  // Q / Qx / K sections: per-head LN over the 128-col tile
  float mu_[4][4], rs_[4][4];
#pragma unroll
  for (int mt = 0; mt < 4; mt++)
#pragma unroll
    for (int j = 0; j < 4; j++) {
      float s = 0.f, sq = 0.f;
#pragma unroll
      for (int nt = 0; nt < 4; nt++) { float t = acc[mt][nt][j]; s += t; sq += t * t; }
#pragma unroll
      for (int mm = 1; mm < 16; mm <<= 1) { s += __shfl_xor(s, mm); sq += __shfl_xor(sq, mm); }
      if (l15 == 0) {
        int ar = wr * 64 + mt * 16 + l4 * 4 + j;
        sred[wc * 128 + ar] = s;
        sred[256 + wc * 128 + ar] = sq;
      }
    }
  __syncthreads();
#pragma unroll
  for (int mt = 0; mt < 4; mt++)
#pragma unroll
    for (int j = 0; j < 4; j++) {
      int ar = wr * 64 + mt * 16 + l4 * 4 + j;
      float Sm = sred[ar] + sred[128 + ar];
      float Sq = sred[256 + ar] + sred[384 + ar];
      float mu = Sm * (1.f / 128.f);
      float var = Sq * (1.f / 128.f) - mu * mu;
      mu_[mt][j] = mu;
      rs_[mt][j] = 1.f / sqrtf(var + 1e-5f);
    }

#pragma unroll
  for (int mt = 0; mt < 4; mt++)
#pragma unroll
    for (int j = 0; j < 4; j++) {
      int r = m0 + wr * 64 + mt * 16 + l4 * 4 + j;
#pragma unroll
      for (int nt = 0; nt < 4; nt++) {
        int d = wc * 64 + nt * 16 + l15;
        float y = (acc[mt][nt][j] - mu_[mt][j]) * rs_[mt][j] * lw[d] + lb[d];
        if (cb < 32) y *= SCLLOG2E;   // fold softmax scale + log2e into Q/Qx
        uint16_t hb = f16_bits(y);
        if (cb < 16) {
          Qh[((size_t)r * NH_ + cb) * D_ + d] = hb;
        } else if (cb < 32) {
          Qxh[((size_t)r * NH_ + (cb - 16)) * D_ + d] = hb;
        } else {
          Kf[((size_t)r * G_ + (cb - 32)) * D_ + d] = hb;
        }
      }
    }
}

// ---------------- kvx GEMM: m97 structure, split A/B 3-MFMA, BM=64 -----------
__global__ __launch_bounds__(256) void k_kvx(
    const uint16_t* __restrict__ Ah, const uint16_t* __restrict__ Al,
    const uint16_t* __restrict__ Bh, const uint16_t* __restrict__ Bl,
    const float* __restrict__ kxln_w, const float* __restrict__ kxln_b,
    uint16_t* __restrict__ Kxf, uint16_t* __restrict__ Vxtf)
{
  const int K = 2048;
  __shared__ __align__(64) uint8_t smem[26624];
  uint16_t* lA  = (uint16_t*)smem;                 // 64*32*2  = 4096
  uint16_t* lA2 = (uint16_t*)(smem + 4096);        // 4096
  uint16_t* lB  = (uint16_t*)(smem + 8192);        // 128*32*2 = 8192
  uint16_t* lB2 = (uint16_t*)(smem + 16384);       // 8192
  float* sred = (float*)(smem + 24576);
  uint16_t* sT = (uint16_t*)smem;                  // Vx overlay: 128*72*2 = 18432

  const int tid = threadIdx.x;
  const int lane = tid & 63;
  const int wv = tid >> 6;
  const int wc = wv;
  const int l15 = lane & 15, l4 = lane >> 4;
  const int m0 = blockIdx.y * 64, n0 = blockIdx.x * 128;

  const int ar0 = tid >> 2, ag0 = (tid & 3) ^ (ar0 & 3);
  int brow[2], bcg[2];
#pragma unroll
  for (int c = 0; c < 2; c++) {
    int i = c * 256 + tid;
    brow[c] = i >> 2;
    bcg[c] = (i & 3) ^ (brow[c] & 3);
  }
  const int axo = ((l4 ^ (l15 & 3)) * 8);

  f32x4 acc[4][2] = {};

  for (int kt = 0; kt < K; kt += 32) {
    __syncthreads();
    GLOAD_LDS16(&Ah[(size_t)(m0 + ar0) * K + kt + ag0 * 8], &lA[(wv * 64) * 8]);
    GLOAD_LDS16(&Al[(size_t)(m0 + ar0) * K + kt + ag0 * 8], &lA2[(wv * 64) * 8]);
#pragma unroll
    for (int c = 0; c < 2; c++) {
      GLOAD_LDS16(&Bh[(size_t)(n0 + brow[c]) * K + kt + bcg[c] * 8],
                  &lB[(c * 256 + wv * 64) * 8]);
      GLOAD_LDS16(&Bl[(size_t)(n0 + brow[c]) * K + kt + bcg[c] * 8],
                  &lB2[(c * 256 + wv * 64) * 8]);
    }
    __syncthreads();
    bf16x8 af[4], af2[4];
#pragma unroll
    for (int mt = 0; mt < 4; mt++) {
      af[mt]  = *(bf16x8*)&lA[(mt * 16 + l15) * 32 + axo];
      af2[mt] = *(bf16x8*)&lA2[(mt * 16 + l15) * 32 + axo];
    }
#pragma unroll
    for (int nt = 0; nt < 2; nt++) {
      bf16x8 bh = *(bf16x8*)&lB[(wc * 32 + nt * 16 + l15) * 32 + axo];
      bf16x8 bl = *(bf16x8*)&lB2[(wc * 32 + nt * 16 + l15) * 32 + axo];
#pragma unroll
      for (int mt = 0; mt < 4; mt++) {
        acc[mt][nt] = __builtin_amdgcn_mfma_f32_16x16x32_bf16(af[mt], bh, acc[mt][nt], 0, 0, 0);
        acc[mt][nt] = __builtin_amdgcn_mfma_f32_16x16x32_bf16(af[mt], bl, acc[mt][nt], 0, 0, 0);
        acc[mt][nt] = __builtin_amdgcn_mfma_f32_16x16x32_bf16(af2[mt], bh, acc[mt][nt], 0, 0, 0);
      }
    }
  }

  const int cb = n0 >> 7;

  if (cb >= 8) {
    // Vx: transpose through LDS (pad 72 keeps 16B alignment), coalesced stores
    __syncthreads();
#pragma unroll
    for (int mt = 0; mt < 4; mt++)
#pragma unroll
      for (int j = 0; j < 4; j++) {
        int rl = mt * 16 + l4 * 4 + j;
#pragma unroll
        for (int nt = 0; nt < 2; nt++) {
          int d = wc * 32 + nt * 16 + l15;
          sT[d * 72 + rl] = f16_bits(acc[mt][nt][j]);
        }
      }
    __syncthreads();
    int gg = cb - 8;
    int d = tid >> 1, rh = (tid & 1) << 5;
    size_t gbase = (((size_t)(m0 >> 9) * G_ + gg) * D_ + d) * (size_t)SC_ +
                   (m0 & 511) + rh;
    const uint16_t* sp = &sT[d * 72 + rh];
#pragma unroll
    for (int k = 0; k < 4; k++)
      *(bf16x8*)&Vxtf[gbase + k * 8] = *(const bf16x8*)&sp[k * 8];
    return;
  }

  float mu_[4][4], rs_[4][4];
#pragma unroll
  for (int mt = 0; mt < 4; mt++)
#pragma unroll
    for (int j = 0; j < 4; j++) {
      float s = 0.f, sq = 0.f;
#pragma unroll
      for (int nt = 0; nt < 2; nt++) { float t = acc[mt][nt][j]; s += t; sq += t * t; }
#pragma unroll
      for (int mm = 1; mm < 16; mm <<= 1) { s += __shfl_xor(s, mm); sq += __shfl_xor(sq, mm); }
      if (l15 == 0) {
        int ar = mt * 16 + l4 * 4 + j;
        sred[wc * 64 + ar] = s;
        sred[256 + wc * 64 + ar] = sq;
      }
    }
  __syncthreads();
#pragma unroll
  for (int mt = 0; mt < 4; mt++)
#pragma unroll
    for (int j = 0; j < 4; j++) {
      int ar = mt * 16 + l4 * 4 + j;
      float Sm = sred[ar] + sred[64 + ar] + sred[128 + ar] + sred[192 + ar];
      float Sq = sred[256 + ar] + sred[320 + ar] + sred[384 + ar] + sred[448 + ar];
      float mu = Sm * (1.f / 128.f);
      float var = Sq * (1.f / 128.f) - mu * mu;
      mu_[mt][j] = mu;
      rs_[mt][j] = 1.f / sqrtf(var + 1e-5f);
    }

#pragma unroll
  for (int mt = 0; mt < 4; mt++)
#pragma unroll
    for (int j = 0; j < 4; j++) {
      int r = m0 + mt * 16 + l4 * 4 + j;
#pragma unroll
      for (int nt = 0; nt < 2; nt++) {
        int d = wc * 32 + nt * 16 + l15;
        float y = (acc[mt][nt][j] - mu_[mt][j]) * rs_[mt][j] * kxln_w[d] + kxln_b[d];
        Kxf[((size_t)r * G_ + cb) * D_ + d] = f16_bits(y);
      }
    }
}

// ---------------- merged flash GQA attention (f16, exp2-domain) --------------
// z: 0,1 = self batches; 2,3 = cross batches. Q pre-scaled by SCL*log2e.
__global__ __launch_bounds__(256) void k_attn(
    const uint16_t* __restrict__ Qs, const uint16_t* __restrict__ Qx,
    const uint16_t* __restrict__ Ks, const uint16_t* __restrict__ Vs,
    const uint16_t* __restrict__ Kx, const uint16_t* __restrict__ Vx,
    const float* __restrict__ smooth, uint8_t* __restrict__ catq)
{
  __shared__ __align__(16) uint16_t lK[2][32 * 128];
  __shared__ __align__(16) uint16_t lV[2][128 * 32];
  __shared__ __align__(16) uint16_t lP[64 * 40];

  const int tid = threadIdx.x, lane = tid & 63, wv = tid >> 6;
  const int l15 = lane & 15, l4 = lane >> 4;
  const int q0 = blockIdx.x * 64, h = blockIdx.y;
  const int zb = blockIdx.z;
  const int b = zb & 1;
  const bool xr = zb >= 2;
  const uint16_t* __restrict__ Q = xr ? Qx : Qs;
  const uint16_t* __restrict__ Kp = xr ? Kx : Ks;
  const uint16_t* __restrict__ Vp = xr ? Vx : Vs;
  const int T = xr ? SC_ : S_;
  const int colOff = xr ? 2048 : 0;
  const int g = h >> 1;

  f16x8 qf[4];
  {
    int srow = q0 + wv * 16 + l15;
    size_t base = (((size_t)b * S_ + srow) * NH_ + h) * (size_t)D_ + l4 * 8;
#pragma unroll
    for (int ks = 0; ks < 4; ks++)
      qf[ks] = *(const f16x8*)&Q[base + ks * 32];
  }

  int krow[2], kcg[2], vrow[2], vcg[2];
#pragma unroll
  for (int c = 0; c < 2; c++) {
    int i = c * 256 + tid;
    krow[c] = i >> 4;
    kcg[c] = (i & 15) ^ (krow[c] & 7);
    vrow[c] = i >> 2;
    vcg[c] = (i & 3) ^ (vrow[c] & 3);
  }
  // paired-column K mapping: output col l15 of MFMA nt <-> K row t = 2*l15+nt.
  // staging stored global chunk s^(t&7) at slot s, so read slot = chunk^(t&7).
  int koff[2][4];
#pragma unroll
  for (int nt = 0; nt < 2; nt++)
#pragma unroll
    for (int ks = 0; ks < 4; ks++) {
      int t = 2 * l15 + nt;
      koff[nt][ks] = t * 128 + (((ks * 4 + l4) ^ (t & 7)) * 8);
    }
  const int vxo = (l4 ^ (l15 & 3)) * 8;

  float mrun[4] = {-1e30f, -1e30f, -1e30f, -1e30f};
  float lsump[4] = {0.f, 0.f, 0.f, 0.f};
  f32x4 oacc[8] = {};

  const size_t kbase = ((size_t)b * T) * G_ * D_ + (size_t)g * D_;
  const size_t vbase = (((size_t)b * G_ + g) * (size_t)D_) * (size_t)T;

  // prologue: stage tile 0 into buf 0
#pragma unroll
  for (int c = 0; c < 2; c++) {
    GLOAD_LDS16(&Kp[kbase + (size_t)krow[c] * (G_ * D_) + kcg[c] * 8],
                &lK[0][(c * 256 + wv * 64) * 8]);
    GLOAD_LDS16(&Vp[vbase + (size_t)vrow[c] * T + vcg[c] * 8],
                &lV[0][(c * 256 + wv * 64) * 8]);
  }

  const int nT = T >> 5;
  for (int tt = 0; tt < nT; tt++) {
    const int cur = tt & 1;
    __syncthreads();
    if (tt + 1 < nT) {
      const int t1 = (tt + 1) << 5;
#pragma unroll
      for (int c = 0; c < 2; c++) {
        GLOAD_LDS16(&Kp[kbase + (size_t)(t1 + krow[c]) * (G_ * D_) + kcg[c] * 8],
                    &lK[cur ^ 1][(c * 256 + wv * 64) * 8]);
        GLOAD_LDS16(&Vp[vbase + (size_t)vrow[c] * T + t1 + vcg[c] * 8],
                    &lV[cur ^ 1][(c * 256 + wv * 64) * 8]);
      }
    }

    f32x4 sf[2];
    __builtin_amdgcn_s_setprio(1);
#pragma unroll
    for (int nt = 0; nt < 2; nt++) {
      f32x4 a = {0.f, 0.f, 0.f, 0.f};
#pragma unroll
      for (int ks = 0; ks < 4; ks++) {
        f16x8 kf = *(f16x8*)&lK[cur][koff[nt][ks]];
        a = __builtin_amdgcn_mfma_f32_16x16x32_f16(qf[ks], kf, a, 0, 0, 0);
      }
      sf[nt] = a;
    }
    __builtin_amdgcn_s_setprio(0);

    // scores already in log2 domain
    float tl[4];
    bool need = false;
#pragma unroll
    for (int j = 0; j < 4; j++) {
      tl[j] = fmaxf(sf[0][j], sf[1][j]);
      need = need || (tl[j] > mrun[j] + THR_LOG2);
    }
    if (__any(need ? 1 : 0)) {
#pragma unroll
      for (int j = 0; j < 4; j++) {
        float tm = tl[j];
#pragma unroll
        for (int mm = 1; mm < 16; mm <<= 1) tm = fmaxf(tm, __shfl_xor(tm, mm));
        float mn = fmaxf(tm, mrun[j]);
        float al = __builtin_amdgcn_exp2f(mrun[j] - mn);
        mrun[j] = mn;
        lsump[j] *= al;
#pragma unroll
        for (int dt = 0; dt < 8; dt++) oacc[dt][j] *= al;
      }
    }
#pragma unroll
    for (int j = 0; j < 4; j++) {
      float p0 = __builtin_amdgcn_exp2f(sf[0][j] - mrun[j]);
      float p1 = __builtin_amdgcn_exp2f(sf[1][j] - mrun[j]);
      lsump[j] += p0 + p1;
      int prow = wv * 16 + l4 * 4 + j;
      uint32_t pk = (uint32_t)f16_bits(p0) | ((uint32_t)f16_bits(p1) << 16);
      *(uint32_t*)&lP[prow * 40 + l15 * 2] = pk;   // cols 2*l15, 2*l15+1
    }

    f16x8 pa = *(f16x8*)&lP[(wv * 16 + l15) * 40 + l4 * 8];
    __builtin_amdgcn_s_setprio(1);
#pragma unroll
    for (int dt = 0; dt < 8; dt++) {
      f16x8 vh = *(f16x8*)&lV[cur][(dt * 16 + l15) * 32 + vxo];
      oacc[dt] = __builtin_amdgcn_mfma_f32_16x16x32_f16(pa, vh, oacc[dt], 0, 0, 0);
    }
    __builtin_amdgcn_s_setprio(0);
  }

#pragma unroll
  for (int j = 0; j < 4; j++) {
    float rsum = lsump[j];
#pragma unroll
    for (int mm = 1; mm < 16; mm <<= 1) rsum += __shfl_xor(rsum, mm);
    float inv = 1.f / rsum;
    int srow = q0 + wv * 16 + l4 * 4 + j;
    size_t rbase = ((size_t)b * S_ + srow) * 4096;
#pragma unroll
    for (int dt = 0; dt < 8; dt++) {
      int c = colOff + h * D_ + dt * 16 + l15;
      float t = (oacc[dt][j] * inv) / smooth[c];
      t = fminf(fmaxf(t, -448.f), 448.f);
      t = fp8_rt(bf16_rne_f(t));
      catq[rbase + c] = fp8_enc(t);
    }
  }
}

// ---------------------------------------------------------------------------
extern "C" void kernel_launch(void* const* d_in, const int* in_sizes, int n_in,
                              void* d_out, int out_size, void* d_ws, size_t ws_size,
                              hipStream_t stream)
{
  (void)in_sizes; (void)n_in; (void)out_size;
  const float* hidden = (const float*)d_in[0];
  const float* cond   = (const float*)d_in[1];
  const float* ln_w   = (const float*)d_in[2];
  const float* ln_b   = (const float*)d_in[3];
  const float* wq     = (const float*)d_in[4];
  const float* wq_s   = (const float*)d_in[5];
  const float* q_is   = (const float*)d_in[6];
  const float* wqx    = (const float*)d_in[7];
  const float* wqx_s  = (const float*)d_in[8];
  const float* qx_is  = (const float*)d_in[9];
  const float* wk     = (const float*)d_in[10];
  const float* wk_s   = (const float*)d_in[11];
  const float* k_is   = (const float*)d_in[12];
  const float* wv     = (const float*)d_in[13];
  const float* wv_s   = (const float*)d_in[14];
  const float* v_is   = (const float*)d_in[15];
  const float* wkvx   = (const float*)d_in[16];
  const float* qln_w  = (const float*)d_in[17];
  const float* qln_b  = (const float*)d_in[18];
  const float* kln_w  = (const float*)d_in[19];
  const float* kln_b  = (const float*)d_in[20];
  const float* qxln_w = (const float*)d_in[21];
  const float* qxln_b = (const float*)d_in[22];
  const float* kxln_w = (const float*)d_in[23];
  const float* kxln_b = (const float*)d_in[24];
  const float* wproj  = (const float*)d_in[25];
  const float* p_ws   = (const float*)d_in[26];
  const float* p_is   = (const float*)d_in[27];
  const float* smooth = (const float*)d_in[28];

  char* ws = (char*)d_ws;
  size_t off = 0;
  auto alloc = [&](size_t bytes) {
    char* p = ws + off;
    off += (bytes + 255) & ~(size_t)255;
    return p;
  };
  uint8_t*  Aq    = (uint8_t*)alloc((size_t)4096 * 2048);
  uint8_t*  Wcat  = (uint8_t*)alloc((size_t)6144 * 2048);
  uint8_t*  Wpb   = (uint8_t*)alloc((size_t)2048 * 4096);
  uint16_t* Wkvxh = (uint16_t*)alloc((size_t)2048 * 2048 * 2);
  uint16_t* Wkvxl = (uint16_t*)alloc((size_t)2048 * 2048 * 2);
  uint16_t* condh = (uint16_t*)alloc((size_t)1024 * 2048 * 2);
  uint16_t* condl = (uint16_t*)alloc((size_t)1024 * 2048 * 2);
  uint16_t* Qh    = (uint16_t*)alloc((size_t)4096 * 16 * 128 * 2);
  uint16_t* Qxh   = (uint16_t*)alloc((size_t)4096 * 16 * 128 * 2);
  uint16_t* Kf    = (uint16_t*)alloc((size_t)4096 * 8 * 128 * 2);
  uint16_t* Vtf   = (uint16_t*)alloc((size_t)4096 * 8 * 128 * 2);
  uint16_t* Kxf   = (uint16_t*)alloc((size_t)1024 * 8 * 128 * 2);
  uint16_t* Vxtf  = (uint16_t*)alloc((size_t)1024 * 8 * 128 * 2);
  uint8_t*  catq  = (uint8_t*)alloc((size_t)4096 * 4096);
  float* scales   = (float*)alloc(256);
  if (ws_size < off) return;

  k_prep<<<2048, 256, 0, stream>>>(wq, wqx, wk, wv, wkvx, wproj, cond,
      q_is, wq_s, qx_is, wqx_s, k_is, wk_s, v_is, wv_s, p_is, p_ws,
      Wcat, Wpb, Wkvxh, Wkvxl, condh, condl, scales);

  k_ln_quant<<<4096, 256, 0, stream>>>(hidden, ln_w, ln_b, q_is, Aq);

  k_gemm8<0><<<dim3(48, 32), 256, 0, stream>>>(Aq, Wcat,
      4096, 6144, 2048, scales, qln_w, qln_b, kln_w, kln_b, qxln_w, qxln_b,
      Qh, Qxh, Kf, Vtf, nullptr);

  k_kvx<<<dim3(16, 16), 256, 0, stream>>>(condh, condl, Wkvxh, Wkvxl,
      kxln_w, kxln_b, Kxf, Vxtf);

  k_attn<<<dim3(32, 16, 4), 256, 0, stream>>>(Qh, Qxh, Kf, Vtf, Kxf, Vxtf,
      smooth, catq);

  k_gemm8<2><<<dim3(16, 32), 256, 0, stream>>>(catq, Wpb,
      4096, 2048, 4096, scales, nullptr, nullptr, nullptr, nullptr, nullptr, nullptr,
      nullptr, nullptr, nullptr, nullptr,
      (float*)d_out);
}

// Round 8
// 390.768 us; speedup vs baseline: 2.7645x; 1.0785x over previous
//
#include <hip/hip_runtime.h>
#include <hip/hip_bf16.h>
#include <stdint.h>

#define B_  2
#define S_  2048
#define SC_ 512
#define H_  2048
#define NH_ 16
#define G_  8
#define D_  128

typedef __attribute__((ext_vector_type(8))) short bf16x8;
typedef __attribute__((ext_vector_type(8))) _Float16 f16x8;
typedef __attribute__((ext_vector_type(4))) float f32x4;
typedef __attribute__((ext_vector_type(8))) int i32x8;

// SCL * log2(e) = (1/sqrt(128)) * 1.4426950408889634
#define SCLLOG2E 0.12751741f
// |score_log2| <= SCLLOG2E * ||q|| * ||k|| = SCLLOG2E*128 = 16.3222 (LN => unit rows)
#define FIXED_M  16.34f

#define GLOAD_LDS16(g, l) __builtin_amdgcn_global_load_lds( \
    (const __attribute__((address_space(1))) uint32_t*)(g), \
    (__attribute__((address_space(3))) uint32_t*)(l), 16, 0, 0)

__device__ __forceinline__ uint16_t bf16_rne_bits(float x) {
  uint32_t u = __float_as_uint(x);
  u += 0x7fffu + ((u >> 16) & 1u);
  return (uint16_t)(u >> 16);
}
__device__ __forceinline__ float bf16_rne_f(float x) {
  uint32_t u = __float_as_uint(x);
  u += 0x7fffu + ((u >> 16) & 1u);
  return __uint_as_float(u & 0xffff0000u);
}
__device__ __forceinline__ uint16_t f16_bits(float x) {
  _Float16 h = (_Float16)x;
  return __builtin_bit_cast(uint16_t, h);
}
// fp8 e4m3fn round-trip (RNE, input already clipped to [-448,448])
__device__ __forceinline__ float fp8_rt(float x) {
  float a = fabsf(x);
  float step;
  if (a >= 0.015625f) {
    uint32_t u = __float_as_uint(a);
    int E = (int)((u >> 23) & 0xffu) - 127;
    step = __uint_as_float((uint32_t)(E - 3 + 127) << 23);
  } else {
    step = 0.001953125f;
  }
  float q = rintf(a / step) * step;
  return x < 0.f ? -q : q;
}
// exact e4m3fn encode of a value that is already an exact fp8 value
__device__ __forceinline__ uint8_t fp8_enc(float v) {
  uint32_t u = __float_as_uint(v);
  uint8_t s = (uint8_t)((u >> 24) & 0x80u);
  float a = fabsf(v);
  if (a == 0.f) return s;
  int E = (int)((u >> 23) & 0xffu) - 127;
  if (E < -6) return s | (uint8_t)(a * 512.f);        // subnormal: k * 2^-9
  uint32_t mant = (u >> 20) & 7u;
  return s | ((uint8_t)(E + 7) << 3) | (uint8_t)mant;
}

// ---------------- prep: weight encodes / splits / scalar scales --------------
__global__ __launch_bounds__(256) void k_prep(
    const float* __restrict__ wq, const float* __restrict__ wqx,
    const float* __restrict__ wk, const float* __restrict__ wv,
    const float* __restrict__ wkvx, const float* __restrict__ wproj,
    const float* __restrict__ cond,
    const float* __restrict__ q_is, const float* __restrict__ wq_s,
    const float* __restrict__ qx_is, const float* __restrict__ wqx_s,
    const float* __restrict__ k_is, const float* __restrict__ wk_s,
    const float* __restrict__ v_is, const float* __restrict__ wv_s,
    const float* __restrict__ p_is, const float* __restrict__ p_ws,
    uint8_t* __restrict__ Wcat, uint8_t* __restrict__ Wpb,
    uint16_t* __restrict__ Wkvxh, uint16_t* __restrict__ Wkvxl,
    uint16_t* __restrict__ condh, uint16_t* __restrict__ condl,
    float* __restrict__ scales)
{
  size_t idx = (size_t)blockIdx.x * 256 + threadIdx.x;
  size_t stride = (size_t)gridDim.x * 256;
  const size_t NC = (size_t)6144 * 2048;
  for (size_t i = idx; i < NC; i += stride) {
    size_t row = i >> 11; int col = (int)(i & 2047);
    float v;
    if (row < 2048)      v = wq[i];
    else if (row < 4096) v = wqx[(row - 2048) * 2048 + col];
    else if (row < 5120) v = wk[(row - 4096) * 2048 + col];
    else                 v = wv[(row - 5120) * 2048 + col];
    Wcat[i] = fp8_enc(v);
  }
  const size_t NP = (size_t)2048 * 4096;
  for (size_t i = idx; i < NP; i += stride)
    Wpb[i] = fp8_enc(wproj[i]);
  const size_t NX = (size_t)2048 * 2048;
  for (size_t i = idx; i < NX; i += stride) {
    float x = wkvx[i];
    uint16_t h = bf16_rne_bits(x);
    Wkvxh[i] = h;
    Wkvxl[i] = bf16_rne_bits(x - __uint_as_float((uint32_t)h << 16));
  }
  const size_t ND = (size_t)1024 * 2048;
  for (size_t i = idx; i < ND; i += stride) {
    float x = cond[i];
    uint16_t h = bf16_rne_bits(x);
    condh[i] = h;
    condl[i] = bf16_rne_bits(x - __uint_as_float((uint32_t)h << 16));
  }
  if (idx == 0) {
    scales[0] = q_is[0] * wq_s[0];
    scales[1] = qx_is[0] * wqx_s[0];
    scales[2] = k_is[0] * wk_s[0];
    scales[3] = v_is[0] * wv_s[0];
    scales[4] = p_is[0] * p_ws[0];
  }
}

// ---------------- hidden LayerNorm + fp8 quantize -> Aq (fp8 bytes) ----------
__global__ __launch_bounds__(256) void k_ln_quant(
    const float* __restrict__ x, const float* __restrict__ w,
    const float* __restrict__ b, const float* __restrict__ qis,
    uint8_t* __restrict__ Aq)
{
  int row = blockIdx.x;
  int tid = threadIdx.x;
  const float* xr = x + (size_t)row * H_;
  float v[8];
  float s = 0.f, sq = 0.f;
#pragma unroll
  for (int i = 0; i < 8; i++) {
    float t = xr[tid + i * 256];
    v[i] = t; s += t; sq += t * t;
  }
#pragma unroll
  for (int m = 1; m < 64; m <<= 1) { s += __shfl_xor(s, m); sq += __shfl_xor(sq, m); }
  __shared__ float red[8];
  int wv = tid >> 6;
  if ((tid & 63) == 0) { red[wv] = s; red[4 + wv] = sq; }
  __syncthreads();
  s = red[0] + red[1] + red[2] + red[3];
  sq = red[4] + red[5] + red[6] + red[7];
  float mu = s * (1.f / H_);
  float var = sq * (1.f / H_) - mu * mu;
  float rs = 1.0f / sqrtf(var + 1e-5f);
#pragma unroll
  for (int i = 0; i < 8; i++) {
    int c = tid + i * 256;
    float y = (v[i] - mu) * rs * w[c] + b[c];
    float t = y / qis[c];
    t = fminf(fmaxf(t, -448.f), 448.f);
    t = fp8_rt(bf16_rne_f(t));
    Aq[(size_t)row * H_ + c] = fp8_enc(t);
  }
}

// ---------------- MX-fp8 GEMM (B^T layout), K-step = 128 fp8 bytes -----------
// MODE 0: QKV proj -> per-head LN -> Q/Qx pre-scaled f16, K f16, V^T bf16
// MODE 2: out proj -> *scale -> f32 out
template <int MODE>
__global__ __launch_bounds__(256) void k_gemm8(
    const uint8_t* __restrict__ A, const uint8_t* __restrict__ Bm,
    int M, int N, int K,
    const float* __restrict__ scales,
    const float* __restrict__ qln_w, const float* __restrict__ qln_b,
    const float* __restrict__ kln_w, const float* __restrict__ kln_b,
    const float* __restrict__ qxln_w, const float* __restrict__ qxln_b,
    uint16_t* __restrict__ Qh,
    uint16_t* __restrict__ Qxh,
    uint16_t* __restrict__ Kf, uint16_t* __restrict__ Vtf,
    float* __restrict__ Cout)
{
  __shared__ __align__(64) uint8_t smem[128 * 136 * 2];  // >= 32768+2048 staging+sred
  uint8_t* lA = smem;
  uint8_t* lB = smem + 128 * 128;
  float* sred = (float*)(smem + 128 * 128 * 2);
  uint16_t* sT = (uint16_t*)smem;          // V-path overlay: 128*136*2 = 34816 B

  const int tid = threadIdx.x;
  const int lane = tid & 63;
  const int wv = tid >> 6;
  const int wr = wv >> 1, wc = wv & 1;
  const int l15 = lane & 15, l4 = lane >> 4;
  const int m0 = blockIdx.y * 128, n0 = blockIdx.x * 128;

  int srow[4]; int soff[4];
#pragma unroll
  for (int c = 0; c < 4; c++) {
    int i = c * 256 + tid;
    int row = i >> 3, s = i & 7;
    srow[c] = row;
    soff[c] = (((s >> 1) ^ (row & 3)) << 5) + ((s & 1) << 4);
  }
  const int axo = ((l4 ^ (l15 & 3)) << 5);

  f32x4 acc[4][4] = {};

  for (int kt = 0; kt < K; kt += 128) {
    __syncthreads();
#pragma unroll
    for (int c = 0; c < 4; c++) {
      GLOAD_LDS16(&A[(size_t)(m0 + srow[c]) * K + kt + soff[c]],
                  &lA[(c * 256 + wv * 64) * 16]);
      GLOAD_LDS16(&Bm[(size_t)(n0 + srow[c]) * K + kt + soff[c]],
                  &lB[(c * 256 + wv * 64) * 16]);
    }
    __syncthreads();
    i32x8 af[4];
#pragma unroll
    for (int mt = 0; mt < 4; mt++)
      af[mt] = *(i32x8*)&lA[(wr * 64 + mt * 16 + l15) * 128 + axo];
#pragma unroll
    for (int nt = 0; nt < 4; nt++) {
      i32x8 bf = *(i32x8*)&lB[(wc * 64 + nt * 16 + l15) * 128 + axo];
#pragma unroll
      for (int mt = 0; mt < 4; mt++)
        acc[mt][nt] = __builtin_amdgcn_mfma_scale_f32_16x16x128_f8f6f4(
            af[mt], bf, acc[mt][nt], 0, 0, 0, 0x7F7F7F7F, 0, 0x7F7F7F7F);
    }
  }

  const int cb = n0 >> 7;
  float sscale;
  const float *lw = nullptr, *lb = nullptr;
  if (MODE == 0) {
    int sect = (cb < 16) ? 0 : (cb < 32) ? 1 : (cb < 40) ? 2 : 3;
    sscale = scales[sect];
    if (sect == 0) { lw = qln_w; lb = qln_b; }
    else if (sect == 1) { lw = qxln_w; lb = qxln_b; }
    else if (sect == 2) { lw = kln_w; lb = kln_b; }
  } else {
    sscale = scales[4];
  }
#pragma unroll
  for (int mt = 0; mt < 4; mt++)
#pragma unroll
    for (int nt = 0; nt < 4; nt++)
#pragma unroll
      for (int j = 0; j < 4; j++) acc[mt][nt][j] *= sscale;

  if (MODE == 2) {
#pragma unroll
    for (int mt = 0; mt < 4; mt++)
#pragma unroll
      for (int j = 0; j < 4; j++) {
        int r = m0 + wr * 64 + mt * 16 + l4 * 4 + j;
#pragma unroll
        for (int nt = 0; nt < 4; nt++) {
          int c = n0 + wc * 64 + nt * 16 + l15;
          Cout[(size_t)r * N + c] = acc[mt][nt][j];
        }
      }
    return;
  }

  if (MODE == 0 && cb >= 40) {
    // V section: transpose through LDS, coalesced bf16 stores.
    __syncthreads();   // staging LDS no longer needed; safe to overlay
#pragma unroll
    for (int mt = 0; mt < 4; mt++)
#pragma unroll
      for (int j = 0; j < 4; j++) {
        int rl = wr * 64 + mt * 16 + l4 * 4 + j;
#pragma unroll
        for (int nt = 0; nt < 4; nt++) {
          int d = wc * 64 + nt * 16 + l15;
          sT[d * 136 + rl] = bf16_rne_bits(acc[mt][nt][j]);
        }
      }
    __syncthreads();
    int gg = cb - 40;
    int d = tid >> 1, rh = (tid & 1) << 6;
    size_t gbase = (((size_t)(m0 >> 11) * G_ + gg) * D_ + d) * (size_t)S_ +
                   (m0 & 2047) + rh;
    const uint16_t* sp = &sT[d * 136 + rh];
#pragma unroll
    for (int k = 0; k < 8; k++)
      *(bf16x8*)&Vtf[gbase + k * 8] = *(const bf16x8*)&sp[k * 8];
    return;
  }

  // Q / Qx / K sections: per-head LN over the 128-col tile
  float mu_[4][4], rs_[4][4];
#pragma unroll
  for (int mt = 0; mt < 4; mt++)
#pragma unroll
    for (int j = 0; j < 4; j++) {
      float s = 0.f, sq = 0.f;
#pragma unroll
      for (int nt = 0; nt < 4; nt++) { float t = acc[mt][nt][j]; s += t; sq += t * t; }
#pragma unroll
      for (int mm = 1; mm < 16; mm <<= 1) { s += __shfl_xor(s, mm); sq += __shfl_xor(sq, mm); }
      if (l15 == 0) {
        int ar = wr * 64 + mt * 16 + l4 * 4 + j;
        sred[wc * 128 + ar] = s;
        sred[256 + wc * 128 + ar] = sq;
      }
    }
  __syncthreads();
#pragma unroll
  for (int mt = 0; mt < 4; mt++)
#pragma unroll
    for (int j = 0; j < 4; j++) {
      int ar = wr * 64 + mt * 16 + l4 * 4 + j;
      float Sm = sred[ar] + sred[128 + ar];
      float Sq = sred[256 + ar] + sred[384 + ar];
      float mu = Sm * (1.f / 128.f);
      float var = Sq * (1.f / 128.f) - mu * mu;
      mu_[mt][j] = mu;
      rs_[mt][j] = 1.f / sqrtf(var + 1e-5f);
    }

#pragma unroll
  for (int mt = 0; mt < 4; mt++)
#pragma unroll
    for (int j = 0; j < 4; j++) {
      int r = m0 + wr * 64 + mt * 16 + l4 * 4 + j;
#pragma unroll
      for (int nt = 0; nt < 4; nt++) {
        int d = wc * 64 + nt * 16 + l15;
        float y = (acc[mt][nt][j] - mu_[mt][j]) * rs_[mt][j] * lw[d] + lb[d];
        if (cb < 32) y *= SCLLOG2E;   // fold softmax scale + log2e into Q/Qx
        uint16_t hb = f16_bits(y);
        if (cb < 16) {
          Qh[((size_t)r * NH_ + cb) * D_ + d] = hb;
        } else if (cb < 32) {
          Qxh[((size_t)r * NH_ + (cb - 16)) * D_ + d] = hb;
        } else {
          Kf[((size_t)r * G_ + (cb - 32)) * D_ + d] = hb;
        }
      }
    }
}

// ---------------- kvx GEMM: m97 structure, split A/B 3-MFMA, BM=64 -----------
__global__ __launch_bounds__(256) void k_kvx(
    const uint16_t* __restrict__ Ah, const uint16_t* __restrict__ Al,
    const uint16_t* __restrict__ Bh, const uint16_t* __restrict__ Bl,
    const float* __restrict__ kxln_w, const float* __restrict__ kxln_b,
    uint16_t* __restrict__ Kxf, uint16_t* __restrict__ Vxtf)
{
  const int K = 2048;
  __shared__ __align__(64) uint8_t smem[26624];
  uint16_t* lA  = (uint16_t*)smem;                 // 64*32*2  = 4096
  uint16_t* lA2 = (uint16_t*)(smem + 4096);        // 4096
  uint16_t* lB  = (uint16_t*)(smem + 8192);        // 128*32*2 = 8192
  uint16_t* lB2 = (uint16_t*)(smem + 16384);       // 8192
  float* sred = (float*)(smem + 24576);
  uint16_t* sT = (uint16_t*)smem;                  // Vx overlay: 128*72*2 = 18432

  const int tid = threadIdx.x;
  const int lane = tid & 63;
  const int wv = tid >> 6;
  const int wc = wv;
  const int l15 = lane & 15, l4 = lane >> 4;
  const int m0 = blockIdx.y * 64, n0 = blockIdx.x * 128;

  const int ar0 = tid >> 2, ag0 = (tid & 3) ^ (ar0 & 3);
  int brow[2], bcg[2];
#pragma unroll
  for (int c = 0; c < 2; c++) {
    int i = c * 256 + tid;
    brow[c] = i >> 2;
    bcg[c] = (i & 3) ^ (brow[c] & 3);
  }
  const int axo = ((l4 ^ (l15 & 3)) * 8);

  f32x4 acc[4][2] = {};

  for (int kt = 0; kt < K; kt += 32) {
    __syncthreads();
    GLOAD_LDS16(&Ah[(size_t)(m0 + ar0) * K + kt + ag0 * 8], &lA[(wv * 64) * 8]);
    GLOAD_LDS16(&Al[(size_t)(m0 + ar0) * K + kt + ag0 * 8], &lA2[(wv * 64) * 8]);
#pragma unroll
    for (int c = 0; c < 2; c++) {
      GLOAD_LDS16(&Bh[(size_t)(n0 + brow[c]) * K + kt + bcg[c] * 8],
                  &lB[(c * 256 + wv * 64) * 8]);
      GLOAD_LDS16(&Bl[(size_t)(n0 + brow[c]) * K + kt + bcg[c] * 8],
                  &lB2[(c * 256 + wv * 64) * 8]);
    }
    __syncthreads();
    bf16x8 af[4], af2[4];
#pragma unroll
    for (int mt = 0; mt < 4; mt++) {
      af[mt]  = *(bf16x8*)&lA[(mt * 16 + l15) * 32 + axo];
      af2[mt] = *(bf16x8*)&lA2[(mt * 16 + l15) * 32 + axo];
    }
#pragma unroll
    for (int nt = 0; nt < 2; nt++) {
      bf16x8 bh = *(bf16x8*)&lB[(wc * 32 + nt * 16 + l15) * 32 + axo];
      bf16x8 bl = *(bf16x8*)&lB2[(wc * 32 + nt * 16 + l15) * 32 + axo];
#pragma unroll
      for (int mt = 0; mt < 4; mt++) {
        acc[mt][nt] = __builtin_amdgcn_mfma_f32_16x16x32_bf16(af[mt], bh, acc[mt][nt], 0, 0, 0);
        acc[mt][nt] = __builtin_amdgcn_mfma_f32_16x16x32_bf16(af[mt], bl, acc[mt][nt], 0, 0, 0);
        acc[mt][nt] = __builtin_amdgcn_mfma_f32_16x16x32_bf16(af2[mt], bh, acc[mt][nt], 0, 0, 0);
      }
    }
  }

  const int cb = n0 >> 7;

  if (cb >= 8) {
    // Vx: transpose through LDS (pad 72 keeps 16B alignment), coalesced stores
    __syncthreads();
#pragma unroll
    for (int mt = 0; mt < 4; mt++)
#pragma unroll
      for (int j = 0; j < 4; j++) {
        int rl = mt * 16 + l4 * 4 + j;
#pragma unroll
        for (int nt = 0; nt < 2; nt++) {
          int d = wc * 32 + nt * 16 + l15;
          sT[d * 72 + rl] = bf16_rne_bits(acc[mt][nt][j]);
        }
      }
    __syncthreads();
    int gg = cb - 8;
    int d = tid >> 1, rh = (tid & 1) << 5;
    size_t gbase = (((size_t)(m0 >> 9) * G_ + gg) * D_ + d) * (size_t)SC_ +
                   (m0 & 511) + rh;
    const uint16_t* sp = &sT[d * 72 + rh];
#pragma unroll
    for (int k = 0; k < 4; k++)
      *(bf16x8*)&Vxtf[gbase + k * 8] = *(const bf16x8*)&sp[k * 8];
    return;
  }

  float mu_[4][4], rs_[4][4];
#pragma unroll
  for (int mt = 0; mt < 4; mt++)
#pragma unroll
    for (int j = 0; j < 4; j++) {
      float s = 0.f, sq = 0.f;
#pragma unroll
      for (int nt = 0; nt < 2; nt++) { float t = acc[mt][nt][j]; s += t; sq += t * t; }
#pragma unroll
      for (int mm = 1; mm < 16; mm <<= 1) { s += __shfl_xor(s, mm); sq += __shfl_xor(sq, mm); }
      if (l15 == 0) {
        int ar = mt * 16 + l4 * 4 + j;
        sred[wc * 64 + ar] = s;
        sred[256 + wc * 64 + ar] = sq;
      }
    }
  __syncthreads();
#pragma unroll
  for (int mt = 0; mt < 4; mt++)
#pragma unroll
    for (int j = 0; j < 4; j++) {
      int ar = mt * 16 + l4 * 4 + j;
      float Sm = sred[ar] + sred[64 + ar] + sred[128 + ar] + sred[192 + ar];
      float Sq = sred[256 + ar] + sred[320 + ar] + sred[384 + ar] + sred[448 + ar];
      float mu = Sm * (1.f / 128.f);
      float var = Sq * (1.f / 128.f) - mu * mu;
      mu_[mt][j] = mu;
      rs_[mt][j] = 1.f / sqrtf(var + 1e-5f);
    }

#pragma unroll
  for (int mt = 0; mt < 4; mt++)
#pragma unroll
    for (int j = 0; j < 4; j++) {
      int r = m0 + mt * 16 + l4 * 4 + j;
#pragma unroll
      for (int nt = 0; nt < 2; nt++) {
        int d = wc * 32 + nt * 16 + l15;
        float y = (acc[mt][nt][j] - mu_[mt][j]) * rs_[mt][j] * kxln_w[d] + kxln_b[d];
        Kxf[((size_t)r * G_ + cb) * D_ + d] = f16_bits(y);
      }
    }
}

// ---------------- merged flash GQA attention (fixed-max, bf16 PV) ------------
// z: 0,1 = self batches; 2,3 = cross batches. Q pre-scaled by SCL*log2e.
// LN guarantees |score_log2| <= 16.33 -> fixed max via MFMA C-init, no
// max-tracking. P,V in bf16 (p in (2^-33,1] would flush in f16).
__global__ __launch_bounds__(256) void k_attn(
    const uint16_t* __restrict__ Qs, const uint16_t* __restrict__ Qx,
    const uint16_t* __restrict__ Ks, const uint16_t* __restrict__ Vs,
    const uint16_t* __restrict__ Kx, const uint16_t* __restrict__ Vx,
    const float* __restrict__ smooth, uint8_t* __restrict__ catq)
{
  __shared__ __align__(16) uint16_t lK[2][32 * 128];
  __shared__ __align__(16) uint16_t lV[2][128 * 32];
  __shared__ __align__(16) uint16_t lP[64 * 40];

  const int tid = threadIdx.x, lane = tid & 63, wv = tid >> 6;
  const int l15 = lane & 15, l4 = lane >> 4;
  const int q0 = blockIdx.x * 64, h = blockIdx.y;
  const int zb = blockIdx.z;
  const int b = zb & 1;
  const bool xr = zb >= 2;
  const uint16_t* __restrict__ Q = xr ? Qx : Qs;
  const uint16_t* __restrict__ Kp = xr ? Kx : Ks;
  const uint16_t* __restrict__ Vp = xr ? Vx : Vs;
  const int T = xr ? SC_ : S_;
  const int colOff = xr ? 2048 : 0;
  const int g = h >> 1;

  f16x8 qf[4];
  {
    int srow = q0 + wv * 16 + l15;
    size_t base = (((size_t)b * S_ + srow) * NH_ + h) * (size_t)D_ + l4 * 8;
#pragma unroll
    for (int ks = 0; ks < 4; ks++)
      qf[ks] = *(const f16x8*)&Q[base + ks * 32];
  }

  int krow[2], kcg[2], vrow[2], vcg[2];
#pragma unroll
  for (int c = 0; c < 2; c++) {
    int i = c * 256 + tid;
    krow[c] = i >> 4;
    kcg[c] = (i & 15) ^ (krow[c] & 7);
    vrow[c] = i >> 2;
    vcg[c] = (i & 3) ^ (vrow[c] & 3);
  }
  // paired-column K mapping: output col l15 of MFMA nt <-> K row t = 2*l15+nt.
  int koff[2][4];
#pragma unroll
  for (int nt = 0; nt < 2; nt++)
#pragma unroll
    for (int ks = 0; ks < 4; ks++) {
      int t = 2 * l15 + nt;
      koff[nt][ks] = t * 128 + (((ks * 4 + l4) ^ (t & 7)) * 8);
    }
  const int vxo = (l4 ^ (l15 & 3)) * 8;

  const f32x4 CINIT = {-FIXED_M, -FIXED_M, -FIXED_M, -FIXED_M};
  float lsump[4] = {0.f, 0.f, 0.f, 0.f};
  f32x4 oacc[8] = {};

  // running staging pointers (advance by constant per tile)
  const uint16_t* pK[2];
  const uint16_t* pV[2];
#pragma unroll
  for (int c = 0; c < 2; c++) {
    pK[c] = Kp + ((size_t)b * T + krow[c]) * (G_ * D_) + (size_t)g * D_ + kcg[c] * 8;
    pV[c] = Vp + (((size_t)b * G_ + g) * (size_t)D_ + vrow[c]) * (size_t)T + vcg[c] * 8;
  }

  // prologue: stage tile 0 into buf 0
#pragma unroll
  for (int c = 0; c < 2; c++) {
    GLOAD_LDS16(pK[c], &lK[0][(c * 256 + wv * 64) * 8]);
    GLOAD_LDS16(pV[c], &lV[0][(c * 256 + wv * 64) * 8]);
    pK[c] += 32 * G_ * D_;
    pV[c] += 32;
  }

  const int nT = T >> 5;
  for (int tt = 0; tt < nT; tt++) {
    const int cur = tt & 1;
    __syncthreads();
    if (tt + 1 < nT) {
#pragma unroll
      for (int c = 0; c < 2; c++) {
        GLOAD_LDS16(pK[c], &lK[cur ^ 1][(c * 256 + wv * 64) * 8]);
        GLOAD_LDS16(pV[c], &lV[cur ^ 1][(c * 256 + wv * 64) * 8]);
        pK[c] += 32 * G_ * D_;
        pV[c] += 32;
      }
    }

    f32x4 sf[2];
    __builtin_amdgcn_s_setprio(1);
#pragma unroll
    for (int nt = 0; nt < 2; nt++) {
      f16x8 kf0 = *(f16x8*)&lK[cur][koff[nt][0]];
      f32x4 a = __builtin_amdgcn_mfma_f32_16x16x32_f16(qf[0], kf0, CINIT, 0, 0, 0);
#pragma unroll
      for (int ks = 1; ks < 4; ks++) {
        f16x8 kf = *(f16x8*)&lK[cur][koff[nt][ks]];
        a = __builtin_amdgcn_mfma_f32_16x16x32_f16(qf[ks], kf, a, 0, 0, 0);
      }
      sf[nt] = a;
    }
    __builtin_amdgcn_s_setprio(0);

    // branchless softmax: p = exp2(s - M), M already folded into MFMA C-init
#pragma unroll
    for (int j = 0; j < 4; j++) {
      float p0 = __builtin_amdgcn_exp2f(sf[0][j]);
      float p1 = __builtin_amdgcn_exp2f(sf[1][j]);
      lsump[j] += p0 + p1;
      int prow = wv * 16 + l4 * 4 + j;
      uint32_t pk;
      asm("v_cvt_pk_bf16_f32 %0, %1, %2" : "=v"(pk) : "v"(p0), "v"(p1));
      *(uint32_t*)&lP[prow * 40 + l15 * 2] = pk;   // cols 2*l15, 2*l15+1
    }

    bf16x8 pa = *(bf16x8*)&lP[(wv * 16 + l15) * 40 + l4 * 8];
    __builtin_amdgcn_s_setprio(1);
#pragma unroll
    for (int dt = 0; dt < 8; dt++) {
      bf16x8 vh = *(bf16x8*)&lV[cur][(dt * 16 + l15) * 32 + vxo];
      oacc[dt] = __builtin_amdgcn_mfma_f32_16x16x32_bf16(pa, vh, oacc[dt], 0, 0, 0);
    }
    __builtin_amdgcn_s_setprio(0);
  }

#pragma unroll
  for (int j = 0; j < 4; j++) {
    float rsum = lsump[j];
#pragma unroll
    for (int mm = 1; mm < 16; mm <<= 1) rsum += __shfl_xor(rsum, mm);
    float inv = 1.f / rsum;
    int srow = q0 + wv * 16 + l4 * 4 + j;
    size_t rbase = ((size_t)b * S_ + srow) * 4096;
#pragma unroll
    for (int dt = 0; dt < 8; dt++) {
      int c = colOff + h * D_ + dt * 16 + l15;
      float t = (oacc[dt][j] * inv) / smooth[c];
      t = fminf(fmaxf(t, -448.f), 448.f);
      t = fp8_rt(bf16_rne_f(t));
      catq[rbase + c] = fp8_enc(t);
    }
  }
}

// ---------------------------------------------------------------------------
extern "C" void kernel_launch(void* const* d_in, const int* in_sizes, int n_in,
                              void* d_out, int out_size, void* d_ws, size_t ws_size,
                              hipStream_t stream)
{
  (void)in_sizes; (void)n_in; (void)out_size;
  const float* hidden = (const float*)d_in[0];
  const float* cond   = (const float*)d_in[1];
  const float* ln_w   = (const float*)d_in[2];
  const float* ln_b   = (const float*)d_in[3];
  const float* wq     = (const float*)d_in[4];
  const float* wq_s   = (const float*)d_in[5];
  const float* q_is   = (const float*)d_in[6];
  const float* wqx    = (const float*)d_in[7];
  const float* wqx_s  = (const float*)d_in[8];
  const float* qx_is  = (const float*)d_in[9];
  const float* wk     = (const float*)d_in[10];
  const float* wk_s   = (const float*)d_in[11];
  const float* k_is   = (const float*)d_in[12];
  const float* wv     = (const float*)d_in[13];
  const float* wv_s   = (const float*)d_in[14];
  const float* v_is   = (const float*)d_in[15];
  const float* wkvx   = (const float*)d_in[16];
  const float* qln_w  = (const float*)d_in[17];
  const float* qln_b  = (const float*)d_in[18];
  const float* kln_w  = (const float*)d_in[19];
  const float* kln_b  = (const float*)d_in[20];
  const float* qxln_w = (const float*)d_in[21];
  const float* qxln_b = (const float*)d_in[22];
  const float* kxln_w = (const float*)d_in[23];
  const float* kxln_b = (const float*)d_in[24];
  const float* wproj  = (const float*)d_in[25];
  const float* p_ws   = (const float*)d_in[26];
  const float* p_is   = (const float*)d_in[27];
  const float* smooth = (const float*)d_in[28];

  char* ws = (char*)d_ws;
  size_t off = 0;
  auto alloc = [&](size_t bytes) {
    char* p = ws + off;
    off += (bytes + 255) & ~(size_t)255;
    return p;
  };
  uint8_t*  Aq    = (uint8_t*)alloc((size_t)4096 * 2048);
  uint8_t*  Wcat  = (uint8_t*)alloc((size_t)6144 * 2048);
  uint8_t*  Wpb   = (uint8_t*)alloc((size_t)2048 * 4096);
  uint16_t* Wkvxh = (uint16_t*)alloc((size_t)2048 * 2048 * 2);
  uint16_t* Wkvxl = (uint16_t*)alloc((size_t)2048 * 2048 * 2);
  uint16_t* condh = (uint16_t*)alloc((size_t)1024 * 2048 * 2);
  uint16_t* condl = (uint16_t*)alloc((size_t)1024 * 2048 * 2);
  uint16_t* Qh    = (uint16_t*)alloc((size_t)4096 * 16 * 128 * 2);
  uint16_t* Qxh   = (uint16_t*)alloc((size_t)4096 * 16 * 128 * 2);
  uint16_t* Kf    = (uint16_t*)alloc((size_t)4096 * 8 * 128 * 2);
  uint16_t* Vtf   = (uint16_t*)alloc((size_t)4096 * 8 * 128 * 2);
  uint16_t* Kxf   = (uint16_t*)alloc((size_t)1024 * 8 * 128 * 2);
  uint16_t* Vxtf  = (uint16_t*)alloc((size_t)1024 * 8 * 128 * 2);
  uint8_t*  catq  = (uint8_t*)alloc((size_t)4096 * 4096);
  float* scales   = (float*)alloc(256);
  if (ws_size < off) return;

  k_prep<<<2048, 256, 0, stream>>>(wq, wqx, wk, wv, wkvx, wproj, cond,
      q_is, wq_s, qx_is, wqx_s, k_is, wk_s, v_is, wv_s, p_is, p_ws,
      Wcat, Wpb, Wkvxh, Wkvxl, condh, condl, scales);

  k_ln_quant<<<4096, 256, 0, stream>>>(hidden, ln_w, ln_b, q_is, Aq);

  k_gemm8<0><<<dim3(48, 32), 256, 0, stream>>>(Aq, Wcat,
      4096, 6144, 2048, scales, qln_w, qln_b, kln_w, kln_b, qxln_w, qxln_b,
      Qh, Qxh, Kf, Vtf, nullptr);

  k_kvx<<<dim3(16, 16), 256, 0, stream>>>(condh, condl, Wkvxh, Wkvxl,
      kxln_w, kxln_b, Kxf, Vxtf);

  k_attn<<<dim3(32, 16, 4), 256, 0, stream>>>(Qh, Qxh, Kf, Vtf, Kxf, Vxtf,
      smooth, catq);

  k_gemm8<2><<<dim3(16, 32), 256, 0, stream>>>(catq, Wpb,
      4096, 2048, 4096, scales, nullptr, nullptr, nullptr, nullptr, nullptr, nullptr,
      nullptr, nullptr, nullptr, nullptr,
      (float*)d_out);
}

// Round 9
// 377.542 us; speedup vs baseline: 2.8613x; 1.0350x over previous
//
#include <hip/hip_runtime.h>
#include <hip/hip_bf16.h>
#include <stdint.h>

#define B_  2
#define S_  2048
#define SC_ 512
#define H_  2048
#define NH_ 16
#define G_  8
#define D_  128

typedef __attribute__((ext_vector_type(8))) short bf16x8;
typedef __attribute__((ext_vector_type(8))) _Float16 f16x8;
typedef __attribute__((ext_vector_type(4))) float f32x4;
typedef __attribute__((ext_vector_type(8))) int i32x8;

// SCL * log2(e) = (1/sqrt(128)) * 1.4426950408889634
#define SCLLOG2E 0.12751741f
// |score_log2| <= SCLLOG2E * ||q|| * ||k|| = SCLLOG2E*128 = 16.3222 (LN => unit rows)
#define FIXED_M  16.34f

#define GLOAD_LDS16(g, l) __builtin_amdgcn_global_load_lds( \
    (const __attribute__((address_space(1))) uint32_t*)(g), \
    (__attribute__((address_space(3))) uint32_t*)(l), 16, 0, 0)

__device__ __forceinline__ uint16_t bf16_rne_bits(float x) {
  uint32_t u = __float_as_uint(x);
  u += 0x7fffu + ((u >> 16) & 1u);
  return (uint16_t)(u >> 16);
}
__device__ __forceinline__ float bf16_rne_f(float x) {
  uint32_t u = __float_as_uint(x);
  u += 0x7fffu + ((u >> 16) & 1u);
  return __uint_as_float(u & 0xffff0000u);
}
__device__ __forceinline__ uint16_t f16_bits(float x) {
  _Float16 h = (_Float16)x;
  return __builtin_bit_cast(uint16_t, h);
}
// fp8 e4m3fn round-trip (RNE, input already clipped to [-448,448])
__device__ __forceinline__ float fp8_rt(float x) {
  float a = fabsf(x);
  float step;
  if (a >= 0.015625f) {
    uint32_t u = __float_as_uint(a);
    int E = (int)((u >> 23) & 0xffu) - 127;
    step = __uint_as_float((uint32_t)(E - 3 + 127) << 23);
  } else {
    step = 0.001953125f;
  }
  float q = rintf(a / step) * step;
  return x < 0.f ? -q : q;
}
// exact e4m3fn encode of a value that is already an exact fp8 value
__device__ __forceinline__ uint8_t fp8_enc(float v) {
  uint32_t u = __float_as_uint(v);
  uint8_t s = (uint8_t)((u >> 24) & 0x80u);
  float a = fabsf(v);
  if (a == 0.f) return s;
  int E = (int)((u >> 23) & 0xffu) - 127;
  if (E < -6) return s | (uint8_t)(a * 512.f);        // subnormal: k * 2^-9
  uint32_t mant = (u >> 20) & 7u;
  return s | ((uint8_t)(E + 7) << 3) | (uint8_t)mant;
}

// ---------------- prep: weight encodes / splits / scalar scales --------------
__global__ __launch_bounds__(256) void k_prep(
    const float* __restrict__ wq, const float* __restrict__ wqx,
    const float* __restrict__ wk, const float* __restrict__ wv,
    const float* __restrict__ wkvx, const float* __restrict__ wproj,
    const float* __restrict__ cond,
    const float* __restrict__ q_is, const float* __restrict__ wq_s,
    const float* __restrict__ qx_is, const float* __restrict__ wqx_s,
    const float* __restrict__ k_is, const float* __restrict__ wk_s,
    const float* __restrict__ v_is, const float* __restrict__ wv_s,
    const float* __restrict__ p_is, const float* __restrict__ p_ws,
    uint8_t* __restrict__ Wcat, uint8_t* __restrict__ Wpb,
    uint16_t* __restrict__ Wkvxh, uint16_t* __restrict__ Wkvxl,
    uint16_t* __restrict__ condh, uint16_t* __restrict__ condl,
    float* __restrict__ scales)
{
  size_t idx = (size_t)blockIdx.x * 256 + threadIdx.x;
  size_t stride = (size_t)gridDim.x * 256;
  const size_t NC = (size_t)6144 * 2048;
  for (size_t i = idx; i < NC; i += stride) {
    size_t row = i >> 11; int col = (int)(i & 2047);
    float v;
    if (row < 2048)      v = wq[i];
    else if (row < 4096) v = wqx[(row - 2048) * 2048 + col];
    else if (row < 5120) v = wk[(row - 4096) * 2048 + col];
    else                 v = wv[(row - 5120) * 2048 + col];
    Wcat[i] = fp8_enc(v);
  }
  const size_t NP = (size_t)2048 * 4096;
  for (size_t i = idx; i < NP; i += stride)
    Wpb[i] = fp8_enc(wproj[i]);
  const size_t NX = (size_t)2048 * 2048;
  for (size_t i = idx; i < NX; i += stride) {
    float x = wkvx[i];
    uint16_t h = bf16_rne_bits(x);
    Wkvxh[i] = h;
    Wkvxl[i] = bf16_rne_bits(x - __uint_as_float((uint32_t)h << 16));
  }
  const size_t ND = (size_t)1024 * 2048;
  for (size_t i = idx; i < ND; i += stride) {
    float x = cond[i];
    uint16_t h = bf16_rne_bits(x);
    condh[i] = h;
    condl[i] = bf16_rne_bits(x - __uint_as_float((uint32_t)h << 16));
  }
  if (idx == 0) {
    scales[0] = q_is[0] * wq_s[0];
    scales[1] = qx_is[0] * wqx_s[0];
    scales[2] = k_is[0] * wk_s[0];
    scales[3] = v_is[0] * wv_s[0];
    scales[4] = p_is[0] * p_ws[0];
  }
}

// ---------------- hidden LayerNorm + fp8 quantize -> Aq (fp8 bytes) ----------
__global__ __launch_bounds__(256) void k_ln_quant(
    const float* __restrict__ x, const float* __restrict__ w,
    const float* __restrict__ b, const float* __restrict__ qis,
    uint8_t* __restrict__ Aq)
{
  int row = blockIdx.x;
  int tid = threadIdx.x;
  const float* xr = x + (size_t)row * H_;
  float v[8];
  float s = 0.f, sq = 0.f;
#pragma unroll
  for (int i = 0; i < 8; i++) {
    float t = xr[tid + i * 256];
    v[i] = t; s += t; sq += t * t;
  }
#pragma unroll
  for (int m = 1; m < 64; m <<= 1) { s += __shfl_xor(s, m); sq += __shfl_xor(sq, m); }
  __shared__ float red[8];
  int wv = tid >> 6;
  if ((tid & 63) == 0) { red[wv] = s; red[4 + wv] = sq; }
  __syncthreads();
  s = red[0] + red[1] + red[2] + red[3];
  sq = red[4] + red[5] + red[6] + red[7];
  float mu = s * (1.f / H_);
  float var = sq * (1.f / H_) - mu * mu;
  float rs = 1.0f / sqrtf(var + 1e-5f);
#pragma unroll
  for (int i = 0; i < 8; i++) {
    int c = tid + i * 256;
    float y = (v[i] - mu) * rs * w[c] + b[c];
    float t = y / qis[c];
    t = fminf(fmaxf(t, -448.f), 448.f);
    t = fp8_rt(bf16_rne_f(t));
    Aq[(size_t)row * H_ + c] = fp8_enc(t);
  }
}

// ---------------- MX-fp8 GEMM (B^T layout), K-step = 128 fp8 bytes -----------
// MODE 0: QKV proj -> per-head LN -> Q/Qx pre-scaled f16, K f16, V^T bf16
// MODE 2: out proj -> *scale -> f32 out
template <int MODE>
__global__ __launch_bounds__(256) void k_gemm8(
    const uint8_t* __restrict__ A, const uint8_t* __restrict__ Bm,
    int M, int N, int K,
    const float* __restrict__ scales,
    const float* __restrict__ qln_w, const float* __restrict__ qln_b,
    const float* __restrict__ kln_w, const float* __restrict__ kln_b,
    const float* __restrict__ qxln_w, const float* __restrict__ qxln_b,
    uint16_t* __restrict__ Qh,
    uint16_t* __restrict__ Qxh,
    uint16_t* __restrict__ Kf, uint16_t* __restrict__ Vtf,
    float* __restrict__ Cout)
{
  __shared__ __align__(64) uint8_t smem[128 * 136 * 2];  // >= 32768+2048 staging+sred
  uint8_t* lA = smem;
  uint8_t* lB = smem + 128 * 128;
  float* sred = (float*)(smem + 128 * 128 * 2);
  uint16_t* sT = (uint16_t*)smem;          // V-path overlay: 128*136*2 = 34816 B

  const int tid = threadIdx.x;
  const int lane = tid & 63;
  const int wv = tid >> 6;
  const int wr = wv >> 1, wc = wv & 1;
  const int l15 = lane & 15, l4 = lane >> 4;
  const int m0 = blockIdx.y * 128, n0 = blockIdx.x * 128;

  int srow[4]; int soff[4];
#pragma unroll
  for (int c = 0; c < 4; c++) {
    int i = c * 256 + tid;
    int row = i >> 3, s = i & 7;
    srow[c] = row;
    soff[c] = (((s >> 1) ^ (row & 3)) << 5) + ((s & 1) << 4);
  }
  const int axo = ((l4 ^ (l15 & 3)) << 5);

  f32x4 acc[4][4] = {};

  for (int kt = 0; kt < K; kt += 128) {
    __syncthreads();
#pragma unroll
    for (int c = 0; c < 4; c++) {
      GLOAD_LDS16(&A[(size_t)(m0 + srow[c]) * K + kt + soff[c]],
                  &lA[(c * 256 + wv * 64) * 16]);
      GLOAD_LDS16(&Bm[(size_t)(n0 + srow[c]) * K + kt + soff[c]],
                  &lB[(c * 256 + wv * 64) * 16]);
    }
    __syncthreads();
    i32x8 af[4];
#pragma unroll
    for (int mt = 0; mt < 4; mt++)
      af[mt] = *(i32x8*)&lA[(wr * 64 + mt * 16 + l15) * 128 + axo];
#pragma unroll
    for (int nt = 0; nt < 4; nt++) {
      i32x8 bf = *(i32x8*)&lB[(wc * 64 + nt * 16 + l15) * 128 + axo];
#pragma unroll
      for (int mt = 0; mt < 4; mt++)
        acc[mt][nt] = __builtin_amdgcn_mfma_scale_f32_16x16x128_f8f6f4(
            af[mt], bf, acc[mt][nt], 0, 0, 0, 0x7F7F7F7F, 0, 0x7F7F7F7F);
    }
  }

  const int cb = n0 >> 7;
  float sscale;
  const float *lw = nullptr, *lb = nullptr;
  if (MODE == 0) {
    int sect = (cb < 16) ? 0 : (cb < 32) ? 1 : (cb < 40) ? 2 : 3;
    sscale = scales[sect];
    if (sect == 0) { lw = qln_w; lb = qln_b; }
    else if (sect == 1) { lw = qxln_w; lb = qxln_b; }
    else if (sect == 2) { lw = kln_w; lb = kln_b; }
  } else {
    sscale = scales[4];
  }
#pragma unroll
  for (int mt = 0; mt < 4; mt++)
#pragma unroll
    for (int nt = 0; nt < 4; nt++)
#pragma unroll
      for (int j = 0; j < 4; j++) acc[mt][nt][j] *= sscale;

  if (MODE == 2) {
#pragma unroll
    for (int mt = 0; mt < 4; mt++)
#pragma unroll
      for (int j = 0; j < 4; j++) {
        int r = m0 + wr * 64 + mt * 16 + l4 * 4 + j;
#pragma unroll
        for (int nt = 0; nt < 4; nt++) {
          int c = n0 + wc * 64 + nt * 16 + l15;
          Cout[(size_t)r * N + c] = acc[mt][nt][j];
        }
      }
    return;
  }

  if (MODE == 0 && cb >= 40) {
    // V section: transpose through LDS, coalesced bf16 stores.
    __syncthreads();   // staging LDS no longer needed; safe to overlay
#pragma unroll
    for (int mt = 0; mt < 4; mt++)
#pragma unroll
      for (int j = 0; j < 4; j++) {
        int rl = wr * 64 + mt * 16 + l4 * 4 + j;
#pragma unroll
        for (int nt = 0; nt < 4; nt++) {
          int d = wc * 64 + nt * 16 + l15;
          sT[d * 136 + rl] = bf16_rne_bits(acc[mt][nt][j]);
        }
      }
    __syncthreads();
    int gg = cb - 40;
    int d = tid >> 1, rh = (tid & 1) << 6;
    size_t gbase = (((size_t)(m0 >> 11) * G_ + gg) * D_ + d) * (size_t)S_ +
                   (m0 & 2047) + rh;
    const uint16_t* sp = &sT[d * 136 + rh];
#pragma unroll
    for (int k = 0; k < 8; k++)
      *(bf16x8*)&Vtf[gbase + k * 8] = *(const bf16x8*)&sp[k * 8];
    return;
  }

  // Q / Qx / K sections: per-head LN over the 128-col tile
  float mu_[4][4], rs_[4][4];
#pragma unroll
  for (int mt = 0; mt < 4; mt++)
#pragma unroll
    for (int j = 0; j < 4; j++) {
      float s = 0.f, sq = 0.f;
#pragma unroll
      for (int nt = 0; nt < 4; nt++) { float t = acc[mt][nt][j]; s += t; sq += t * t; }
#pragma unroll
      for (int mm = 1; mm < 16; mm <<= 1) { s += __shfl_xor(s, mm); sq += __shfl_xor(sq, mm); }
      if (l15 == 0) {
        int ar = wr * 64 + mt * 16 + l4 * 4 + j;
        sred[wc * 128 + ar] = s;
        sred[256 + wc * 128 + ar] = sq;
      }
    }
  __syncthreads();
#pragma unroll
  for (int mt = 0; mt < 4; mt++)
#pragma unroll
    for (int j = 0; j < 4; j++) {
      int ar = wr * 64 + mt * 16 + l4 * 4 + j;
      float Sm = sred[ar] + sred[128 + ar];
      float Sq = sred[256 + ar] + sred[384 + ar];
      float mu = Sm * (1.f / 128.f);
      float var = Sq * (1.f / 128.f) - mu * mu;
      mu_[mt][j] = mu;
      rs_[mt][j] = 1.f / sqrtf(var + 1e-5f);
    }

#pragma unroll
  for (int mt = 0; mt < 4; mt++)
#pragma unroll
    for (int j = 0; j < 4; j++) {
      int r = m0 + wr * 64 + mt * 16 + l4 * 4 + j;
#pragma unroll
      for (int nt = 0; nt < 4; nt++) {
        int d = wc * 64 + nt * 16 + l15;
        float y = (acc[mt][nt][j] - mu_[mt][j]) * rs_[mt][j] * lw[d] + lb[d];
        if (cb < 32) y *= SCLLOG2E;   // fold softmax scale + log2e into Q/Qx
        uint16_t hb = f16_bits(y);
        if (cb < 16) {
          Qh[((size_t)r * NH_ + cb) * D_ + d] = hb;
        } else if (cb < 32) {
          Qxh[((size_t)r * NH_ + (cb - 16)) * D_ + d] = hb;
        } else {
          Kf[((size_t)r * G_ + (cb - 32)) * D_ + d] = hb;
        }
      }
    }
}

// ---------------- kvx GEMM: m97 structure, split A/B 3-MFMA, BM=64 -----------
__global__ __launch_bounds__(256) void k_kvx(
    const uint16_t* __restrict__ Ah, const uint16_t* __restrict__ Al,
    const uint16_t* __restrict__ Bh, const uint16_t* __restrict__ Bl,
    const float* __restrict__ kxln_w, const float* __restrict__ kxln_b,
    uint16_t* __restrict__ Kxf, uint16_t* __restrict__ Vxtf)
{
  const int K = 2048;
  __shared__ __align__(64) uint8_t smem[26624];
  uint16_t* lA  = (uint16_t*)smem;                 // 64*32*2  = 4096
  uint16_t* lA2 = (uint16_t*)(smem + 4096);        // 4096
  uint16_t* lB  = (uint16_t*)(smem + 8192);        // 128*32*2 = 8192
  uint16_t* lB2 = (uint16_t*)(smem + 16384);       // 8192
  float* sred = (float*)(smem + 24576);
  uint16_t* sT = (uint16_t*)smem;                  // Vx overlay: 128*72*2 = 18432

  const int tid = threadIdx.x;
  const int lane = tid & 63;
  const int wv = tid >> 6;
  const int wc = wv;
  const int l15 = lane & 15, l4 = lane >> 4;
  const int m0 = blockIdx.y * 64, n0 = blockIdx.x * 128;

  const int ar0 = tid >> 2, ag0 = (tid & 3) ^ (ar0 & 3);
  int brow[2], bcg[2];
#pragma unroll
  for (int c = 0; c < 2; c++) {
    int i = c * 256 + tid;
    brow[c] = i >> 2;
    bcg[c] = (i & 3) ^ (brow[c] & 3);
  }
  const int axo = ((l4 ^ (l15 & 3)) * 8);

  f32x4 acc[4][2] = {};

  for (int kt = 0; kt < K; kt += 32) {
    __syncthreads();
    GLOAD_LDS16(&Ah[(size_t)(m0 + ar0) * K + kt + ag0 * 8], &lA[(wv * 64) * 8]);
    GLOAD_LDS16(&Al[(size_t)(m0 + ar0) * K + kt + ag0 * 8], &lA2[(wv * 64) * 8]);
#pragma unroll
    for (int c = 0; c < 2; c++) {
      GLOAD_LDS16(&Bh[(size_t)(n0 + brow[c]) * K + kt + bcg[c] * 8],
                  &lB[(c * 256 + wv * 64) * 8]);
      GLOAD_LDS16(&Bl[(size_t)(n0 + brow[c]) * K + kt + bcg[c] * 8],
                  &lB2[(c * 256 + wv * 64) * 8]);
    }
    __syncthreads();
    bf16x8 af[4], af2[4];
#pragma unroll
    for (int mt = 0; mt < 4; mt++) {
      af[mt]  = *(bf16x8*)&lA[(mt * 16 + l15) * 32 + axo];
      af2[mt] = *(bf16x8*)&lA2[(mt * 16 + l15) * 32 + axo];
    }
#pragma unroll
    for (int nt = 0; nt < 2; nt++) {
      bf16x8 bh = *(bf16x8*)&lB[(wc * 32 + nt * 16 + l15) * 32 + axo];
      bf16x8 bl = *(bf16x8*)&lB2[(wc * 32 + nt * 16 + l15) * 32 + axo];
#pragma unroll
      for (int mt = 0; mt < 4; mt++) {
        acc[mt][nt] = __builtin_amdgcn_mfma_f32_16x16x32_bf16(af[mt], bh, acc[mt][nt], 0, 0, 0);
        acc[mt][nt] = __builtin_amdgcn_mfma_f32_16x16x32_bf16(af[mt], bl, acc[mt][nt], 0, 0, 0);
        acc[mt][nt] = __builtin_amdgcn_mfma_f32_16x16x32_bf16(af2[mt], bh, acc[mt][nt], 0, 0, 0);
      }
    }
  }

  const int cb = n0 >> 7;

  if (cb >= 8) {
    // Vx: transpose through LDS (pad 72 keeps 16B alignment), coalesced stores
    __syncthreads();
#pragma unroll
    for (int mt = 0; mt < 4; mt++)
#pragma unroll
      for (int j = 0; j < 4; j++) {
        int rl = mt * 16 + l4 * 4 + j;
#pragma unroll
        for (int nt = 0; nt < 2; nt++) {
          int d = wc * 32 + nt * 16 + l15;
          sT[d * 72 + rl] = bf16_rne_bits(acc[mt][nt][j]);
        }
      }
    __syncthreads();
    int gg = cb - 8;
    int d = tid >> 1, rh = (tid & 1) << 5;
    size_t gbase = (((size_t)(m0 >> 9) * G_ + gg) * D_ + d) * (size_t)SC_ +
                   (m0 & 511) + rh;
    const uint16_t* sp = &sT[d * 72 + rh];
#pragma unroll
    for (int k = 0; k < 4; k++)
      *(bf16x8*)&Vxtf[gbase + k * 8] = *(const bf16x8*)&sp[k * 8];
    return;
  }

  float mu_[4][4], rs_[4][4];
#pragma unroll
  for (int mt = 0; mt < 4; mt++)
#pragma unroll
    for (int j = 0; j < 4; j++) {
      float s = 0.f, sq = 0.f;
#pragma unroll
      for (int nt = 0; nt < 2; nt++) { float t = acc[mt][nt][j]; s += t; sq += t * t; }
#pragma unroll
      for (int mm = 1; mm < 16; mm <<= 1) { s += __shfl_xor(s, mm); sq += __shfl_xor(sq, mm); }
      if (l15 == 0) {
        int ar = mt * 16 + l4 * 4 + j;
        sred[wc * 64 + ar] = s;
        sred[256 + wc * 64 + ar] = sq;
      }
    }
  __syncthreads();
#pragma unroll
  for (int mt = 0; mt < 4; mt++)
#pragma unroll
    for (int j = 0; j < 4; j++) {
      int ar = mt * 16 + l4 * 4 + j;
      float Sm = sred[ar] + sred[64 + ar] + sred[128 + ar] + sred[192 + ar];
      float Sq = sred[256 + ar] + sred[320 + ar] + sred[384 + ar] + sred[448 + ar];
      float mu = Sm * (1.f / 128.f);
      float var = Sq * (1.f / 128.f) - mu * mu;
      mu_[mt][j] = mu;
      rs_[mt][j] = 1.f / sqrtf(var + 1e-5f);
    }

#pragma unroll
  for (int mt = 0; mt < 4; mt++)
#pragma unroll
    for (int j = 0; j < 4; j++) {
      int r = m0 + mt * 16 + l4 * 4 + j;
#pragma unroll
      for (int nt = 0; nt < 2; nt++) {
        int d = wc * 32 + nt * 16 + l15;
        float y = (acc[mt][nt][j] - mu_[mt][j]) * rs_[mt][j] * kxln_w[d] + kxln_b[d];
        Kxf[((size_t)r * G_ + cb) * D_ + d] = f16_bits(y);
      }
    }
}

// ---------------- merged flash GQA attention (8-wave, QBLK=128) --------------
// z: 0,1 = self batches; 2,3 = cross batches. Q pre-scaled by SCL*log2e.
// Fixed max via MFMA C-init (LN => |score_log2| <= 16.33). P,V in bf16.
// 8 waves x 16 q-rows share each staged K/V tile; LDS exactly 40 KB ->
// 4 blocks/CU x 8 waves = full occupancy.
__global__ __launch_bounds__(512) void k_attn(
    const uint16_t* __restrict__ Qs, const uint16_t* __restrict__ Qx,
    const uint16_t* __restrict__ Ks, const uint16_t* __restrict__ Vs,
    const uint16_t* __restrict__ Kx, const uint16_t* __restrict__ Vx,
    const float* __restrict__ smooth, uint8_t* __restrict__ catq)
{
  __shared__ __align__(16) uint16_t lK[2][32 * 128];   // 16 KB
  __shared__ __align__(16) uint16_t lV[2][128 * 32];   // 16 KB
  __shared__ __align__(16) uint16_t lP[128 * 32];      // 8 KB

  const int tid = threadIdx.x, lane = tid & 63, wv = tid >> 6;  // wv 0..7
  const int l15 = lane & 15, l4 = lane >> 4;
  const int q0 = blockIdx.x * 128, h = blockIdx.y;
  const int zb = blockIdx.z;
  const int b = zb & 1;
  const bool xr = zb >= 2;
  const uint16_t* __restrict__ Q = xr ? Qx : Qs;
  const uint16_t* __restrict__ Kp = xr ? Kx : Ks;
  const uint16_t* __restrict__ Vp = xr ? Vx : Vs;
  const int T = xr ? SC_ : S_;
  const int colOff = xr ? 2048 : 0;
  const int g = h >> 1;

  f16x8 qf[4];
  {
    int srow = q0 + wv * 16 + l15;
    size_t base = (((size_t)b * S_ + srow) * NH_ + h) * (size_t)D_ + l4 * 8;
#pragma unroll
    for (int ks = 0; ks < 4; ks++)
      qf[ks] = *(const f16x8*)&Q[base + ks * 32];
  }

  // staging: 512 threads, 1 chunk (16 B) each for K and V
  const int krow = tid >> 4, kcg = (tid & 15) ^ (krow & 7);
  const int vrow = tid >> 2, vcg = (tid & 3) ^ (vrow & 3);

  // paired-column K mapping: output col l15 of MFMA nt <-> K row t = 2*l15+nt.
  int koff[2][4];
#pragma unroll
  for (int nt = 0; nt < 2; nt++)
#pragma unroll
    for (int ks = 0; ks < 4; ks++) {
      int t = 2 * l15 + nt;
      koff[nt][ks] = t * 128 + (((ks * 4 + l4) ^ (t & 7)) * 8);
    }
  const int vxo = (l4 ^ (l15 & 3)) * 8;

  const f32x4 CINIT = {-FIXED_M, -FIXED_M, -FIXED_M, -FIXED_M};
  float lsump[4] = {0.f, 0.f, 0.f, 0.f};
  f32x4 oacc[8] = {};

  const uint16_t* pK = Kp + ((size_t)b * T + krow) * (G_ * D_) + (size_t)g * D_ + kcg * 8;
  const uint16_t* pV = Vp + (((size_t)b * G_ + g) * (size_t)D_ + vrow) * (size_t)T + vcg * 8;

  // prologue: stage tile 0 into buf 0
  GLOAD_LDS16(pK, &lK[0][(wv * 64) * 8]);
  GLOAD_LDS16(pV, &lV[0][(wv * 64) * 8]);
  pK += 32 * G_ * D_;
  pV += 32;

  const int nT = T >> 5;
  for (int tt = 0; tt < nT; tt++) {
    const int cur = tt & 1;
    __syncthreads();
    if (tt + 1 < nT) {
      GLOAD_LDS16(pK, &lK[cur ^ 1][(wv * 64) * 8]);
      GLOAD_LDS16(pV, &lV[cur ^ 1][(wv * 64) * 8]);
      pK += 32 * G_ * D_;
      pV += 32;
    }

    f32x4 sf[2];
    __builtin_amdgcn_s_setprio(1);
#pragma unroll
    for (int nt = 0; nt < 2; nt++) {
      f16x8 kf0 = *(f16x8*)&lK[cur][koff[nt][0]];
      f32x4 a = __builtin_amdgcn_mfma_f32_16x16x32_f16(qf[0], kf0, CINIT, 0, 0, 0);
#pragma unroll
      for (int ks = 1; ks < 4; ks++) {
        f16x8 kf = *(f16x8*)&lK[cur][koff[nt][ks]];
        a = __builtin_amdgcn_mfma_f32_16x16x32_f16(qf[ks], kf, a, 0, 0, 0);
      }
      sf[nt] = a;
    }
    __builtin_amdgcn_s_setprio(0);

    // branchless softmax: p = exp2(s - M), M folded into MFMA C-init
#pragma unroll
    for (int j = 0; j < 4; j++) {
      float p0 = __builtin_amdgcn_exp2f(sf[0][j]);
      float p1 = __builtin_amdgcn_exp2f(sf[1][j]);
      lsump[j] += p0 + p1;
      int prow = wv * 16 + l4 * 4 + j;
      uint32_t pk;
      asm("v_cvt_pk_bf16_f32 %0, %1, %2" : "=v"(pk) : "v"(p0), "v"(p1));
      *(uint32_t*)&lP[prow * 32 + l15 * 2] = pk;   // cols 2*l15, 2*l15+1
    }

    bf16x8 pa = *(bf16x8*)&lP[(wv * 16 + l15) * 32 + l4 * 8];
    __builtin_amdgcn_s_setprio(1);
#pragma unroll
    for (int dt = 0; dt < 8; dt++) {
      bf16x8 vh = *(bf16x8*)&lV[cur][(dt * 16 + l15) * 32 + vxo];
      oacc[dt] = __builtin_amdgcn_mfma_f32_16x16x32_bf16(pa, vh, oacc[dt], 0, 0, 0);
    }
    __builtin_amdgcn_s_setprio(0);
  }

#pragma unroll
  for (int j = 0; j < 4; j++) {
    float rsum = lsump[j];
#pragma unroll
    for (int mm = 1; mm < 16; mm <<= 1) rsum += __shfl_xor(rsum, mm);
    float inv = 1.f / rsum;
    int srow = q0 + wv * 16 + l4 * 4 + j;
    size_t rbase = ((size_t)b * S_ + srow) * 4096;
#pragma unroll
    for (int dt = 0; dt < 8; dt++) {
      int c = colOff + h * D_ + dt * 16 + l15;
      float t = (oacc[dt][j] * inv) / smooth[c];
      t = fminf(fmaxf(t, -448.f), 448.f);
      t = fp8_rt(bf16_rne_f(t));
      catq[rbase + c] = fp8_enc(t);
    }
  }
}

// ---------------------------------------------------------------------------
extern "C" void kernel_launch(void* const* d_in, const int* in_sizes, int n_in,
                              void* d_out, int out_size, void* d_ws, size_t ws_size,
                              hipStream_t stream)
{
  (void)in_sizes; (void)n_in; (void)out_size;
  const float* hidden = (const float*)d_in[0];
  const float* cond   = (const float*)d_in[1];
  const float* ln_w   = (const float*)d_in[2];
  const float* ln_b   = (const float*)d_in[3];
  const float* wq     = (const float*)d_in[4];
  const float* wq_s   = (const float*)d_in[5];
  const float* q_is   = (const float*)d_in[6];
  const float* wqx    = (const float*)d_in[7];
  const float* wqx_s  = (const float*)d_in[8];
  const float* qx_is  = (const float*)d_in[9];
  const float* wk     = (const float*)d_in[10];
  const float* wk_s   = (const float*)d_in[11];
  const float* k_is   = (const float*)d_in[12];
  const float* wv     = (const float*)d_in[13];
  const float* wv_s   = (const float*)d_in[14];
  const float* v_is   = (const float*)d_in[15];
  const float* wkvx   = (const float*)d_in[16];
  const float* qln_w  = (const float*)d_in[17];
  const float* qln_b  = (const float*)d_in[18];
  const float* kln_w  = (const float*)d_in[19];
  const float* kln_b  = (const float*)d_in[20];
  const float* qxln_w = (const float*)d_in[21];
  const float* qxln_b = (const float*)d_in[22];
  const float* kxln_w = (const float*)d_in[23];
  const float* kxln_b = (const float*)d_in[24];
  const float* wproj  = (const float*)d_in[25];
  const float* p_ws   = (const float*)d_in[26];
  const float* p_is   = (const float*)d_in[27];
  const float* smooth = (const float*)d_in[28];

  char* ws = (char*)d_ws;
  size_t off = 0;
  auto alloc = [&](size_t bytes) {
    char* p = ws + off;
    off += (bytes + 255) & ~(size_t)255;
    return p;
  };
  uint8_t*  Aq    = (uint8_t*)alloc((size_t)4096 * 2048);
  uint8_t*  Wcat  = (uint8_t*)alloc((size_t)6144 * 2048);
  uint8_t*  Wpb   = (uint8_t*)alloc((size_t)2048 * 4096);
  uint16_t* Wkvxh = (uint16_t*)alloc((size_t)2048 * 2048 * 2);
  uint16_t* Wkvxl = (uint16_t*)alloc((size_t)2048 * 2048 * 2);
  uint16_t* condh = (uint16_t*)alloc((size_t)1024 * 2048 * 2);
  uint16_t* condl = (uint16_t*)alloc((size_t)1024 * 2048 * 2);
  uint16_t* Qh    = (uint16_t*)alloc((size_t)4096 * 16 * 128 * 2);
  uint16_t* Qxh   = (uint16_t*)alloc((size_t)4096 * 16 * 128 * 2);
  uint16_t* Kf    = (uint16_t*)alloc((size_t)4096 * 8 * 128 * 2);
  uint16_t* Vtf   = (uint16_t*)alloc((size_t)4096 * 8 * 128 * 2);
  uint16_t* Kxf   = (uint16_t*)alloc((size_t)1024 * 8 * 128 * 2);
  uint16_t* Vxtf  = (uint16_t*)alloc((size_t)1024 * 8 * 128 * 2);
  uint8_t*  catq  = (uint8_t*)alloc((size_t)4096 * 4096);
  float* scales   = (float*)alloc(256);
  if (ws_size < off) return;

  k_prep<<<2048, 256, 0, stream>>>(wq, wqx, wk, wv, wkvx, wproj, cond,
      q_is, wq_s, qx_is, wqx_s, k_is, wk_s, v_is, wv_s, p_is, p_ws,
      Wcat, Wpb, Wkvxh, Wkvxl, condh, condl, scales);

  k_ln_quant<<<4096, 256, 0, stream>>>(hidden, ln_w, ln_b, q_is, Aq);

  k_gemm8<0><<<dim3(48, 32), 256, 0, stream>>>(Aq, Wcat,
      4096, 6144, 2048, scales, qln_w, qln_b, kln_w, kln_b, qxln_w, qxln_b,
      Qh, Qxh, Kf, Vtf, nullptr);

  k_kvx<<<dim3(16, 16), 256, 0, stream>>>(condh, condl, Wkvxh, Wkvxl,
      kxln_w, kxln_b, Kxf, Vxtf);

  k_attn<<<dim3(16, 16, 4), 512, 0, stream>>>(Qh, Qxh, Kf, Vtf, Kxf, Vxtf,
      smooth, catq);

  k_gemm8<2><<<dim3(16, 32), 256, 0, stream>>>(catq, Wpb,
      4096, 2048, 4096, scales, nullptr, nullptr, nullptr, nullptr, nullptr, nullptr,
      nullptr, nullptr, nullptr, nullptr,
      (float*)d_out);
}